// Round 2
// baseline (1886.391 us; speedup 1.0000x reference)
//
#include <hip/hip_runtime.h>
#include <math.h>

#define NB 8
#define NT 2048
#define ND 512
#define NH 8
#define NDK 64
#define NL 512

__device__ __forceinline__ float sigf(float v){ return 1.0f/(1.0f+__expf(-v)); }

// ---------------- pool by 4 over time (block mean) ----------------
// in: [rows*4, 512] f32, out: [rows, 512]; operates on float4 lanes (128/row)
__global__ void k_pool4(const float4* __restrict__ in, float4* __restrict__ out, int n4){
  int i = blockIdx.x*256 + threadIdx.x;
  if(i>=n4) return;
  int d4 = i & 127;
  size_t row = (size_t)(i>>7);
  const float4* p = in + row*512 + d4;   // row*4 input rows * 128 f4/row
  float4 a=p[0], b=p[128], c=p[256], d=p[384];
  float4 r;
  r.x=(a.x+b.x+c.x+d.x)*0.25f; r.y=(a.y+b.y+c.y+d.y)*0.25f;
  r.z=(a.z+b.z+c.z+d.z)*0.25f; r.w=(a.w+b.w+c.w+d.w)*0.25f;
  out[i]=r;
}

// ---------------- row LayerNorm over D=512, one wave per row ----------------
__global__ void k_ln(const float* __restrict__ in, float* __restrict__ out,
                     const float* __restrict__ gam, const float* __restrict__ bet){
  size_t row = blockIdx.x;
  int lane = threadIdx.x;   // 64
  const float4* p = (const float4*)(in + row*ND);
  float4 v0=p[lane*2], v1=p[lane*2+1];
  float s  = v0.x+v0.y+v0.z+v0.w+v1.x+v1.y+v1.z+v1.w;
  float ss = v0.x*v0.x+v0.y*v0.y+v0.z*v0.z+v0.w*v0.w
           + v1.x*v1.x+v1.y*v1.y+v1.z*v1.z+v1.w*v1.w;
  #pragma unroll
  for(int o=32;o;o>>=1){ s+=__shfl_xor(s,o); ss+=__shfl_xor(ss,o); }
  float m  = s*(1.0f/ND);
  float rs = rsqrtf(ss*(1.0f/ND)-m*m+1e-5f);
  const float4* gp=(const float4*)gam; const float4* bp=(const float4*)bet;
  float4 g0=gp[lane*2],g1=gp[lane*2+1],b0=bp[lane*2],b1=bp[lane*2+1];
  float4 o0,o1;
  o0.x=(v0.x-m)*rs*g0.x+b0.x; o0.y=(v0.y-m)*rs*g0.y+b0.y;
  o0.z=(v0.z-m)*rs*g0.z+b0.z; o0.w=(v0.w-m)*rs*g0.w+b0.w;
  o1.x=(v1.x-m)*rs*g1.x+b1.x; o1.y=(v1.y-m)*rs*g1.y+b1.y;
  o1.z=(v1.z-m)*rs*g1.z+b1.z; o1.w=(v1.w-m)*rs*g1.w+b1.w;
  float4* q=(float4*)(out+row*ND);
  q[lane*2]=o0; q[lane*2+1]=o1;
}

// NOTE: parameter names must not collide with float4 member names x/y/z/w
// (the `.w` token inside the body would be substituted by the macro arg).
#define FMA16(acc,va,vb) \
  acc[0][0]+=va.x*vb.x; acc[0][1]+=va.x*vb.y; acc[0][2]+=va.x*vb.z; acc[0][3]+=va.x*vb.w; \
  acc[1][0]+=va.y*vb.x; acc[1][1]+=va.y*vb.y; acc[1][2]+=va.y*vb.z; acc[1][3]+=va.y*vb.w; \
  acc[2][0]+=va.z*vb.x; acc[2][1]+=va.z*vb.y; acc[2][2]+=va.z*vb.z; acc[2][3]+=va.z*vb.w; \
  acc[3][0]+=va.w*vb.x; acc[3][1]+=va.w*vb.y; acc[3][2]+=va.w*vb.z; acc[3][3]+=va.w*vb.w;

// ---------------- generic tiled GEMM: C[M,N] = A[M,K] @ W[K,N] + bias ----------------
// grid = (N/64, M/64), 256 threads, 4x4 per thread, BK=16
__global__ __launch_bounds__(256)
void k_gemm_bias(const float* __restrict__ A, const float* __restrict__ W,
                 const float* __restrict__ bias, float* __restrict__ C,
                 int N, int K){
  __shared__ float As[16][64];
  __shared__ float Ws[16][64];
  int tid = threadIdx.x;
  int m0 = blockIdx.y*64, n0 = blockIdx.x*64;
  int tx4 = (tid&15)*4, ty4 = (tid>>4)*4;
  int ar = tid>>2,       ak = (tid&3)*4;   // A-tile: 64 rows x 16 k
  int wr = tid>>4,       wn = (tid&15)*4;  // W-tile: 16 k   x 64 n
  float acc[4][4]={};
  for(int k0=0;k0<K;k0+=16){
    float4 av = *(const float4*)&A[(size_t)(m0+ar)*K + k0 + ak];
    float4 wv = *(const float4*)&W[(size_t)(k0+wr)*N + n0 + wn];
    __syncthreads();
    As[ak+0][ar]=av.x; As[ak+1][ar]=av.y; As[ak+2][ar]=av.z; As[ak+3][ar]=av.w;
    *(float4*)&Ws[wr][wn] = wv;
    __syncthreads();
    #pragma unroll
    for(int kk=0;kk<16;kk++){
      float4 a = *(const float4*)&As[kk][ty4];
      float4 w = *(const float4*)&Ws[kk][tx4];
      FMA16(acc,a,w)
    }
  }
  float4 bv = *(const float4*)&bias[n0+tx4];
  #pragma unroll
  for(int i=0;i<4;i++){
    float4 o;
    o.x=acc[i][0]+bv.x; o.y=acc[i][1]+bv.y; o.z=acc[i][2]+bv.z; o.w=acc[i][3]+bv.w;
    *(float4*)&C[(size_t)(m0+ty4+i)*N + n0 + tx4] = o;
  }
}

// ---------------- GLU-fused GEMM: C[M,Dh] = (A@W[:,:Dh]+b_a) * sigmoid(A@W[:,Dh:]+b_b)
// W is [K, 2*Dh]. grid = (Dh/64, M/64)
__global__ __launch_bounds__(256)
void k_gemm_glu(const float* __restrict__ A, const float* __restrict__ W,
                const float* __restrict__ bias, float* __restrict__ C,
                int Dh, int K){
  __shared__ float As[16][64];
  __shared__ float Wa[16][64];
  __shared__ float Wb[16][64];
  int tid = threadIdx.x;
  int m0 = blockIdx.y*64, n0 = blockIdx.x*64;
  int tx4 = (tid&15)*4, ty4 = (tid>>4)*4;
  int ar = tid>>2,  ak = (tid&3)*4;
  int wr = tid>>4,  wn = (tid&15)*4;
  int N2 = 2*Dh;
  float acca[4][4]={}, accb[4][4]={};
  for(int k0=0;k0<K;k0+=16){
    float4 av = *(const float4*)&A[(size_t)(m0+ar)*K + k0 + ak];
    float4 wva = *(const float4*)&W[(size_t)(k0+wr)*N2 + n0 + wn];
    float4 wvb = *(const float4*)&W[(size_t)(k0+wr)*N2 + Dh + n0 + wn];
    __syncthreads();
    As[ak+0][ar]=av.x; As[ak+1][ar]=av.y; As[ak+2][ar]=av.z; As[ak+3][ar]=av.w;
    *(float4*)&Wa[wr][wn] = wva;
    *(float4*)&Wb[wr][wn] = wvb;
    __syncthreads();
    #pragma unroll
    for(int kk=0;kk<16;kk++){
      float4 a  = *(const float4*)&As[kk][ty4];
      float4 u1 = *(const float4*)&Wa[kk][tx4];
      float4 u2 = *(const float4*)&Wb[kk][tx4];
      FMA16(acca,a,u1)
      FMA16(accb,a,u2)
    }
  }
  float4 ba = *(const float4*)&bias[n0+tx4];
  float4 bb = *(const float4*)&bias[Dh+n0+tx4];
  #pragma unroll
  for(int i=0;i<4;i++){
    float4 o;
    o.x=(acca[i][0]+ba.x)*sigf(accb[i][0]+bb.x);
    o.y=(acca[i][1]+ba.y)*sigf(accb[i][1]+bb.y);
    o.z=(acca[i][2]+ba.z)*sigf(accb[i][2]+bb.z);
    o.w=(acca[i][3]+ba.w)*sigf(accb[i][3]+bb.w);
    *(float4*)&C[(size_t)(m0+ty4+i)*Dh + n0 + tx4] = o;
  }
}

// ---------------- attention: scores[b,h,i,j] = sum_d q[b,i,h,d]*k[b,j,h,d] ----------------
// grid = (8 jt, 8 it, 64 z=b*8+h), tiles 64x64, K=64
__global__ __launch_bounds__(256)
void k_qkt(const float* __restrict__ q, const float* __restrict__ k,
           float* __restrict__ scores){
  int z = blockIdx.z, b = z>>3, h = z&7;
  int i0 = blockIdx.y*64, j0 = blockIdx.x*64;
  __shared__ float Qs[64][64];   // [d][i]
  __shared__ float Ks[64][64];   // [d][j]
  int tid = threadIdx.x;
  const float* qb = q + ((size_t)b*NL + i0)*ND + h*NDK;
  const float* kb = k + ((size_t)b*NL + j0)*ND + h*NDK;
  #pragma unroll
  for(int r=0;r<4;r++){
    int f4 = tid + r*256;
    int row = f4>>4, dq = (f4&15)*4;
    float4 qa = *(const float4*)&qb[(size_t)row*ND + dq];
    float4 ka = *(const float4*)&kb[(size_t)row*ND + dq];
    Qs[dq+0][row]=qa.x; Qs[dq+1][row]=qa.y; Qs[dq+2][row]=qa.z; Qs[dq+3][row]=qa.w;
    Ks[dq+0][row]=ka.x; Ks[dq+1][row]=ka.y; Ks[dq+2][row]=ka.z; Ks[dq+3][row]=ka.w;
  }
  __syncthreads();
  int tx4 = (tid&15)*4, ty4 = (tid>>4)*4;
  float acc[4][4]={};
  #pragma unroll 8
  for(int d=0; d<64; d++){
    float4 a = *(const float4*)&Qs[d][ty4];
    float4 w = *(const float4*)&Ks[d][tx4];
    FMA16(acc,a,w)
  }
  float* sb = scores + (size_t)z*NL*NL;
  #pragma unroll
  for(int i=0;i<4;i++){
    float4 o; o.x=acc[i][0]; o.y=acc[i][1]; o.z=acc[i][2]; o.w=acc[i][3];
    *(float4*)&sb[(size_t)(i0+ty4+i)*NL + j0 + tx4] = o;
  }
}

// ---------------- scores[b,h,i,j] += sum_d q[b,i,h,d]*pos[i,j,d] ----------------
// grid = (8 jt, 512 i). Rows of the mini-GEMM are bh=0..63.
__global__ __launch_bounds__(256)
void k_bm(const float* __restrict__ q, const float* __restrict__ pos,
          float* __restrict__ scores){
  int i = blockIdx.y, j0 = blockIdx.x*64;
  __shared__ float Qs[64][64];   // [d][bh]
  __shared__ float Ps[64][64];   // [d][j]
  int tid = threadIdx.x;
  #pragma unroll
  for(int r=0;r<4;r++){
    int f4 = tid + r*256;
    int row = f4>>4, dq = (f4&15)*4;     // row: bh for Q, j for P
    float4 qa = *(const float4*)&q[(((size_t)(row>>3))*NL + i)*ND + (row&7)*NDK + dq];
    float4 pa = *(const float4*)&pos[((size_t)i*NL + j0 + row)*NDK + dq];
    Qs[dq+0][row]=qa.x; Qs[dq+1][row]=qa.y; Qs[dq+2][row]=qa.z; Qs[dq+3][row]=qa.w;
    Ps[dq+0][row]=pa.x; Ps[dq+1][row]=pa.y; Ps[dq+2][row]=pa.z; Ps[dq+3][row]=pa.w;
  }
  __syncthreads();
  int tx4 = (tid&15)*4, ty4 = (tid>>4)*4;
  float acc[4][4]={};
  #pragma unroll 8
  for(int d=0; d<64; d++){
    float4 a = *(const float4*)&Qs[d][ty4];
    float4 w = *(const float4*)&Ps[d][tx4];
    FMA16(acc,a,w)
  }
  #pragma unroll
  for(int ii=0;ii<4;ii++){
    int bh = ty4+ii;
    float* dst = scores + ((size_t)bh*NL + i)*NL + j0 + tx4;
    float4 cur = *(float4*)dst;
    cur.x+=acc[ii][0]; cur.y+=acc[ii][1]; cur.z+=acc[ii][2]; cur.w+=acc[ii][3];
    *(float4*)dst = cur;
  }
}

// ---------------- softmax over last dim (512), scale 1/8, one wave per row ----------------
__global__ void k_softmax(float* __restrict__ s){
  size_t row = blockIdx.x;
  float4* p = (float4*)(s + row*NL);
  int lane = threadIdx.x;
  float4 v0=p[lane*2], v1=p[lane*2+1];
  const float sc=0.125f;
  v0.x*=sc; v0.y*=sc; v0.z*=sc; v0.w*=sc;
  v1.x*=sc; v1.y*=sc; v1.z*=sc; v1.w*=sc;
  float mx = fmaxf(fmaxf(fmaxf(v0.x,v0.y),fmaxf(v0.z,v0.w)),
                   fmaxf(fmaxf(v1.x,v1.y),fmaxf(v1.z,v1.w)));
  #pragma unroll
  for(int o=32;o;o>>=1) mx = fmaxf(mx, __shfl_xor(mx,o));
  v0.x=__expf(v0.x-mx); v0.y=__expf(v0.y-mx); v0.z=__expf(v0.z-mx); v0.w=__expf(v0.w-mx);
  v1.x=__expf(v1.x-mx); v1.y=__expf(v1.y-mx); v1.z=__expf(v1.z-mx); v1.w=__expf(v1.w-mx);
  float sm = v0.x+v0.y+v0.z+v0.w+v1.x+v1.y+v1.z+v1.w;
  #pragma unroll
  for(int o=32;o;o>>=1) sm += __shfl_xor(sm,o);
  float inv = 1.0f/sm;
  v0.x*=inv; v0.y*=inv; v0.z*=inv; v0.w*=inv;
  v1.x*=inv; v1.y*=inv; v1.z*=inv; v1.w*=inv;
  p[lane*2]=v0; p[lane*2+1]=v1;
}

// ---------------- o[b,i,h*64+d] = sum_j attn[b,h,i,j] * v[b,j,h*64+d] ----------------
// grid = (8 it, 64 z), tile 64(i) x 64(d), K=512 in BK=32 steps
__global__ __launch_bounds__(256)
void k_pv(const float* __restrict__ attn, const float* __restrict__ v,
          float* __restrict__ o){
  int z = blockIdx.y, b = z>>3, h = z&7;
  int i0 = blockIdx.x*64;
  __shared__ float As[32][64];  // [k][i]
  __shared__ float Vs[32][64];  // [k][d]
  const float* ab = attn + ((size_t)z*NL + i0)*NL;
  const float* vb = v + (size_t)b*NL*ND + h*NDK;
  int tid = threadIdx.x;
  int tx4 = (tid&15)*4, ty4 = (tid>>4)*4;
  float acc[4][4]={};
  for(int k0=0;k0<NL;k0+=32){
    int f40 = tid,     f41 = tid+256;
    int ai0 = f40>>3,  aq0 = (f40&7)*4;
    int ai1 = f41>>3,  aq1 = (f41&7)*4;
    int vk0 = f40>>4,  vd0 = (f40&15)*4;
    int vk1 = f41>>4,  vd1 = (f41&15)*4;
    float4 av0 = *(const float4*)&ab[(size_t)ai0*NL + k0 + aq0];
    float4 av1 = *(const float4*)&ab[(size_t)ai1*NL + k0 + aq1];
    float4 vv0 = *(const float4*)&vb[(size_t)(k0+vk0)*ND + vd0];
    float4 vv1 = *(const float4*)&vb[(size_t)(k0+vk1)*ND + vd1];
    __syncthreads();
    As[aq0+0][ai0]=av0.x; As[aq0+1][ai0]=av0.y; As[aq0+2][ai0]=av0.z; As[aq0+3][ai0]=av0.w;
    As[aq1+0][ai1]=av1.x; As[aq1+1][ai1]=av1.y; As[aq1+2][ai1]=av1.z; As[aq1+3][ai1]=av1.w;
    *(float4*)&Vs[vk0][vd0]=vv0;
    *(float4*)&Vs[vk1][vd1]=vv1;
    __syncthreads();
    #pragma unroll
    for(int kk=0;kk<32;kk++){
      float4 a = *(const float4*)&As[kk][ty4];
      float4 w = *(const float4*)&Vs[kk][tx4];
      FMA16(acc,a,w)
    }
  }
  float* ob = o + ((size_t)b*NL + i0)*ND + h*NDK;
  #pragma unroll
  for(int i=0;i<4;i++){
    float4 r; r.x=acc[i][0]; r.y=acc[i][1]; r.z=acc[i][2]; r.w=acc[i][3];
    *(float4*)&ob[(size_t)(ty4+i)*ND + tx4] = r;
  }
}

// ---------------- x_out = x_in + sigmoid(gate) * up[row/4] ----------------
__global__ void k_combine(const float4* __restrict__ xin, const float4* __restrict__ gate,
                          const float4* __restrict__ up, float4* __restrict__ xout, int n4){
  int i = blockIdx.x*256 + threadIdx.x;
  if(i>=n4) return;
  int d4 = i & 127;
  size_t row = (size_t)(i>>7);      // b*T + t
  size_t prow = row>>2;             // b*(T/4) + t/4
  float4 x = xin[i], g = gate[i], u = up[prow*128 + d4];
  float4 r;
  r.x = x.x + sigf(g.x)*u.x;
  r.y = x.y + sigf(g.y)*u.y;
  r.z = x.z + sigf(g.z)*u.z;
  r.w = x.w + sigf(g.w)*u.w;
  xout[i]=r;
}

// ---------------- x_out = a + b ----------------
__global__ void k_add(const float4* __restrict__ a, const float4* __restrict__ b,
                      float4* __restrict__ out, int n4){
  int i = blockIdx.x*256 + threadIdx.x;
  if(i>=n4) return;
  float4 x=a[i], y=b[i], r;
  r.x=x.x+y.x; r.y=x.y+y.y; r.z=x.z+y.z; r.w=x.w+y.w;
  out[i]=r;
}

// ---------------- depthwise conv1d over time, K=31, SAME, per channel ----------------
// in/out: [b, t, c] with c contiguous (512). w: [c, 31]. grid (2 c-half, T/4, B)
__global__ __launch_bounds__(256)
void k_dwconv(const float* __restrict__ in, const float* __restrict__ w,
              const float* __restrict__ bias, float* __restrict__ out){
  int c  = blockIdx.x*256 + threadIdx.x;
  int t0 = blockIdx.y*4;
  int b  = blockIdx.z;
  const float* ib = in + (size_t)b*NT*ND + c;
  float win[34];
  #pragma unroll
  for(int r=0;r<34;r++){
    int t = t0 - 15 + r;
    win[r] = (t>=0 && t<NT) ? ib[(size_t)t*ND] : 0.0f;
  }
  float wg[31];
  #pragma unroll
  for(int kk=0;kk<31;kk++) wg[kk] = w[c*31+kk];
  float bs = bias[c];
  float* ob = out + (size_t)b*NT*ND + c;
  #pragma unroll
  for(int oo=0;oo<4;oo++){
    float s = bs;
    #pragma unroll
    for(int kk=0;kk<31;kk++) s += win[oo+kk]*wg[kk];
    ob[(size_t)(t0+oo)*ND] = s;
  }
}

extern "C" void kernel_launch(void* const* d_in, const int* in_sizes, int n_in,
                              void* d_out, int out_size, void* d_ws, size_t ws_size,
                              hipStream_t stream) {
  const float* x      = (const float*)d_in[0];
  const float* pos    = (const float*)d_in[1];
  const float* mha_g  = (const float*)d_in[2];
  const float* mha_b  = (const float*)d_in[3];
  const float* wq     = (const float*)d_in[4];
  const float* bq     = (const float*)d_in[5];
  const float* wk     = (const float*)d_in[6];
  const float* bk     = (const float*)d_in[7];
  const float* wv     = (const float*)d_in[8];
  const float* bv     = (const float*)d_in[9];
  const float* wo     = (const float*)d_in[10];
  const float* bo     = (const float*)d_in[11];
  const float* ega_wg = (const float*)d_in[12];
  const float* ega_bg = (const float*)d_in[13];
  const float* g1_ln_g= (const float*)d_in[14];
  const float* g1_ln_b= (const float*)d_in[15];
  const float* g1_w1  = (const float*)d_in[16];
  const float* g1_b1  = (const float*)d_in[17];
  const float* g1_w2  = (const float*)d_in[18];
  const float* g1_b2  = (const float*)d_in[19];
  const float* g1_wg  = (const float*)d_in[20];
  const float* g1_bg  = (const float*)d_in[21];
  const float* cla_ln_g=(const float*)d_in[22];
  const float* cla_ln_b=(const float*)d_in[23];
  const float* cla_w1 = (const float*)d_in[24];
  const float* cla_b1 = (const float*)d_in[25];
  const float* dw_w   = (const float*)d_in[26];
  const float* dw_b   = (const float*)d_in[27];
  const float* cla_w2 = (const float*)d_in[28];
  const float* cla_b2 = (const float*)d_in[29];
  const float* g2_ln_g= (const float*)d_in[30];
  const float* g2_ln_b= (const float*)d_in[31];
  const float* g2_w1  = (const float*)d_in[32];
  const float* g2_b1  = (const float*)d_in[33];
  const float* g2_w2  = (const float*)d_in[34];
  const float* g2_b2  = (const float*)d_in[35];
  const float* g2_wg  = (const float*)d_in[36];
  const float* g2_bg  = (const float*)d_in[37];

  float* xo = (float*)d_out;
  float* ws = (float*)d_ws;
  const size_t M1 = 1024*1024;
  float* SC = ws;                 // 16M floats: scores / GCFN glu / conv out
  float* X0 = ws + 16*M1;         // 8M: gates / CLA glu
  float* X1 = ws + 24*M1;         // 8M: CLA ln(x) / CLA y2
  float* s0 = ws + 32*M1;         // 2M: pooled
  float* s1 = ws + 34*M1;         // 2M: ln out
  float* s2 = ws + 36*M1;         // 2M: q
  float* s3 = ws + 38*M1;         // 2M: k
  float* s4 = ws + 40*M1;         // 2M: v
  float* s5 = ws + 42*M1;         // 2M: attn out o
  float* s6 = ws + 44*M1;         // 2M: o@wo / GCFN y2

  const int rowsP = NB*NL;        // 4096 pooled rows
  const int rowsF = NB*NT;        // 16384 full rows
  const int n4P = rowsP*128, n4F = rowsF*128;
  dim3 blk(256);
  dim3 gP(ND/64, rowsP/64);       // pooled-M gemm grid (8,64)
  dim3 gF(ND/64, rowsF/64);       // full-M gemm grid (8,256)

  // ================= EGA =================
  k_pool4<<<(n4P+255)/256, blk, 0, stream>>>((const float4*)x, (float4*)s0, n4P);
  k_ln<<<rowsP, 64, 0, stream>>>(s0, s1, mha_g, mha_b);
  k_gemm_bias<<<gP, blk, 0, stream>>>(s1, wq, bq, s2, ND, ND);
  k_gemm_bias<<<gP, blk, 0, stream>>>(s1, wk, bk, s3, ND, ND);
  k_gemm_bias<<<gP, blk, 0, stream>>>(s1, wv, bv, s4, ND, ND);
  k_qkt<<<dim3(8,8,64), blk, 0, stream>>>(s2, s3, SC);
  k_bm<<<dim3(8,512), blk, 0, stream>>>(s2, pos, SC);
  k_softmax<<<NB*NH*NL, 64, 0, stream>>>(SC);
  k_pv<<<dim3(8,64), blk, 0, stream>>>(SC, s4, s5);
  k_gemm_bias<<<gP, blk, 0, stream>>>(s5, wo, bo, s6, ND, ND);
  k_gemm_bias<<<gF, blk, 0, stream>>>(x, ega_wg, ega_bg, X0, ND, ND);
  k_combine<<<(n4F+255)/256, blk, 0, stream>>>((const float4*)x, (const float4*)X0,
                                               (const float4*)s6, (float4*)xo, n4F);

  // ================= GCFN (global, g1) =================
  k_pool4<<<(n4P+255)/256, blk, 0, stream>>>((const float4*)xo, (float4*)s0, n4P);
  k_ln<<<rowsP, 64, 0, stream>>>(s0, s1, g1_ln_g, g1_ln_b);
  k_gemm_glu<<<dim3(1536/64, rowsP/64), blk, 0, stream>>>(s1, g1_w1, g1_b1, SC, 1536, ND);
  k_gemm_bias<<<gP, blk, 0, stream>>>(SC, g1_w2, g1_b2, s6, ND, 1536);
  k_gemm_bias<<<gF, blk, 0, stream>>>(xo, g1_wg, g1_bg, X0, ND, ND);
  k_combine<<<(n4F+255)/256, blk, 0, stream>>>((const float4*)xo, (const float4*)X0,
                                               (const float4*)s6, (float4*)xo, n4F);

  // ================= CLA =================
  k_ln<<<rowsF, 64, 0, stream>>>(xo, X1, cla_ln_g, cla_ln_b);
  k_gemm_glu<<<dim3(ND/64, rowsF/64), blk, 0, stream>>>(X1, cla_w1, cla_b1, X0, ND, ND);
  k_dwconv<<<dim3(2, NT/4, NB), blk, 0, stream>>>(X0, dw_w, dw_b, SC);
  k_gemm_bias<<<gF, blk, 0, stream>>>(SC, cla_w2, cla_b2, X1, ND, ND);
  k_add<<<(n4F+255)/256, blk, 0, stream>>>((const float4*)xo, (const float4*)X1,
                                           (float4*)xo, n4F);

  // ================= GCFN (local, g2) =================
  k_pool4<<<(n4P+255)/256, blk, 0, stream>>>((const float4*)xo, (float4*)s0, n4P);
  k_ln<<<rowsP, 64, 0, stream>>>(s0, s1, g2_ln_g, g2_ln_b);
  k_gemm_glu<<<dim3(1536/64, rowsP/64), blk, 0, stream>>>(s1, g2_w1, g2_b1, SC, 1536, ND);
  k_gemm_bias<<<gP, blk, 0, stream>>>(SC, g2_w2, g2_b2, s6, ND, 1536);
  k_gemm_bias<<<gF, blk, 0, stream>>>(xo, g2_wg, g2_bg, X0, ND, ND);
  k_combine<<<(n4F+255)/256, blk, 0, stream>>>((const float4*)xo, (const float4*)X0,
                                               (const float4*)s6, (float4*)xo, n4F);
}

// Round 5
// 698.659 us; speedup vs baseline: 2.7000x; 2.7000x over previous
//
#include <hip/hip_runtime.h>
#include <math.h>

#define NB 8
#define NT 2048
#define ND 512
#define NH 8
#define NDK 64
#define NL 512

typedef unsigned short u16;
typedef __attribute__((ext_vector_type(8))) short bf16x8;
typedef __attribute__((ext_vector_type(4))) float f32x4;

__device__ __forceinline__ float sigf(float v){ return 1.0f/(1.0f+__expf(-v)); }

__device__ __forceinline__ u16 f2b(float f){
  union{float f; unsigned u;} v; v.f = f;
  unsigned r = v.u + 0x7fffu + ((v.u>>16)&1u);
  return (u16)(r>>16);
}

#define GLOAD16(src, dst) \
  __builtin_amdgcn_global_load_lds((const __attribute__((address_space(1))) void*)(src), \
                                   (__attribute__((address_space(3))) void*)(dst), 16, 0, 0)

// ---------------- pool by 4 over time ----------------
__global__ void k_pool4(const float4* __restrict__ in, float4* __restrict__ out, int n4){
  int i = blockIdx.x*256 + threadIdx.x;
  if(i>=n4) return;
  int d4 = i & 127;
  size_t row = (size_t)(i>>7);
  const float4* p = in + row*512 + d4;
  float4 a=p[0], b=p[128], c=p[256], d=p[384];
  float4 r;
  r.x=(a.x+b.x+c.x+d.x)*0.25f; r.y=(a.y+b.y+c.y+d.y)*0.25f;
  r.z=(a.z+b.z+c.z+d.z)*0.25f; r.w=(a.w+b.w+c.w+d.w)*0.25f;
  out[i]=r;
}

// ---------------- row LayerNorm over D=512 -> bf16 out ----------------
__global__ void k_ln(const float* __restrict__ in, u16* __restrict__ outb,
                     const float* __restrict__ gam, const float* __restrict__ bet){
  size_t row = blockIdx.x;
  int lane = threadIdx.x;   // 64
  const float4* p = (const float4*)(in + row*ND);
  float4 v0=p[lane*2], v1=p[lane*2+1];
  float s  = v0.x+v0.y+v0.z+v0.w+v1.x+v1.y+v1.z+v1.w;
  float ss = v0.x*v0.x+v0.y*v0.y+v0.z*v0.z+v0.w*v0.w
           + v1.x*v1.x+v1.y*v1.y+v1.z*v1.z+v1.w*v1.w;
  #pragma unroll
  for(int o=32;o;o>>=1){ s+=__shfl_xor(s,o); ss+=__shfl_xor(ss,o); }
  float m  = s*(1.0f/ND);
  float rs = rsqrtf(ss*(1.0f/ND)-m*m+1e-5f);
  const float4* gp=(const float4*)gam; const float4* bp=(const float4*)bet;
  float4 g0=gp[lane*2],g1=gp[lane*2+1],b0=bp[lane*2],b1=bp[lane*2+1];
  float o0=(v0.x-m)*rs*g0.x+b0.x, o1=(v0.y-m)*rs*g0.y+b0.y;
  float o2=(v0.z-m)*rs*g0.z+b0.z, o3=(v0.w-m)*rs*g0.w+b0.w;
  float o4=(v1.x-m)*rs*g1.x+b1.x, o5=(v1.y-m)*rs*g1.y+b1.y;
  float o6=(v1.z-m)*rs*g1.z+b1.z, o7=(v1.w-m)*rs*g1.w+b1.w;
  uint4 pk;
  pk.x = (unsigned)f2b(o0) | ((unsigned)f2b(o1)<<16);
  pk.y = (unsigned)f2b(o2) | ((unsigned)f2b(o3)<<16);
  pk.z = (unsigned)f2b(o4) | ((unsigned)f2b(o5)<<16);
  pk.w = (unsigned)f2b(o6) | ((unsigned)f2b(o7)<<16);
  *(uint4*)&outb[row*ND + lane*8] = pk;
}

// ---------------- cast f32 -> bf16 (one float4 per thread) ----------------
__global__ void k_castb(const float4* __restrict__ in, ushort4* __restrict__ out, int n4){
  int i = blockIdx.x*256 + threadIdx.x;
  if(i>=n4) return;
  float4 v = in[i];
  out[i] = make_ushort4(f2b(v.x), f2b(v.y), f2b(v.z), f2b(v.w));
}

// ---------------- weight transpose+cast: W[K][N] f32 -> WT[N][K] bf16 ----------------
__global__ __launch_bounds__(256)
void k_wt(const float* __restrict__ W, u16* __restrict__ WT, int K, int N){
  __shared__ float ls[32][33];
  int tid = threadIdx.x;
  int n0 = blockIdx.x*32, k0 = blockIdx.y*32;
  int tx = tid&31, ty = tid>>5;   // ty 0..7
  #pragma unroll
  for(int p=0;p<4;p++)
    ls[ty+p*8][tx] = W[(size_t)(k0+ty+p*8)*N + n0+tx];
  __syncthreads();
  #pragma unroll
  for(int p=0;p<4;p++)
    WT[(size_t)(n0+ty+p*8)*K + k0+tx] = f2b(ls[tx][ty+p*8]);
}

// =======================================================================
// MFMA GEMM: C[M,N] = A_bf16[M,K] @ (BT_bf16[N,K])^T  (+ epilogue)
// BM=128, BN=128, BK=32, 256 threads (4 waves, 2x2), wave tile 64x64.
// EPI: 0 = outF = acc+bias (f32)
//      1 = gate: outF = xin + sigmoid(acc+bias)*up[row>>2]; outB (opt) = bf16(outF)
//      2 = add:  outF = xin + acc + bias;                   outB (opt) = bf16(outF)
// =======================================================================
template<int EPI>
__global__ __launch_bounds__(256)
void k_gemm_mfma(const u16* __restrict__ A, const u16* __restrict__ BT,
                 const float* __restrict__ bias,
                 const float* __restrict__ xin, const float* __restrict__ up,
                 float* __restrict__ outF, u16* __restrict__ outB,
                 int M, int N, int K){
  __shared__ short lA[128*32];
  __shared__ short lB[128*32];
  int tid = threadIdx.x;
  int wv_ = tid>>6, ln_ = tid&63;
  int wy = wv_>>1, wx = wv_&1;
  int m0 = blockIdx.y*128, n0 = blockIdx.x*128;

  f32x4 acc[4][4];
  #pragma unroll
  for(int i=0;i<4;i++)
    #pragma unroll
    for(int j=0;j<4;j++){ f32x4 z = {0.f,0.f,0.f,0.f}; acc[i][j]=z; }

  int fr = ln_&15, kg = ln_>>4;
  int aoff[4], boff[4];
  #pragma unroll
  for(int i=0;i<4;i++){
    int ar = wy*64 + i*16 + fr;
    aoff[i] = ar*64 + ((kg ^ ((ar>>1)&3))<<4);
    int br = wx*64 + i*16 + fr;
    boff[i] = br*64 + ((kg ^ ((br>>1)&3))<<4);
  }

  for(int k0=0;k0<K;k0+=32){
    #pragma unroll
    for(int q=0;q<2;q++){
      int s = q*256 + tid;
      int row = s>>2;
      int gl = (s&3) ^ ((row>>1)&3);
      GLOAD16(A  + (size_t)(m0+row)*K + k0 + gl*8, &lA[(q*4+wv_)*512]);
      GLOAD16(BT + (size_t)(n0+row)*K + k0 + gl*8, &lB[(q*4+wv_)*512]);
    }
    __syncthreads();
    bf16x8 af[4], bf[4];
    #pragma unroll
    for(int i=0;i<4;i++) af[i] = *(const bf16x8*)((const char*)lA + aoff[i]);
    #pragma unroll
    for(int j=0;j<4;j++) bf[j] = *(const bf16x8*)((const char*)lB + boff[j]);
    #pragma unroll
    for(int i=0;i<4;i++)
      #pragma unroll
      for(int j=0;j<4;j++)
        acc[i][j] = __builtin_amdgcn_mfma_f32_16x16x32_bf16(af[i], bf[j], acc[i][j], 0,0,0);
    __syncthreads();
  }

  int r0 = (ln_>>4)*4, c0 = ln_&15;
  #pragma unroll
  for(int i=0;i<4;i++){
    #pragma unroll
    for(int j=0;j<4;j++){
      int gr = m0 + wy*64 + i*16 + r0;
      int gc = n0 + wx*64 + j*16 + c0;
      float bv = bias[gc];
      #pragma unroll
      for(int r=0;r<4;r++){
        float val = acc[i][j][r] + bv;
        size_t idx = (size_t)(gr+r)*N + gc;
        if(EPI==0){
          outF[idx] = val;
        } else if(EPI==1){
          float o = xin[idx] + sigf(val)*up[(size_t)((gr+r)>>2)*N + gc];
          outF[idx] = o;
          if(outB) outB[idx] = f2b(o);
        } else {
          float o = xin[idx] + val;
          outF[idx] = o;
          if(outB) outB[idx] = f2b(o);
        }
      }
    }
  }
}

// =======================================================================
// MFMA GLU GEMM: out[M,Dh] = (A@Wa^T + ba) * sigmoid(A@Wb^T + bb)
// WT is [2*Dh][K] bf16; Wa rows = n, Wb rows = Dh+n. BM=128, BN=64, BK=32.
// =======================================================================
template<bool OUT_BF16>
__global__ __launch_bounds__(256)
void k_glu_mfma(const u16* __restrict__ A, const u16* __restrict__ WT,
                const float* __restrict__ bias,
                float* __restrict__ outF, u16* __restrict__ outB,
                int M, int Dh, int K){
  __shared__ short lA [128*32];
  __shared__ short lBa[64*32];
  __shared__ short lBb[64*32];
  int tid = threadIdx.x;
  int wv_ = tid>>6, ln_ = tid&63;
  int wy = wv_>>1, wx = wv_&1;
  int m0 = blockIdx.y*128, n0 = blockIdx.x*64;

  f32x4 aca[4][2], acb[4][2];
  #pragma unroll
  for(int i=0;i<4;i++)
    #pragma unroll
    for(int j=0;j<2;j++){ f32x4 z={0.f,0.f,0.f,0.f}; aca[i][j]=z; acb[i][j]=z; }

  int fr = ln_&15, kg = ln_>>4;
  int aoff[4], boff[2];
  #pragma unroll
  for(int i=0;i<4;i++){
    int ar = wy*64 + i*16 + fr;
    aoff[i] = ar*64 + ((kg ^ ((ar>>1)&3))<<4);
  }
  #pragma unroll
  for(int j=0;j<2;j++){
    int br = wx*32 + j*16 + fr;
    boff[j] = br*64 + ((kg ^ ((br>>1)&3))<<4);
  }

  for(int k0=0;k0<K;k0+=32){
    #pragma unroll
    for(int q=0;q<2;q++){
      int s = q*256 + tid;
      int row = s>>2;
      int gl = (s&3) ^ ((row>>1)&3);
      GLOAD16(A + (size_t)(m0+row)*K + k0 + gl*8, &lA[(q*4+wv_)*512]);
    }
    {
      int s = tid;                    // 256 slots = 64 rows
      int row = s>>2;
      int gl = (s&3) ^ ((row>>1)&3);
      GLOAD16(WT + (size_t)(n0+row)*K      + k0 + gl*8, &lBa[wv_*512]);
      GLOAD16(WT + (size_t)(Dh+n0+row)*K   + k0 + gl*8, &lBb[wv_*512]);
    }
    __syncthreads();
    bf16x8 af[4], ba[2], bb[2];
    #pragma unroll
    for(int i=0;i<4;i++) af[i] = *(const bf16x8*)((const char*)lA + aoff[i]);
    #pragma unroll
    for(int j=0;j<2;j++){
      ba[j] = *(const bf16x8*)((const char*)lBa + boff[j]);
      bb[j] = *(const bf16x8*)((const char*)lBb + boff[j]);
    }
    #pragma unroll
    for(int i=0;i<4;i++)
      #pragma unroll
      for(int j=0;j<2;j++){
        aca[i][j] = __builtin_amdgcn_mfma_f32_16x16x32_bf16(af[i], ba[j], aca[i][j], 0,0,0);
        acb[i][j] = __builtin_amdgcn_mfma_f32_16x16x32_bf16(af[i], bb[j], acb[i][j], 0,0,0);
      }
    __syncthreads();
  }

  int r0 = (ln_>>4)*4, c0 = ln_&15;
  #pragma unroll
  for(int i=0;i<4;i++){
    #pragma unroll
    for(int j=0;j<2;j++){
      int gr = m0 + wy*64 + i*16 + r0;
      int gc = n0 + wx*32 + j*16 + c0;
      float bva = bias[gc], bvb = bias[Dh+gc];
      #pragma unroll
      for(int r=0;r<4;r++){
        float o = (aca[i][j][r]+bva) * sigf(acb[i][j][r]+bvb);
        size_t idx = (size_t)(gr+r)*Dh + gc;
        if(OUT_BF16) outB[idx] = f2b(o);
        else         outF[idx] = o;
      }
    }
  }
}

#define FMA16(acc,va,vb) \
  acc[0][0]+=va.x*vb.x; acc[0][1]+=va.x*vb.y; acc[0][2]+=va.x*vb.z; acc[0][3]+=va.x*vb.w; \
  acc[1][0]+=va.y*vb.x; acc[1][1]+=va.y*vb.y; acc[1][2]+=va.y*vb.z; acc[1][3]+=va.y*vb.w; \
  acc[2][0]+=va.z*vb.x; acc[2][1]+=va.z*vb.y; acc[2][2]+=va.z*vb.z; acc[2][3]+=va.z*vb.w; \
  acc[3][0]+=va.w*vb.x; acc[3][1]+=va.w*vb.y; acc[3][2]+=va.w*vb.z; acc[3][3]+=va.w*vb.w;

// ---------------- attention: scores = q.k^T (fp32) ----------------
__global__ __launch_bounds__(256)
void k_qkt(const float* __restrict__ q, const float* __restrict__ k,
           float* __restrict__ scores){
  int z = blockIdx.z, b = z>>3, h = z&7;
  int i0 = blockIdx.y*64, j0 = blockIdx.x*64;
  __shared__ float Qs[64][64];
  __shared__ float Ks[64][64];
  int tid = threadIdx.x;
  const float* qb = q + ((size_t)b*NL + i0)*ND + h*NDK;
  const float* kb = k + ((size_t)b*NL + j0)*ND + h*NDK;
  #pragma unroll
  for(int r=0;r<4;r++){
    int f4 = tid + r*256;
    int row = f4>>4, dq = (f4&15)*4;
    float4 qa = *(const float4*)&qb[(size_t)row*ND + dq];
    float4 ka = *(const float4*)&kb[(size_t)row*ND + dq];
    Qs[dq+0][row]=qa.x; Qs[dq+1][row]=qa.y; Qs[dq+2][row]=qa.z; Qs[dq+3][row]=qa.w;
    Ks[dq+0][row]=ka.x; Ks[dq+1][row]=ka.y; Ks[dq+2][row]=ka.z; Ks[dq+3][row]=ka.w;
  }
  __syncthreads();
  int tx4 = (tid&15)*4, ty4 = (tid>>4)*4;
  float acc[4][4]={};
  #pragma unroll 8
  for(int d=0; d<64; d++){
    float4 a = *(const float4*)&Qs[d][ty4];
    float4 w = *(const float4*)&Ks[d][tx4];
    FMA16(acc,a,w)
  }
  float* sb = scores + (size_t)z*NL*NL;
  #pragma unroll
  for(int i=0;i<4;i++){
    float4 o; o.x=acc[i][0]; o.y=acc[i][1]; o.z=acc[i][2]; o.w=acc[i][3];
    *(float4*)&sb[(size_t)(i0+ty4+i)*NL + j0 + tx4] = o;
  }
}

// ---------------- scores += q . pos^T ----------------
__global__ __launch_bounds__(256)
void k_bm(const float* __restrict__ q, const float* __restrict__ pos,
          float* __restrict__ scores){
  int i = blockIdx.y, j0 = blockIdx.x*64;
  __shared__ float Qs[64][64];
  __shared__ float Ps[64][64];
  int tid = threadIdx.x;
  #pragma unroll
  for(int r=0;r<4;r++){
    int f4 = tid + r*256;
    int row = f4>>4, dq = (f4&15)*4;
    float4 qa = *(const float4*)&q[(((size_t)(row>>3))*NL + i)*ND + (row&7)*NDK + dq];
    float4 pa = *(const float4*)&pos[((size_t)i*NL + j0 + row)*NDK + dq];
    Qs[dq+0][row]=qa.x; Qs[dq+1][row]=qa.y; Qs[dq+2][row]=qa.z; Qs[dq+3][row]=qa.w;
    Ps[dq+0][row]=pa.x; Ps[dq+1][row]=pa.y; Ps[dq+2][row]=pa.z; Ps[dq+3][row]=pa.w;
  }
  __syncthreads();
  int tx4 = (tid&15)*4, ty4 = (tid>>4)*4;
  float acc[4][4]={};
  #pragma unroll 8
  for(int d=0; d<64; d++){
    float4 a = *(const float4*)&Qs[d][ty4];
    float4 w = *(const float4*)&Ps[d][tx4];
    FMA16(acc,a,w)
  }
  #pragma unroll
  for(int ii=0;ii<4;ii++){
    int bh = ty4+ii;
    float* dst = scores + ((size_t)bh*NL + i)*NL + j0 + tx4;
    float4 cur = *(float4*)dst;
    cur.x+=acc[ii][0]; cur.y+=acc[ii][1]; cur.z+=acc[ii][2]; cur.w+=acc[ii][3];
    *(float4*)dst = cur;
  }
}

// ---------------- softmax over last dim (512), scale 1/8 ----------------
__global__ void k_softmax(float* __restrict__ s){
  size_t row = blockIdx.x;
  float4* p = (float4*)(s + row*NL);
  int lane = threadIdx.x;
  float4 v0=p[lane*2], v1=p[lane*2+1];
  const float sc=0.125f;
  v0.x*=sc; v0.y*=sc; v0.z*=sc; v0.w*=sc;
  v1.x*=sc; v1.y*=sc; v1.z*=sc; v1.w*=sc;
  float mx = fmaxf(fmaxf(fmaxf(v0.x,v0.y),fmaxf(v0.z,v0.w)),
                   fmaxf(fmaxf(v1.x,v1.y),fmaxf(v1.z,v1.w)));
  #pragma unroll
  for(int o=32;o;o>>=1) mx = fmaxf(mx, __shfl_xor(mx,o));
  v0.x=__expf(v0.x-mx); v0.y=__expf(v0.y-mx); v0.z=__expf(v0.z-mx); v0.w=__expf(v0.w-mx);
  v1.x=__expf(v1.x-mx); v1.y=__expf(v1.y-mx); v1.z=__expf(v1.z-mx); v1.w=__expf(v1.w-mx);
  float sm = v0.x+v0.y+v0.z+v0.w+v1.x+v1.y+v1.z+v1.w;
  #pragma unroll
  for(int o=32;o;o>>=1) sm += __shfl_xor(sm,o);
  float inv = 1.0f/sm;
  v0.x*=inv; v0.y*=inv; v0.z*=inv; v0.w*=inv;
  v1.x*=inv; v1.y*=inv; v1.z*=inv; v1.w*=inv;
  p[lane*2]=v0; p[lane*2+1]=v1;
}

// ---------------- o = attn @ v  (fp32 in, bf16 out) ----------------
__global__ __launch_bounds__(256)
void k_pv(const float* __restrict__ attn, const float* __restrict__ v,
          u16* __restrict__ o){
  int z = blockIdx.y, b = z>>3, h = z&7;
  int i0 = blockIdx.x*64;
  __shared__ float As[32][64];
  __shared__ float Vs[32][64];
  const float* ab = attn + ((size_t)z*NL + i0)*NL;
  const float* vb = v + (size_t)b*NL*ND + h*NDK;
  int tid = threadIdx.x;
  int tx4 = (tid&15)*4, ty4 = (tid>>4)*4;
  float acc[4][4]={};
  for(int k0=0;k0<NL;k0+=32){
    int f40 = tid,     f41 = tid+256;
    int ai0 = f40>>3,  aq0 = (f40&7)*4;
    int ai1 = f41>>3,  aq1 = (f41&7)*4;
    int vk0 = f40>>4,  vd0 = (f40&15)*4;
    int vk1 = f41>>4,  vd1 = (f41&15)*4;
    float4 av0 = *(const float4*)&ab[(size_t)ai0*NL + k0 + aq0];
    float4 av1 = *(const float4*)&ab[(size_t)ai1*NL + k0 + aq1];
    float4 vv0 = *(const float4*)&vb[(size_t)(k0+vk0)*ND + vd0];
    float4 vv1 = *(const float4*)&vb[(size_t)(k0+vk1)*ND + vd1];
    __syncthreads();
    As[aq0+0][ai0]=av0.x; As[aq0+1][ai0]=av0.y; As[aq0+2][ai0]=av0.z; As[aq0+3][ai0]=av0.w;
    As[aq1+0][ai1]=av1.x; As[aq1+1][ai1]=av1.y; As[aq1+2][ai1]=av1.z; As[aq1+3][ai1]=av1.w;
    *(float4*)&Vs[vk0][vd0]=vv0;
    *(float4*)&Vs[vk1][vd1]=vv1;
    __syncthreads();
    #pragma unroll
    for(int kk=0;kk<32;kk++){
      float4 a = *(const float4*)&As[kk][ty4];
      float4 w = *(const float4*)&Vs[kk][tx4];
      FMA16(acc,a,w)
    }
  }
  u16* ob = o + ((size_t)b*NL + i0)*ND + h*NDK;
  #pragma unroll
  for(int i=0;i<4;i++){
    ushort4 hv = make_ushort4(f2b(acc[i][0]), f2b(acc[i][1]), f2b(acc[i][2]), f2b(acc[i][3]));
    *(ushort4*)&ob[(size_t)(ty4+i)*ND + tx4] = hv;
  }
}

// ---------------- depthwise conv1d, K=31, SAME (f32 in, bf16 out) ----------------
__global__ __launch_bounds__(256)
void k_dwconv(const float* __restrict__ in, const float* __restrict__ w,
              const float* __restrict__ bias, u16* __restrict__ out){
  int c  = blockIdx.x*256 + threadIdx.x;
  int t0 = blockIdx.y*4;
  int b  = blockIdx.z;
  const float* ib = in + (size_t)b*NT*ND + c;
  float win[34];
  #pragma unroll
  for(int r=0;r<34;r++){
    int t = t0 - 15 + r;
    win[r] = (t>=0 && t<NT) ? ib[(size_t)t*ND] : 0.0f;
  }
  float wg[31];
  #pragma unroll
  for(int kk=0;kk<31;kk++) wg[kk] = w[c*31+kk];
  float bs = bias[c];
  u16* ob = out + (size_t)b*NT*ND + c;
  #pragma unroll
  for(int oo=0;oo<4;oo++){
    float s = bs;
    #pragma unroll
    for(int kk=0;kk<31;kk++) s += win[oo+kk]*wg[kk];
    ob[(size_t)(t0+oo)*ND] = f2b(s);
  }
}

extern "C" void kernel_launch(void* const* d_in, const int* in_sizes, int n_in,
                              void* d_out, int out_size, void* d_ws, size_t ws_size,
                              hipStream_t stream) {
  const float* x      = (const float*)d_in[0];
  const float* pos    = (const float*)d_in[1];
  const float* mha_g  = (const float*)d_in[2];
  const float* mha_b  = (const float*)d_in[3];
  const float* wq     = (const float*)d_in[4];
  const float* bq     = (const float*)d_in[5];
  const float* wk     = (const float*)d_in[6];
  const float* bk     = (const float*)d_in[7];
  const float* wv     = (const float*)d_in[8];
  const float* bv     = (const float*)d_in[9];
  const float* wo     = (const float*)d_in[10];
  const float* bo     = (const float*)d_in[11];
  const float* ega_wg = (const float*)d_in[12];
  const float* ega_bg = (const float*)d_in[13];
  const float* g1_ln_g= (const float*)d_in[14];
  const float* g1_ln_b= (const float*)d_in[15];
  const float* g1_w1  = (const float*)d_in[16];   // [512, 3072]
  const float* g1_b1  = (const float*)d_in[17];   // [3072]
  const float* g1_w2  = (const float*)d_in[18];   // [1536, 512]
  const float* g1_b2  = (const float*)d_in[19];
  const float* g1_wg  = (const float*)d_in[20];
  const float* g1_bg  = (const float*)d_in[21];
  const float* cla_ln_g=(const float*)d_in[22];
  const float* cla_ln_b=(const float*)d_in[23];
  const float* cla_w1 = (const float*)d_in[24];   // [512, 1024]
  const float* cla_b1 = (const float*)d_in[25];
  const float* dw_w   = (const float*)d_in[26];
  const float* dw_b   = (const float*)d_in[27];
  const float* cla_w2 = (const float*)d_in[28];
  const float* cla_b2 = (const float*)d_in[29];
  const float* g2_ln_g= (const float*)d_in[30];
  const float* g2_ln_b= (const float*)d_in[31];
  const float* g2_w1  = (const float*)d_in[32];   // [512, 3072]
  const float* g2_b1  = (const float*)d_in[33];
  const float* g2_w2  = (const float*)d_in[34];   // [1536, 512]
  const float* g2_b2  = (const float*)d_in[35];
  const float* g2_wg  = (const float*)d_in[36];
  const float* g2_bg  = (const float*)d_in[37];

  float* xo = (float*)d_out;
  float* ws = (float*)d_ws;
  const size_t M1 = 1024*1024;

  // f32-unit workspace map
  float* SC    = ws;                       // 16M f32: scores; CLA: glu_f(0-8M)+conv_b(8-12M)+lnFb(12-16M)
  float* glu_f = SC;
  u16*  conv_b = (u16*)(SC + 8*M1);
  u16*  lnFb   = (u16*)(SC + 12*M1);
  u16*  xb1    = (u16*)(ws + 16*M1);       // bf16 stream copy A
  u16*  xb2    = (u16*)(ws + 20*M1);       // bf16 stream copy B
  u16*  WTb    = (u16*)(ws + 24*M1);       // transposed bf16 weights (7.34M u16 < 8M u16)
  float* s0    = ws + 28*M1;               // pooled f32 (2M)
  u16*  lnPb   = (u16*)(ws + 30*M1);       // pooled ln out bf16
  float* q     = ws + 31*M1;
  float* k     = ws + 33*M1;
  float* v     = ws + 35*M1;
  u16*  s5b    = (u16*)(ws + 37*M1);       // attn out bf16
  float* s6    = ws + 38*M1;               // up-branch f32 pooled (2M)
  u16*  glu_p  = (u16*)(ws + 40*M1);       // GCFN glu out bf16 [4096][1536] (3M f32)

  // transposed-weight sub-offsets (u16 units)
  u16* wqT   = WTb + 0;         // 512x512
  u16* wkT   = WTb + 262144;
  u16* wvT   = WTb + 524288;
  u16* woT   = WTb + 786432;
  u16* egaT  = WTb + 1048576;
  u16* g1w1T = WTb + 1310720;   // [3072][512] = 1572864
  u16* g1w2T = WTb + 2883584;   // [512][1536] = 786432
  u16* g1wgT = WTb + 3670016;   // 262144
  u16* claw1T= WTb + 3932160;   // [1024][512] = 524288
  u16* claw2T= WTb + 4456448;   // 262144
  u16* g2w1T = WTb + 4718592;   // 1572864
  u16* g2w2T = WTb + 6291456;   // 786432
  u16* g2wgT = WTb + 7077888;   // 262144 -> end 7340032

  const int rowsP = NB*NL;        // 4096
  const int rowsF = NB*NT;        // 16384
  const int n4P = rowsP*128, n4F = rowsF*128;
  dim3 blk(256);

  // ---- weight transposes ----
  k_wt<<<dim3(16,16), blk, 0, stream>>>(wq, wqT, 512, 512);
  k_wt<<<dim3(16,16), blk, 0, stream>>>(wk, wkT, 512, 512);
  k_wt<<<dim3(16,16), blk, 0, stream>>>(wv, wvT, 512, 512);
  k_wt<<<dim3(16,16), blk, 0, stream>>>(wo, woT, 512, 512);
  k_wt<<<dim3(16,16), blk, 0, stream>>>(ega_wg, egaT, 512, 512);
  k_wt<<<dim3(96,16), blk, 0, stream>>>(g1_w1, g1w1T, 512, 3072);   // Dh=1536 (d6=3072)
  k_wt<<<dim3(16,48), blk, 0, stream>>>(g1_w2, g1w2T, 1536, 512);
  k_wt<<<dim3(16,16), blk, 0, stream>>>(g1_wg, g1wgT, 512, 512);
  k_wt<<<dim3(32,16), blk, 0, stream>>>(cla_w1, claw1T, 512, 1024);
  k_wt<<<dim3(16,16), blk, 0, stream>>>(cla_w2, claw2T, 512, 512);
  k_wt<<<dim3(96,16), blk, 0, stream>>>(g2_w1, g2w1T, 512, 3072);
  k_wt<<<dim3(16,48), blk, 0, stream>>>(g2_w2, g2w2T, 1536, 512);
  k_wt<<<dim3(16,16), blk, 0, stream>>>(g2_wg, g2wgT, 512, 512);
  // bf16 copy of input stream (one float4 per thread)
  k_castb<<<(n4F+255)/256, blk, 0, stream>>>((const float4*)x, (ushort4*)xb1, n4F);

  // ================= EGA =================
  k_pool4<<<(n4P+255)/256, blk, 0, stream>>>((const float4*)x, (float4*)s0, n4P);
  k_ln<<<rowsP, 64, 0, stream>>>(s0, lnPb, mha_g, mha_b);
  k_gemm_mfma<0><<<dim3(4,32), blk, 0, stream>>>(lnPb, wqT, bq, nullptr,nullptr, q, nullptr, rowsP, ND, ND);
  k_gemm_mfma<0><<<dim3(4,32), blk, 0, stream>>>(lnPb, wkT, bk, nullptr,nullptr, k, nullptr, rowsP, ND, ND);
  k_gemm_mfma<0><<<dim3(4,32), blk, 0, stream>>>(lnPb, wvT, bv, nullptr,nullptr, v, nullptr, rowsP, ND, ND);
  k_qkt<<<dim3(8,8,64), blk, 0, stream>>>(q, k, SC);
  k_bm<<<dim3(8,512), blk, 0, stream>>>(q, pos, SC);
  k_softmax<<<NB*NH*NL, 64, 0, stream>>>(SC);
  k_pv<<<dim3(8,64), blk, 0, stream>>>(SC, v, s5b);
  k_gemm_mfma<0><<<dim3(4,32), blk, 0, stream>>>(s5b, woT, bo, nullptr,nullptr, s6, nullptr, rowsP, ND, ND);
  k_gemm_mfma<1><<<dim3(4,128), blk, 0, stream>>>(xb1, egaT, ega_bg, x, s6, xo, xb2, rowsF, ND, ND);

  // ================= GCFN global (g1), Dh=1536 =================
  k_pool4<<<(n4P+255)/256, blk, 0, stream>>>((const float4*)xo, (float4*)s0, n4P);
  k_ln<<<rowsP, 64, 0, stream>>>(s0, lnPb, g1_ln_g, g1_ln_b);
  k_glu_mfma<true><<<dim3(24,32), blk, 0, stream>>>(lnPb, g1w1T, g1_b1, nullptr, glu_p, rowsP, 1536, ND);
  k_gemm_mfma<0><<<dim3(4,32), blk, 0, stream>>>(glu_p, g1w2T, g1_b2, nullptr,nullptr, s6, nullptr, rowsP, ND, 1536);
  k_gemm_mfma<1><<<dim3(4,128), blk, 0, stream>>>(xb2, g1wgT, g1_bg, xo, s6, xo, nullptr, rowsF, ND, ND);

  // ================= CLA (Dh=512) =================
  k_ln<<<rowsF, 64, 0, stream>>>(xo, lnFb, cla_ln_g, cla_ln_b);
  k_glu_mfma<false><<<dim3(8,128), blk, 0, stream>>>(lnFb, claw1T, cla_b1, glu_f, nullptr, rowsF, 512, ND);
  k_dwconv<<<dim3(2, NT/4, NB), blk, 0, stream>>>(glu_f, dw_w, dw_b, conv_b);
  k_gemm_mfma<2><<<dim3(4,128), blk, 0, stream>>>(conv_b, claw2T, cla_b2, xo, nullptr, xo, xb2, rowsF, ND, ND);

  // ================= GCFN local (g2), Dh=1536 =================
  k_pool4<<<(n4P+255)/256, blk, 0, stream>>>((const float4*)xo, (float4*)s0, n4P);
  k_ln<<<rowsP, 64, 0, stream>>>(s0, lnPb, g2_ln_g, g2_ln_b);
  k_glu_mfma<true><<<dim3(24,32), blk, 0, stream>>>(lnPb, g2w1T, g2_b1, nullptr, glu_p, rowsP, 1536, ND);
  k_gemm_mfma<0><<<dim3(4,32), blk, 0, stream>>>(glu_p, g2w2T, g2_b2, nullptr,nullptr, s6, nullptr, rowsP, ND, 1536);
  k_gemm_mfma<1><<<dim3(4,128), blk, 0, stream>>>(xb2, g2wgT, g2_bg, xo, s6, xo, nullptr, rowsF, ND, ND);
}

// Round 6
// 625.423 us; speedup vs baseline: 3.0162x; 1.1171x over previous
//
#include <hip/hip_runtime.h>
#include <math.h>

#define NB 8
#define NT 2048
#define ND 512
#define NH 8
#define NDK 64
#define NL 512

typedef unsigned short u16;
typedef __attribute__((ext_vector_type(8))) short bf16x8;
typedef __attribute__((ext_vector_type(4))) float f32x4;

__device__ __forceinline__ float sigf(float v){ return 1.0f/(1.0f+__expf(-v)); }

__device__ __forceinline__ u16 f2b(float f){
  union{float f; unsigned u;} v; v.f = f;
  unsigned r = v.u + 0x7fffu + ((v.u>>16)&1u);
  return (u16)(r>>16);
}
__device__ __forceinline__ float b2f(u16 h){
  union{unsigned u; float f;} v; v.u = ((unsigned)h)<<16; return v.f;
}

#define GLOAD16(src, dst) \
  __builtin_amdgcn_global_load_lds((const __attribute__((address_space(1))) void*)(src), \
                                   (__attribute__((address_space(3))) void*)(dst), 16, 0, 0)

// ---------------- pool by 4 over time (f32 in) ----------------
__global__ void k_pool4(const float4* __restrict__ in, float4* __restrict__ out, int n4){
  int i = blockIdx.x*256 + threadIdx.x;
  if(i>=n4) return;
  int d4 = i & 127;
  size_t row = (size_t)(i>>7);
  const float4* p = in + row*512 + d4;
  float4 a=p[0], b=p[128], c=p[256], d=p[384];
  float4 r;
  r.x=(a.x+b.x+c.x+d.x)*0.25f; r.y=(a.y+b.y+c.y+d.y)*0.25f;
  r.z=(a.z+b.z+c.z+d.z)*0.25f; r.w=(a.w+b.w+c.w+d.w)*0.25f;
  out[i]=r;
}

// ---------------- pool by 4 over time (bf16 in, f32 out) ----------------
__global__ void k_pool4b(const u16* __restrict__ in, float4* __restrict__ out, int n4){
  int i = blockIdx.x*256 + threadIdx.x;
  if(i>=n4) return;
  int d4 = i & 127;
  size_t row = (size_t)(i>>7);
  const u16* p = in + row*4*512 + d4*4;
  float4 r = {0.f,0.f,0.f,0.f};
  #pragma unroll
  for(int rr=0;rr<4;rr++){
    ushort4 v = *(const ushort4*)&p[(size_t)rr*512];
    r.x += b2f(v.x); r.y += b2f(v.y); r.z += b2f(v.z); r.w += b2f(v.w);
  }
  r.x*=0.25f; r.y*=0.25f; r.z*=0.25f; r.w*=0.25f;
  out[i]=r;
}

// ---------------- row LayerNorm over D=512, f32 in -> bf16 out ----------------
__global__ void k_ln(const float* __restrict__ in, u16* __restrict__ outb,
                     const float* __restrict__ gam, const float* __restrict__ bet){
  size_t row = blockIdx.x;
  int lane = threadIdx.x;   // 64
  const float4* p = (const float4*)(in + row*ND);
  float4 v0=p[lane*2], v1=p[lane*2+1];
  float s  = v0.x+v0.y+v0.z+v0.w+v1.x+v1.y+v1.z+v1.w;
  float ss = v0.x*v0.x+v0.y*v0.y+v0.z*v0.z+v0.w*v0.w
           + v1.x*v1.x+v1.y*v1.y+v1.z*v1.z+v1.w*v1.w;
  #pragma unroll
  for(int o=32;o;o>>=1){ s+=__shfl_xor(s,o); ss+=__shfl_xor(ss,o); }
  float m  = s*(1.0f/ND);
  float rs = rsqrtf(ss*(1.0f/ND)-m*m+1e-5f);
  const float4* gp=(const float4*)gam; const float4* bp=(const float4*)bet;
  float4 g0=gp[lane*2],g1=gp[lane*2+1],b0=bp[lane*2],b1=bp[lane*2+1];
  float o0=(v0.x-m)*rs*g0.x+b0.x, o1=(v0.y-m)*rs*g0.y+b0.y;
  float o2=(v0.z-m)*rs*g0.z+b0.z, o3=(v0.w-m)*rs*g0.w+b0.w;
  float o4=(v1.x-m)*rs*g1.x+b1.x, o5=(v1.y-m)*rs*g1.y+b1.y;
  float o6=(v1.z-m)*rs*g1.z+b1.z, o7=(v1.w-m)*rs*g1.w+b1.w;
  uint4 pk;
  pk.x = (unsigned)f2b(o0) | ((unsigned)f2b(o1)<<16);
  pk.y = (unsigned)f2b(o2) | ((unsigned)f2b(o3)<<16);
  pk.z = (unsigned)f2b(o4) | ((unsigned)f2b(o5)<<16);
  pk.w = (unsigned)f2b(o6) | ((unsigned)f2b(o7)<<16);
  *(uint4*)&outb[row*ND + lane*8] = pk;
}

// ---------------- row LayerNorm, bf16 in -> bf16 out ----------------
__global__ void k_lnb(const u16* __restrict__ in, u16* __restrict__ outb,
                      const float* __restrict__ gam, const float* __restrict__ bet){
  size_t row = blockIdx.x;
  int lane = threadIdx.x;
  const u16* p = in + row*ND + lane*8;
  ushort4 a0 = *(const ushort4*)p;
  ushort4 a1 = *(const ushort4*)(p+4);
  float x0=b2f(a0.x),x1=b2f(a0.y),x2=b2f(a0.z),x3=b2f(a0.w);
  float x4=b2f(a1.x),x5=b2f(a1.y),x6=b2f(a1.z),x7=b2f(a1.w);
  float s  = x0+x1+x2+x3+x4+x5+x6+x7;
  float ss = x0*x0+x1*x1+x2*x2+x3*x3+x4*x4+x5*x5+x6*x6+x7*x7;
  #pragma unroll
  for(int o=32;o;o>>=1){ s+=__shfl_xor(s,o); ss+=__shfl_xor(ss,o); }
  float m  = s*(1.0f/ND);
  float rs = rsqrtf(ss*(1.0f/ND)-m*m+1e-5f);
  const float4* gp=(const float4*)gam; const float4* bp=(const float4*)bet;
  float4 g0=gp[lane*2],g1=gp[lane*2+1],b0=bp[lane*2],b1=bp[lane*2+1];
  float o0=(x0-m)*rs*g0.x+b0.x, o1=(x1-m)*rs*g0.y+b0.y;
  float o2=(x2-m)*rs*g0.z+b0.z, o3=(x3-m)*rs*g0.w+b0.w;
  float o4=(x4-m)*rs*g1.x+b1.x, o5=(x5-m)*rs*g1.y+b1.y;
  float o6=(x6-m)*rs*g1.z+b1.z, o7=(x7-m)*rs*g1.w+b1.w;
  uint4 pk;
  pk.x = (unsigned)f2b(o0) | ((unsigned)f2b(o1)<<16);
  pk.y = (unsigned)f2b(o2) | ((unsigned)f2b(o3)<<16);
  pk.z = (unsigned)f2b(o4) | ((unsigned)f2b(o5)<<16);
  pk.w = (unsigned)f2b(o6) | ((unsigned)f2b(o7)<<16);
  *(uint4*)&outb[row*ND + lane*8] = pk;
}

// ---------------- cast f32 -> bf16 ----------------
__global__ void k_castb(const float4* __restrict__ in, ushort4* __restrict__ out, int n4){
  int i = blockIdx.x*256 + threadIdx.x;
  if(i>=n4) return;
  float4 v = in[i];
  out[i] = make_ushort4(f2b(v.x), f2b(v.y), f2b(v.z), f2b(v.w));
}

// ---------------- weight transpose+cast: W[K][N] f32 -> WT[N][K] bf16 ----------------
__global__ __launch_bounds__(256)
void k_wt(const float* __restrict__ W, u16* __restrict__ WT, int K, int N){
  __shared__ float ls[32][33];
  int tid = threadIdx.x;
  int n0 = blockIdx.x*32, k0 = blockIdx.y*32;
  int tx = tid&31, ty = tid>>5;
  #pragma unroll
  for(int p=0;p<4;p++)
    ls[ty+p*8][tx] = W[(size_t)(k0+ty+p*8)*N + n0+tx];
  __syncthreads();
  #pragma unroll
  for(int p=0;p<4;p++)
    WT[(size_t)(n0+ty+p*8)*K + k0+tx] = f2b(ls[tx][ty+p*8]);
}

// =======================================================================
// MFMA GEMM: C[M,N] = A_bf16[M,K] @ (BT_bf16[N,K])^T  (+ epilogue)
// MI = m-frags per wave (4 -> BM=128, 2 -> BM=64). BN=128, BK=32, 4 waves 2x2.
// EPI: 0 = o = acc+bias
//      1 = gate: o = b2f(xinB) + sigmoid(acc+bias)*b2f(upB[row>>2])
//      2 = add:  o = b2f(xinB) + acc + bias
// outF written if non-null (f32), outB if non-null (bf16).
// XCD-aware block swizzle (grid size must be %8==0).
// =======================================================================
template<int EPI, int MI>
__global__ __launch_bounds__(256)
void k_gemm_mfma(const u16* __restrict__ A, const u16* __restrict__ BT,
                 const float* __restrict__ bias,
                 const u16* __restrict__ xinB, const u16* __restrict__ upB,
                 float* __restrict__ outF, u16* __restrict__ outB,
                 int M, int N, int K){
  constexpr int BM = MI*32;
  __shared__ short lA[BM*32];
  __shared__ short lB[128*32];
  int tid = threadIdx.x;
  int wv_ = tid>>6, ln_ = tid&63;
  int wy = wv_>>1, wx = wv_&1;
  int nx = gridDim.x;
  int flat = blockIdx.y*nx + blockIdx.x;
  int cpx = (nx*gridDim.y)>>3;
  int swz = (flat&7)*cpx + (flat>>3);
  int m0 = (swz/nx)*BM, n0 = (swz%nx)*128;

  f32x4 acc[MI][4];
  #pragma unroll
  for(int i=0;i<MI;i++)
    #pragma unroll
    for(int j=0;j<4;j++){ f32x4 z = {0.f,0.f,0.f,0.f}; acc[i][j]=z; }

  int fr = ln_&15, kg = ln_>>4;
  int aoff[MI], boff[4];
  #pragma unroll
  for(int i=0;i<MI;i++){
    int ar = wy*(MI*16) + i*16 + fr;
    aoff[i] = ar*64 + ((kg ^ ((ar>>1)&3))<<4);
  }
  #pragma unroll
  for(int j=0;j<4;j++){
    int br = wx*64 + j*16 + fr;
    boff[j] = br*64 + ((kg ^ ((br>>1)&3))<<4);
  }

  for(int k0=0;k0<K;k0+=32){
    #pragma unroll
    for(int q=0;q<BM/64;q++){
      int s = q*256 + tid;
      int row = s>>2;
      int gl = (s&3) ^ ((row>>1)&3);
      GLOAD16(A + (size_t)(m0+row)*K + k0 + gl*8, &lA[(q*4+wv_)*512]);
    }
    #pragma unroll
    for(int q=0;q<2;q++){
      int s = q*256 + tid;
      int row = s>>2;
      int gl = (s&3) ^ ((row>>1)&3);
      GLOAD16(BT + (size_t)(n0+row)*K + k0 + gl*8, &lB[(q*4+wv_)*512]);
    }
    __syncthreads();
    bf16x8 af[MI], bf[4];
    #pragma unroll
    for(int i=0;i<MI;i++) af[i] = *(const bf16x8*)((const char*)lA + aoff[i]);
    #pragma unroll
    for(int j=0;j<4;j++) bf[j] = *(const bf16x8*)((const char*)lB + boff[j]);
    #pragma unroll
    for(int i=0;i<MI;i++)
      #pragma unroll
      for(int j=0;j<4;j++)
        acc[i][j] = __builtin_amdgcn_mfma_f32_16x16x32_bf16(af[i], bf[j], acc[i][j], 0,0,0);
    __syncthreads();
  }

  int r0 = (ln_>>4)*4, c0 = ln_&15;
  #pragma unroll
  for(int i=0;i<MI;i++){
    #pragma unroll
    for(int j=0;j<4;j++){
      int gr = m0 + wy*(MI*16) + i*16 + r0;
      int gc = n0 + wx*64 + j*16 + c0;
      float bv = bias[gc];
      #pragma unroll
      for(int r=0;r<4;r++){
        float val = acc[i][j][r] + bv;
        size_t idx = (size_t)(gr+r)*N + gc;
        float o;
        if(EPI==0){
          o = val;
        } else if(EPI==1){
          o = b2f(xinB[idx]) + sigf(val)*b2f(upB[(size_t)((gr+r)>>2)*N + gc]);
        } else {
          o = b2f(xinB[idx]) + val;
        }
        if(outF) outF[idx] = o;
        if(outB) outB[idx] = f2b(o);
      }
    }
  }
}

// =======================================================================
// MFMA GLU GEMM: outB[M,Dh] = bf16( (A@Wa^T + ba) * sigmoid(A@Wb^T + bb) )
// WT is [2*Dh][K] bf16; BM=128, BN=64, BK=32. XCD swizzle.
// =======================================================================
__global__ __launch_bounds__(256)
void k_glu_mfma(const u16* __restrict__ A, const u16* __restrict__ WT,
                const float* __restrict__ bias, u16* __restrict__ outB,
                int M, int Dh, int K){
  __shared__ short lA [128*32];
  __shared__ short lBa[64*32];
  __shared__ short lBb[64*32];
  int tid = threadIdx.x;
  int wv_ = tid>>6, ln_ = tid&63;
  int wy = wv_>>1, wx = wv_&1;
  int nx = gridDim.x;
  int flat = blockIdx.y*nx + blockIdx.x;
  int cpx = (nx*gridDim.y)>>3;
  int swz = (flat&7)*cpx + (flat>>3);
  int m0 = (swz/nx)*128, n0 = (swz%nx)*64;

  f32x4 aca[4][2], acb[4][2];
  #pragma unroll
  for(int i=0;i<4;i++)
    #pragma unroll
    for(int j=0;j<2;j++){ f32x4 z={0.f,0.f,0.f,0.f}; aca[i][j]=z; acb[i][j]=z; }

  int fr = ln_&15, kg = ln_>>4;
  int aoff[4], boff[2];
  #pragma unroll
  for(int i=0;i<4;i++){
    int ar = wy*64 + i*16 + fr;
    aoff[i] = ar*64 + ((kg ^ ((ar>>1)&3))<<4);
  }
  #pragma unroll
  for(int j=0;j<2;j++){
    int br = wx*32 + j*16 + fr;
    boff[j] = br*64 + ((kg ^ ((br>>1)&3))<<4);
  }

  for(int k0=0;k0<K;k0+=32){
    #pragma unroll
    for(int q=0;q<2;q++){
      int s = q*256 + tid;
      int row = s>>2;
      int gl = (s&3) ^ ((row>>1)&3);
      GLOAD16(A + (size_t)(m0+row)*K + k0 + gl*8, &lA[(q*4+wv_)*512]);
    }
    {
      int s = tid;
      int row = s>>2;
      int gl = (s&3) ^ ((row>>1)&3);
      GLOAD16(WT + (size_t)(n0+row)*K      + k0 + gl*8, &lBa[wv_*512]);
      GLOAD16(WT + (size_t)(Dh+n0+row)*K   + k0 + gl*8, &lBb[wv_*512]);
    }
    __syncthreads();
    bf16x8 af[4], ba[2], bb[2];
    #pragma unroll
    for(int i=0;i<4;i++) af[i] = *(const bf16x8*)((const char*)lA + aoff[i]);
    #pragma unroll
    for(int j=0;j<2;j++){
      ba[j] = *(const bf16x8*)((const char*)lBa + boff[j]);
      bb[j] = *(const bf16x8*)((const char*)lBb + boff[j]);
    }
    #pragma unroll
    for(int i=0;i<4;i++)
      #pragma unroll
      for(int j=0;j<2;j++){
        aca[i][j] = __builtin_amdgcn_mfma_f32_16x16x32_bf16(af[i], ba[j], aca[i][j], 0,0,0);
        acb[i][j] = __builtin_amdgcn_mfma_f32_16x16x32_bf16(af[i], bb[j], acb[i][j], 0,0,0);
      }
    __syncthreads();
  }

  int r0 = (ln_>>4)*4, c0 = ln_&15;
  #pragma unroll
  for(int i=0;i<4;i++){
    #pragma unroll
    for(int j=0;j<2;j++){
      int gr = m0 + wy*64 + i*16 + r0;
      int gc = n0 + wx*32 + j*16 + c0;
      float bva = bias[gc], bvb = bias[Dh+gc];
      #pragma unroll
      for(int r=0;r<4;r++){
        float o = (aca[i][j][r]+bva) * sigf(acb[i][j][r]+bvb);
        outB[(size_t)(gr+r)*Dh + gc] = f2b(o);
      }
    }
  }
}

#define FMA16(acc,va,vb) \
  acc[0][0]+=va.x*vb.x; acc[0][1]+=va.x*vb.y; acc[0][2]+=va.x*vb.z; acc[0][3]+=va.x*vb.w; \
  acc[1][0]+=va.y*vb.x; acc[1][1]+=va.y*vb.y; acc[1][2]+=va.y*vb.z; acc[1][3]+=va.y*vb.w; \
  acc[2][0]+=va.z*vb.x; acc[2][1]+=va.z*vb.y; acc[2][2]+=va.z*vb.z; acc[2][3]+=va.z*vb.w; \
  acc[3][0]+=va.w*vb.x; acc[3][1]+=va.w*vb.y; acc[3][2]+=va.w*vb.z; acc[3][3]+=va.w*vb.w;

// ---------------- attention: scores = q.k^T (fp32) ----------------
__global__ __launch_bounds__(256)
void k_qkt(const float* __restrict__ q, const float* __restrict__ k,
           float* __restrict__ scores){
  int z = blockIdx.z, b = z>>3, h = z&7;
  int i0 = blockIdx.y*64, j0 = blockIdx.x*64;
  __shared__ float Qs[64][64];
  __shared__ float Ks[64][64];
  int tid = threadIdx.x;
  const float* qb = q + ((size_t)b*NL + i0)*ND + h*NDK;
  const float* kb = k + ((size_t)b*NL + j0)*ND + h*NDK;
  #pragma unroll
  for(int r=0;r<4;r++){
    int f4 = tid + r*256;
    int row = f4>>4, dq = (f4&15)*4;
    float4 qa = *(const float4*)&qb[(size_t)row*ND + dq];
    float4 ka = *(const float4*)&kb[(size_t)row*ND + dq];
    Qs[dq+0][row]=qa.x; Qs[dq+1][row]=qa.y; Qs[dq+2][row]=qa.z; Qs[dq+3][row]=qa.w;
    Ks[dq+0][row]=ka.x; Ks[dq+1][row]=ka.y; Ks[dq+2][row]=ka.z; Ks[dq+3][row]=ka.w;
  }
  __syncthreads();
  int tx4 = (tid&15)*4, ty4 = (tid>>4)*4;
  float acc[4][4]={};
  #pragma unroll 8
  for(int d=0; d<64; d++){
    float4 a = *(const float4*)&Qs[d][ty4];
    float4 w = *(const float4*)&Ks[d][tx4];
    FMA16(acc,a,w)
  }
  float* sb = scores + (size_t)z*NL*NL;
  #pragma unroll
  for(int i=0;i<4;i++){
    float4 o; o.x=acc[i][0]; o.y=acc[i][1]; o.z=acc[i][2]; o.w=acc[i][3];
    *(float4*)&sb[(size_t)(i0+ty4+i)*NL + j0 + tx4] = o;
  }
}

// =======================================================================
// Fused Bm + softmax: for block i, P[bh][i][j] over all 64 bh, 512 j.
// S = (A[bh][i][j] + q_i[bh][:].pos[i][j][:]) / 8 ; P = softmax_j(S) in bf16.
// pos[i] staged as f32 [512][64] with d-XOR swizzle (128 KB LDS).
// =======================================================================
__global__ __launch_bounds__(512)
void k_bmsm(const float* __restrict__ A, const float* __restrict__ q,
            const float* __restrict__ pos, u16* __restrict__ P){
  int i = blockIdx.x;
  __shared__ float Ps[512][64];   // 128 KB
  __shared__ float Qs[64][64];    // 16 KB
  int tid = threadIdx.x;
  const float4* pp = (const float4*)(pos + (size_t)i*NL*NDK);
  #pragma unroll
  for(int t0=0;t0<16;t0++){
    int t = t0*512 + tid;
    int j = t>>4, d4 = (t&15)*4;
    int dsw = d4 ^ (((j>>4)&15)<<2);
    *(float4*)&Ps[j][dsw] = pp[t];
  }
  #pragma unroll
  for(int t0=0;t0<2;t0++){
    int t = t0*512 + tid;
    int bh = t>>4, dq = (t&15)*4;
    *(float4*)&Qs[bh][dq] = *(const float4*)&q[((size_t)(bh>>3)*NL + i)*ND + (bh&7)*NDK + dq];
  }
  __syncthreads();
  int jg = tid&31, rg = tid>>5;
  int j0 = jg*16, r0 = rg*4;
  int myx = (jg&15)<<2;
  float acc[4][16];
  #pragma unroll
  for(int r=0;r<4;r++){
    const float* arow = A + ((size_t)(r0+r)*NL + i)*NL + j0;
    #pragma unroll
    for(int c4=0;c4<4;c4++){
      float4 av = *(const float4*)&arow[c4*4];
      acc[r][c4*4+0]=av.x; acc[r][c4*4+1]=av.y; acc[r][c4*4+2]=av.z; acc[r][c4*4+3]=av.w;
    }
  }
  for(int d=0; d<64; d+=4){
    float4 q0 = *(const float4*)&Qs[r0+0][d];
    float4 q1 = *(const float4*)&Qs[r0+1][d];
    float4 q2 = *(const float4*)&Qs[r0+2][d];
    float4 q3 = *(const float4*)&Qs[r0+3][d];
    #pragma unroll
    for(int c=0;c<16;c++){
      float4 pv = *(const float4*)&Ps[j0+c][d ^ myx];
      acc[0][c] += q0.x*pv.x + q0.y*pv.y + q0.z*pv.z + q0.w*pv.w;
      acc[1][c] += q1.x*pv.x + q1.y*pv.y + q1.z*pv.z + q1.w*pv.w;
      acc[2][c] += q2.x*pv.x + q2.y*pv.y + q2.z*pv.z + q2.w*pv.w;
      acc[3][c] += q3.x*pv.x + q3.y*pv.y + q3.z*pv.z + q3.w*pv.w;
    }
  }
  #pragma unroll
  for(int r=0;r<4;r++){
    float mx = -3e38f;
    #pragma unroll
    for(int c=0;c<16;c++){ acc[r][c] *= 0.125f; mx = fmaxf(mx, acc[r][c]); }
    #pragma unroll
    for(int o=16;o;o>>=1) mx = fmaxf(mx, __shfl_xor(mx, o));
    float sm = 0.f;
    #pragma unroll
    for(int c=0;c<16;c++){ acc[r][c] = __expf(acc[r][c]-mx); sm += acc[r][c]; }
    #pragma unroll
    for(int o=16;o;o>>=1) sm += __shfl_xor(sm, o);
    float inv = 1.0f/sm;
    u16 tmp[16];
    #pragma unroll
    for(int c=0;c<16;c++) tmp[c] = f2b(acc[r][c]*inv);
    u16* prow = P + ((size_t)(r0+r)*NL + i)*NL + j0;
    *(uint4*)&prow[0] = *(uint4*)&tmp[0];
    *(uint4*)&prow[8] = *(uint4*)&tmp[8];
  }
}

// ---------------- o = P(bf16) @ v(f32) -> bf16 out ----------------
__global__ __launch_bounds__(256)
void k_pv(const u16* __restrict__ attn, const float* __restrict__ v,
          u16* __restrict__ o){
  int z = blockIdx.y, b = z>>3, h = z&7;
  int i0 = blockIdx.x*64;
  __shared__ float As[32][64];
  __shared__ float Vs[32][64];
  const u16* ab = attn + ((size_t)z*NL + i0)*NL;
  const float* vb = v + (size_t)b*NL*ND + h*NDK;
  int tid = threadIdx.x;
  int tx4 = (tid&15)*4, ty4 = (tid>>4)*4;
  float acc[4][4]={};
  for(int k0=0;k0<NL;k0+=32){
    int f40 = tid,     f41 = tid+256;
    int ai0 = f40>>3,  aq0 = (f40&7)*4;
    int ai1 = f41>>3,  aq1 = (f41&7)*4;
    int vk0 = f40>>4,  vd0 = (f40&15)*4;
    int vk1 = f41>>4,  vd1 = (f41&15)*4;
    ushort4 av0 = *(const ushort4*)&ab[(size_t)ai0*NL + k0 + aq0];
    ushort4 av1 = *(const ushort4*)&ab[(size_t)ai1*NL + k0 + aq1];
    float4 vv0 = *(const float4*)&vb[(size_t)(k0+vk0)*ND + vd0];
    float4 vv1 = *(const float4*)&vb[(size_t)(k0+vk1)*ND + vd1];
    __syncthreads();
    As[aq0+0][ai0]=b2f(av0.x); As[aq0+1][ai0]=b2f(av0.y); As[aq0+2][ai0]=b2f(av0.z); As[aq0+3][ai0]=b2f(av0.w);
    As[aq1+0][ai1]=b2f(av1.x); As[aq1+1][ai1]=b2f(av1.y); As[aq1+2][ai1]=b2f(av1.z); As[aq1+3][ai1]=b2f(av1.w);
    *(float4*)&Vs[vk0][vd0]=vv0;
    *(float4*)&Vs[vk1][vd1]=vv1;
    __syncthreads();
    #pragma unroll
    for(int kk=0;kk<32;kk++){
      float4 a = *(const float4*)&As[kk][ty4];
      float4 w = *(const float4*)&Vs[kk][tx4];
      FMA16(acc,a,w)
    }
  }
  u16* ob = o + ((size_t)b*NL + i0)*ND + h*NDK;
  #pragma unroll
  for(int i=0;i<4;i++){
    ushort4 hv = make_ushort4(f2b(acc[i][0]), f2b(acc[i][1]), f2b(acc[i][2]), f2b(acc[i][3]));
    *(ushort4*)&ob[(size_t)(ty4+i)*ND + tx4] = hv;
  }
}

// ---------------- depthwise conv1d, K=31, SAME (bf16 in, bf16 out) ----------------
__global__ __launch_bounds__(256)
void k_dwconv(const u16* __restrict__ in, const float* __restrict__ w,
              const float* __restrict__ bias, u16* __restrict__ out){
  int c  = blockIdx.x*256 + threadIdx.x;
  int t0 = blockIdx.y*4;
  int b  = blockIdx.z;
  const u16* ib = in + (size_t)b*NT*ND + c;
  float win[34];
  #pragma unroll
  for(int r=0;r<34;r++){
    int t = t0 - 15 + r;
    win[r] = (t>=0 && t<NT) ? b2f(ib[(size_t)t*ND]) : 0.0f;
  }
  float wg[31];
  #pragma unroll
  for(int kk=0;kk<31;kk++) wg[kk] = w[c*31+kk];
  float bs = bias[c];
  u16* ob = out + (size_t)b*NT*ND + c;
  #pragma unroll
  for(int oo=0;oo<4;oo++){
    float s = bs;
    #pragma unroll
    for(int kk=0;kk<31;kk++) s += win[oo+kk]*wg[kk];
    ob[(size_t)(t0+oo)*ND] = f2b(s);
  }
}

extern "C" void kernel_launch(void* const* d_in, const int* in_sizes, int n_in,
                              void* d_out, int out_size, void* d_ws, size_t ws_size,
                              hipStream_t stream) {
  const float* x      = (const float*)d_in[0];
  const float* pos    = (const float*)d_in[1];
  const float* mha_g  = (const float*)d_in[2];
  const float* mha_b  = (const float*)d_in[3];
  const float* wq     = (const float*)d_in[4];
  const float* bq     = (const float*)d_in[5];
  const float* wk     = (const float*)d_in[6];
  const float* bk     = (const float*)d_in[7];
  const float* wv     = (const float*)d_in[8];
  const float* bv     = (const float*)d_in[9];
  const float* wo     = (const float*)d_in[10];
  const float* bo     = (const float*)d_in[11];
  const float* ega_wg = (const float*)d_in[12];
  const float* ega_bg = (const float*)d_in[13];
  const float* g1_ln_g= (const float*)d_in[14];
  const float* g1_ln_b= (const float*)d_in[15];
  const float* g1_w1  = (const float*)d_in[16];   // [512,3072]
  const float* g1_b1  = (const float*)d_in[17];
  const float* g1_w2  = (const float*)d_in[18];   // [1536,512]
  const float* g1_b2  = (const float*)d_in[19];
  const float* g1_wg  = (const float*)d_in[20];
  const float* g1_bg  = (const float*)d_in[21];
  const float* cla_ln_g=(const float*)d_in[22];
  const float* cla_ln_b=(const float*)d_in[23];
  const float* cla_w1 = (const float*)d_in[24];   // [512,1024]
  const float* cla_b1 = (const float*)d_in[25];
  const float* dw_w   = (const float*)d_in[26];
  const float* dw_b   = (const float*)d_in[27];
  const float* cla_w2 = (const float*)d_in[28];
  const float* cla_b2 = (const float*)d_in[29];
  const float* g2_ln_g= (const float*)d_in[30];
  const float* g2_ln_b= (const float*)d_in[31];
  const float* g2_w1  = (const float*)d_in[32];
  const float* g2_b1  = (const float*)d_in[33];
  const float* g2_w2  = (const float*)d_in[34];
  const float* g2_b2  = (const float*)d_in[35];
  const float* g2_wg  = (const float*)d_in[36];
  const float* g2_bg  = (const float*)d_in[37];

  float* xo = (float*)d_out;
  float* ws = (float*)d_ws;
  const size_t M1 = 1024*1024;

  // workspace map (f32 units); region [0,16M) is time-multiplexed:
  float* SC    = ws;                       // scores f32 (attn phase)
  u16*  s5b    = (u16*)ws;                 // [0,1)   attn out bf16 (post-bmsm)
  u16*  glu_p  = (u16*)ws;                 // [0,6)   g1/g2 GLU out [4096][1536]
  u16*  glu_b  = (u16*)ws;                 // [0,4)   CLA GLU out [16384][512]
  u16*  conv_b = (u16*)(ws + 4*M1);        // [4,8)   CLA conv out
  u16*  s6b    = (u16*)(ws + 6*M1);        // [6,7)   'up' bf16 [4096][512]
  u16*  lnPb   = (u16*)(ws + 7*M1);        // [7,8)   pooled ln bf16
  u16*  lnFb   = (u16*)(ws + 8*M1);        // [8,12)  CLA ln bf16
  u16*  Pb     = (u16*)(ws + 16*M1);       // [16,24) attn probs bf16
  u16*  xbA    = (u16*)(ws + 24*M1);       // [24,28) stream ping
  u16*  xbB    = (u16*)(ws + 28*M1);       // [28,32) stream pong
  u16*  WTb    = (u16*)(ws + 32*M1);       // [32,36) bf16 weights
  float* s0    = ws + 36*M1;               // [36,38) pooled f32
  float* q     = ws + 38*M1;               // [38,40)
  float* k     = ws + 40*M1;               // [40,42)
  float* v     = ws + 42*M1;               // [42,44)

  u16* wqT   = WTb + 0;
  u16* wkT   = WTb + 262144;
  u16* wvT   = WTb + 524288;
  u16* woT   = WTb + 786432;
  u16* egaT  = WTb + 1048576;
  u16* g1w1T = WTb + 1310720;   // [3072][512]
  u16* g1w2T = WTb + 2883584;   // [512][1536]
  u16* g1wgT = WTb + 3670016;
  u16* claw1T= WTb + 3932160;   // [1024][512]
  u16* claw2T= WTb + 4456448;
  u16* g2w1T = WTb + 4718592;
  u16* g2w2T = WTb + 6291456;
  u16* g2wgT = WTb + 7077888;

  const int rowsP = NB*NL;        // 4096
  const int rowsF = NB*NT;        // 16384
  const int n4P = rowsP*128, n4F = rowsF*128;
  dim3 blk(256);
  dim3 gPool(4,64);               // pooled GEMM: BM=64 -> 256 blocks
  dim3 gFull(4,128);              // full-T GEMM: BM=128 -> 512 blocks

  // ---- weight prep ----
  k_wt<<<dim3(16,16), blk, 0, stream>>>(wq, wqT, 512, 512);
  k_wt<<<dim3(16,16), blk, 0, stream>>>(wk, wkT, 512, 512);
  k_wt<<<dim3(16,16), blk, 0, stream>>>(wv, wvT, 512, 512);
  k_wt<<<dim3(16,16), blk, 0, stream>>>(wo, woT, 512, 512);
  k_wt<<<dim3(16,16), blk, 0, stream>>>(ega_wg, egaT, 512, 512);
  k_wt<<<dim3(96,16), blk, 0, stream>>>(g1_w1, g1w1T, 512, 3072);
  k_wt<<<dim3(16,48), blk, 0, stream>>>(g1_w2, g1w2T, 1536, 512);
  k_wt<<<dim3(16,16), blk, 0, stream>>>(g1_wg, g1wgT, 512, 512);
  k_wt<<<dim3(32,16), blk, 0, stream>>>(cla_w1, claw1T, 512, 1024);
  k_wt<<<dim3(16,16), blk, 0, stream>>>(cla_w2, claw2T, 512, 512);
  k_wt<<<dim3(96,16), blk, 0, stream>>>(g2_w1, g2w1T, 512, 3072);
  k_wt<<<dim3(16,48), blk, 0, stream>>>(g2_w2, g2w2T, 1536, 512);
  k_wt<<<dim3(16,16), blk, 0, stream>>>(g2_wg, g2wgT, 512, 512);
  k_castb<<<(n4F+255)/256, blk, 0, stream>>>((const float4*)x, (ushort4*)xbA, n4F);

  // ================= EGA =================
  k_pool4<<<(n4P+255)/256, blk, 0, stream>>>((const float4*)x, (float4*)s0, n4P);
  k_ln<<<rowsP, 64, 0, stream>>>(s0, lnPb, mha_g, mha_b);
  k_gemm_mfma<0,2><<<gPool, blk, 0, stream>>>(lnPb, wqT, bq, nullptr,nullptr, q, nullptr, rowsP, ND, ND);
  k_gemm_mfma<0,2><<<gPool, blk, 0, stream>>>(lnPb, wkT, bk, nullptr,nullptr, k, nullptr, rowsP, ND, ND);
  k_gemm_mfma<0,2><<<gPool, blk, 0, stream>>>(lnPb, wvT, bv, nullptr,nullptr, v, nullptr, rowsP, ND, ND);
  k_qkt<<<dim3(8,8,64), blk, 0, stream>>>(q, k, SC);
  k_bmsm<<<512, 512, 0, stream>>>(SC, q, pos, Pb);
  k_pv<<<dim3(8,64), blk, 0, stream>>>(Pb, v, s5b);
  k_gemm_mfma<0,2><<<gPool, blk, 0, stream>>>(s5b, woT, bo, nullptr,nullptr, nullptr, s6b, rowsP, ND, ND);
  // gate: stream' = x + sig(x@wg+b)*up  (bf16 in/out)
  k_gemm_mfma<1,4><<<gFull, blk, 0, stream>>>(xbA, egaT, ega_bg, xbA, s6b, nullptr, xbB, rowsF, ND, ND);

  // ================= GCFN global (g1) =================
  k_pool4b<<<(n4P+255)/256, blk, 0, stream>>>(xbB, (float4*)s0, n4P);
  k_ln<<<rowsP, 64, 0, stream>>>(s0, lnPb, g1_ln_g, g1_ln_b);
  k_glu_mfma<<<dim3(24,32), blk, 0, stream>>>(lnPb, g1w1T, g1_b1, glu_p, rowsP, 1536, ND);
  k_gemm_mfma<0,2><<<gPool, blk, 0, stream>>>(glu_p, g1w2T, g1_b2, nullptr,nullptr, nullptr, s6b, rowsP, ND, 1536);
  k_gemm_mfma<1,4><<<gFull, blk, 0, stream>>>(xbB, g1wgT, g1_bg, xbB, s6b, nullptr, xbA, rowsF, ND, ND);

  // ================= CLA =================
  k_lnb<<<rowsF, 64, 0, stream>>>(xbA, lnFb, cla_ln_g, cla_ln_b);
  k_glu_mfma<<<dim3(8,128), blk, 0, stream>>>(lnFb, claw1T, cla_b1, glu_b, rowsF, 512, ND);
  k_dwconv<<<dim3(2, NT/4, NB), blk, 0, stream>>>(glu_b, dw_w, dw_b, conv_b);
  k_gemm_mfma<2,4><<<gFull, blk, 0, stream>>>(conv_b, claw2T, cla_b2, xbA, nullptr, nullptr, xbB, rowsF, ND, ND);

  // ================= GCFN local (g2) =================
  k_pool4b<<<(n4P+255)/256, blk, 0, stream>>>(xbB, (float4*)s0, n4P);
  k_ln<<<rowsP, 64, 0, stream>>>(s0, lnPb, g2_ln_g, g2_ln_b);
  k_glu_mfma<<<dim3(24,32), blk, 0, stream>>>(lnPb, g2w1T, g2_b1, glu_p, rowsP, 1536, ND);
  k_gemm_mfma<0,2><<<gPool, blk, 0, stream>>>(glu_p, g2w2T, g2_b2, nullptr,nullptr, nullptr, s6b, rowsP, ND, 1536);
  // final gate writes f32 output
  k_gemm_mfma<1,4><<<gFull, blk, 0, stream>>>(xbB, g2wgT, g2_bg, xbB, s6b, xo, nullptr, rowsF, ND, ND);
}

// Round 7
// 580.420 us; speedup vs baseline: 3.2500x; 1.0775x over previous
//
#include <hip/hip_runtime.h>
#include <math.h>

#define NB 8
#define NT 2048
#define ND 512
#define NH 8
#define NDK 64
#define NL 512

typedef unsigned short u16;
typedef __attribute__((ext_vector_type(8))) short bf16x8;
typedef __attribute__((ext_vector_type(4))) float f32x4;

__device__ __forceinline__ float sigf(float v){ return 1.0f/(1.0f+__expf(-v)); }

__device__ __forceinline__ u16 f2b(float f){
  union{float f; unsigned u;} v; v.f = f;
  unsigned r = v.u + 0x7fffu + ((v.u>>16)&1u);
  return (u16)(r>>16);
}
__device__ __forceinline__ float b2f(u16 h){
  union{unsigned u; float f;} v; v.u = ((unsigned)h)<<16; return v.f;
}

#define GLOAD16(src, dst) \
  __builtin_amdgcn_global_load_lds((const __attribute__((address_space(1))) void*)(src), \
                                   (__attribute__((address_space(3))) void*)(dst), 16, 0, 0)

// ---------------- fused pool4 + LayerNorm, f32 in -> bf16 out ----------------
// one wave per pooled row
__global__ void k_poollnf(const float* __restrict__ in, u16* __restrict__ outb,
                          const float* __restrict__ gam, const float* __restrict__ bet){
  size_t prow = blockIdx.x;
  int lane = threadIdx.x;   // 64
  const float* p = in + prow*4*ND + lane*8;
  float x[8] = {0,0,0,0,0,0,0,0};
  #pragma unroll
  for(int rr=0;rr<4;rr++){
    float4 a = *(const float4*)&p[(size_t)rr*ND];
    float4 b = *(const float4*)&p[(size_t)rr*ND+4];
    x[0]+=a.x; x[1]+=a.y; x[2]+=a.z; x[3]+=a.w;
    x[4]+=b.x; x[5]+=b.y; x[6]+=b.z; x[7]+=b.w;
  }
  #pragma unroll
  for(int e=0;e<8;e++) x[e]*=0.25f;
  float s=0.f, ss=0.f;
  #pragma unroll
  for(int e=0;e<8;e++){ s+=x[e]; ss+=x[e]*x[e]; }
  #pragma unroll
  for(int o=32;o;o>>=1){ s+=__shfl_xor(s,o); ss+=__shfl_xor(ss,o); }
  float m  = s*(1.0f/ND);
  float rs = rsqrtf(ss*(1.0f/ND)-m*m+1e-5f);
  const float4* gp=(const float4*)gam; const float4* bp=(const float4*)bet;
  float4 g0=gp[lane*2],g1=gp[lane*2+1],b0=bp[lane*2],b1=bp[lane*2+1];
  float o0=(x[0]-m)*rs*g0.x+b0.x, o1=(x[1]-m)*rs*g0.y+b0.y;
  float o2=(x[2]-m)*rs*g0.z+b0.z, o3=(x[3]-m)*rs*g0.w+b0.w;
  float o4=(x[4]-m)*rs*g1.x+b1.x, o5=(x[5]-m)*rs*g1.y+b1.y;
  float o6=(x[6]-m)*rs*g1.z+b1.z, o7=(x[7]-m)*rs*g1.w+b1.w;
  uint4 pk;
  pk.x = (unsigned)f2b(o0) | ((unsigned)f2b(o1)<<16);
  pk.y = (unsigned)f2b(o2) | ((unsigned)f2b(o3)<<16);
  pk.z = (unsigned)f2b(o4) | ((unsigned)f2b(o5)<<16);
  pk.w = (unsigned)f2b(o6) | ((unsigned)f2b(o7)<<16);
  *(uint4*)&outb[prow*ND + lane*8] = pk;
}

// ---------------- fused pool4 + LayerNorm, bf16 in -> bf16 out ----------------
__global__ void k_poollnb(const u16* __restrict__ in, u16* __restrict__ outb,
                          const float* __restrict__ gam, const float* __restrict__ bet){
  size_t prow = blockIdx.x;
  int lane = threadIdx.x;
  const u16* p = in + prow*4*ND + lane*8;
  float x[8] = {0,0,0,0,0,0,0,0};
  #pragma unroll
  for(int rr=0;rr<4;rr++){
    ushort4 a = *(const ushort4*)&p[(size_t)rr*ND];
    ushort4 b = *(const ushort4*)&p[(size_t)rr*ND+4];
    x[0]+=b2f(a.x); x[1]+=b2f(a.y); x[2]+=b2f(a.z); x[3]+=b2f(a.w);
    x[4]+=b2f(b.x); x[5]+=b2f(b.y); x[6]+=b2f(b.z); x[7]+=b2f(b.w);
  }
  #pragma unroll
  for(int e=0;e<8;e++) x[e]*=0.25f;
  float s=0.f, ss=0.f;
  #pragma unroll
  for(int e=0;e<8;e++){ s+=x[e]; ss+=x[e]*x[e]; }
  #pragma unroll
  for(int o=32;o;o>>=1){ s+=__shfl_xor(s,o); ss+=__shfl_xor(ss,o); }
  float m  = s*(1.0f/ND);
  float rs = rsqrtf(ss*(1.0f/ND)-m*m+1e-5f);
  const float4* gp=(const float4*)gam; const float4* bp=(const float4*)bet;
  float4 g0=gp[lane*2],g1=gp[lane*2+1],b0=bp[lane*2],b1=bp[lane*2+1];
  float o0=(x[0]-m)*rs*g0.x+b0.x, o1=(x[1]-m)*rs*g0.y+b0.y;
  float o2=(x[2]-m)*rs*g0.z+b0.z, o3=(x[3]-m)*rs*g0.w+b0.w;
  float o4=(x[4]-m)*rs*g1.x+b1.x, o5=(x[5]-m)*rs*g1.y+b1.y;
  float o6=(x[6]-m)*rs*g1.z+b1.z, o7=(x[7]-m)*rs*g1.w+b1.w;
  uint4 pk;
  pk.x = (unsigned)f2b(o0) | ((unsigned)f2b(o1)<<16);
  pk.y = (unsigned)f2b(o2) | ((unsigned)f2b(o3)<<16);
  pk.z = (unsigned)f2b(o4) | ((unsigned)f2b(o5)<<16);
  pk.w = (unsigned)f2b(o6) | ((unsigned)f2b(o7)<<16);
  *(uint4*)&outb[prow*ND + lane*8] = pk;
}

// ---------------- row LayerNorm, bf16 in -> bf16 out, 4 rows/block ----------------
__global__ __launch_bounds__(256)
void k_lnb4(const u16* __restrict__ in, u16* __restrict__ outb,
            const float* __restrict__ gam, const float* __restrict__ bet){
  size_t row = (size_t)blockIdx.x*4 + (threadIdx.x>>6);
  int lane = threadIdx.x & 63;
  const u16* p = in + row*ND + lane*8;
  ushort4 a0 = *(const ushort4*)p;
  ushort4 a1 = *(const ushort4*)(p+4);
  float x0=b2f(a0.x),x1=b2f(a0.y),x2=b2f(a0.z),x3=b2f(a0.w);
  float x4=b2f(a1.x),x5=b2f(a1.y),x6=b2f(a1.z),x7=b2f(a1.w);
  float s  = x0+x1+x2+x3+x4+x5+x6+x7;
  float ss = x0*x0+x1*x1+x2*x2+x3*x3+x4*x4+x5*x5+x6*x6+x7*x7;
  #pragma unroll
  for(int o=32;o;o>>=1){ s+=__shfl_xor(s,o); ss+=__shfl_xor(ss,o); }
  float m  = s*(1.0f/ND);
  float rs = rsqrtf(ss*(1.0f/ND)-m*m+1e-5f);
  const float4* gp=(const float4*)gam; const float4* bp=(const float4*)bet;
  float4 g0=gp[lane*2],g1=gp[lane*2+1],b0=bp[lane*2],b1=bp[lane*2+1];
  float o0=(x0-m)*rs*g0.x+b0.x, o1=(x1-m)*rs*g0.y+b0.y;
  float o2=(x2-m)*rs*g0.z+b0.z, o3=(x3-m)*rs*g0.w+b0.w;
  float o4=(x4-m)*rs*g1.x+b1.x, o5=(x5-m)*rs*g1.y+b1.y;
  float o6=(x6-m)*rs*g1.z+b1.z, o7=(x7-m)*rs*g1.w+b1.w;
  uint4 pk;
  pk.x = (unsigned)f2b(o0) | ((unsigned)f2b(o1)<<16);
  pk.y = (unsigned)f2b(o2) | ((unsigned)f2b(o3)<<16);
  pk.z = (unsigned)f2b(o4) | ((unsigned)f2b(o5)<<16);
  pk.w = (unsigned)f2b(o6) | ((unsigned)f2b(o7)<<16);
  *(uint4*)&outb[row*ND + lane*8] = pk;
}

// ---------------- cast f32 -> bf16 ----------------
__global__ void k_castb(const float4* __restrict__ in, ushort4* __restrict__ out, int n4){
  int i = blockIdx.x*256 + threadIdx.x;
  if(i>=n4) return;
  float4 v = in[i];
  out[i] = make_ushort4(f2b(v.x), f2b(v.y), f2b(v.z), f2b(v.w));
}

// ---------------- merged weight transpose+cast: 13 jobs, one launch ----------------
struct WtJobs {
  const float* W[13];
  u16* WT[13];
  int K[13], N[13];
  int off[14];
};
__global__ __launch_bounds__(256)
void k_wt_all(WtJobs jobs){
  __shared__ float ls[32][33];
  int bid = blockIdx.x;
  int ji = 0;
  #pragma unroll
  for(int t=0;t<12;t++) if(bid >= jobs.off[t+1]) ji = t+1;
  int local = bid - jobs.off[ji];
  const float* W = jobs.W[ji];
  u16* WT = jobs.WT[ji];
  int K = jobs.K[ji], N = jobs.N[ji];
  int tn = N>>5;
  int n0 = (local % tn)*32, k0 = (local / tn)*32;
  int tid = threadIdx.x;
  int tx = tid&31, ty = tid>>5;
  #pragma unroll
  for(int p=0;p<4;p++)
    ls[ty+p*8][tx] = W[(size_t)(k0+ty+p*8)*N + n0+tx];
  __syncthreads();
  #pragma unroll
  for(int p=0;p<4;p++)
    WT[(size_t)(n0+ty+p*8)*K + k0+tx] = f2b(ls[tx][ty+p*8]);
}

// =======================================================================
// MFMA GEMM: C[M,N] = A_bf16[M,K] @ (BT_bf16[N,K])^T  (+ epilogue)
// MI = m-frags per wave (4 -> BM=128, 2 -> BM=64). BN=128, BK=32, 4 waves 2x2.
// EPI: 0 = o = acc+bias
//      1 = gate: o = b2f(xinB) + sigmoid(acc+bias)*b2f(upB[row>>2])
//      2 = add:  o = b2f(xinB) + acc + bias
// outF written if non-null (f32), outB if non-null (bf16). XCD swizzle.
// =======================================================================
template<int EPI, int MI>
__global__ __launch_bounds__(256)
void k_gemm_mfma(const u16* __restrict__ A, const u16* __restrict__ BT,
                 const float* __restrict__ bias,
                 const u16* __restrict__ xinB, const u16* __restrict__ upB,
                 float* __restrict__ outF, u16* __restrict__ outB,
                 int M, int N, int K){
  constexpr int BM = MI*32;
  __shared__ short lA[BM*32];
  __shared__ short lB[128*32];
  int tid = threadIdx.x;
  int wv_ = tid>>6, ln_ = tid&63;
  int wy = wv_>>1, wx = wv_&1;
  int nx = gridDim.x;
  int flat = blockIdx.y*nx + blockIdx.x;
  int cpx = (nx*gridDim.y)>>3;
  int swz = (flat&7)*cpx + (flat>>3);
  int m0 = (swz/nx)*BM, n0 = (swz%nx)*128;

  f32x4 acc[MI][4];
  #pragma unroll
  for(int i=0;i<MI;i++)
    #pragma unroll
    for(int j=0;j<4;j++){ f32x4 z = {0.f,0.f,0.f,0.f}; acc[i][j]=z; }

  int fr = ln_&15, kg = ln_>>4;
  int aoff[MI], boff[4];
  #pragma unroll
  for(int i=0;i<MI;i++){
    int ar = wy*(MI*16) + i*16 + fr;
    aoff[i] = ar*64 + ((kg ^ ((ar>>1)&3))<<4);
  }
  #pragma unroll
  for(int j=0;j<4;j++){
    int br = wx*64 + j*16 + fr;
    boff[j] = br*64 + ((kg ^ ((br>>1)&3))<<4);
  }

  for(int k0=0;k0<K;k0+=32){
    #pragma unroll
    for(int q=0;q<BM/64;q++){
      int s = q*256 + tid;
      int row = s>>2;
      int gl = (s&3) ^ ((row>>1)&3);
      GLOAD16(A + (size_t)(m0+row)*K + k0 + gl*8, &lA[(q*4+wv_)*512]);
    }
    #pragma unroll
    for(int q=0;q<2;q++){
      int s = q*256 + tid;
      int row = s>>2;
      int gl = (s&3) ^ ((row>>1)&3);
      GLOAD16(BT + (size_t)(n0+row)*K + k0 + gl*8, &lB[(q*4+wv_)*512]);
    }
    __syncthreads();
    bf16x8 af[MI], bf[4];
    #pragma unroll
    for(int i=0;i<MI;i++) af[i] = *(const bf16x8*)((const char*)lA + aoff[i]);
    #pragma unroll
    for(int j=0;j<4;j++) bf[j] = *(const bf16x8*)((const char*)lB + boff[j]);
    #pragma unroll
    for(int i=0;i<MI;i++)
      #pragma unroll
      for(int j=0;j<4;j++)
        acc[i][j] = __builtin_amdgcn_mfma_f32_16x16x32_bf16(af[i], bf[j], acc[i][j], 0,0,0);
    __syncthreads();
  }

  int r0 = (ln_>>4)*4, c0 = ln_&15;
  #pragma unroll
  for(int i=0;i<MI;i++){
    #pragma unroll
    for(int j=0;j<4;j++){
      int gr = m0 + wy*(MI*16) + i*16 + r0;
      int gc = n0 + wx*64 + j*16 + c0;
      float bv = bias[gc];
      #pragma unroll
      for(int r=0;r<4;r++){
        float val = acc[i][j][r] + bv;
        size_t idx = (size_t)(gr+r)*N + gc;
        float o;
        if(EPI==0){
          o = val;
        } else if(EPI==1){
          o = b2f(xinB[idx]) + sigf(val)*b2f(upB[(size_t)((gr+r)>>2)*N + gc]);
        } else {
          o = b2f(xinB[idx]) + val;
        }
        if(outF) outF[idx] = o;
        if(outB) outB[idx] = f2b(o);
      }
    }
  }
}

// =======================================================================
// MFMA GLU GEMM: outB[M,Dh] = bf16( (A@Wa^T + ba) * sigmoid(A@Wb^T + bb) )
// =======================================================================
__global__ __launch_bounds__(256)
void k_glu_mfma(const u16* __restrict__ A, const u16* __restrict__ WT,
                const float* __restrict__ bias, u16* __restrict__ outB,
                int M, int Dh, int K){
  __shared__ short lA [128*32];
  __shared__ short lBa[64*32];
  __shared__ short lBb[64*32];
  int tid = threadIdx.x;
  int wv_ = tid>>6, ln_ = tid&63;
  int wy = wv_>>1, wx = wv_&1;
  int nx = gridDim.x;
  int flat = blockIdx.y*nx + blockIdx.x;
  int cpx = (nx*gridDim.y)>>3;
  int swz = (flat&7)*cpx + (flat>>3);
  int m0 = (swz/nx)*128, n0 = (swz%nx)*64;

  f32x4 aca[4][2], acb[4][2];
  #pragma unroll
  for(int i=0;i<4;i++)
    #pragma unroll
    for(int j=0;j<2;j++){ f32x4 z={0.f,0.f,0.f,0.f}; aca[i][j]=z; acb[i][j]=z; }

  int fr = ln_&15, kg = ln_>>4;
  int aoff[4], boff[2];
  #pragma unroll
  for(int i=0;i<4;i++){
    int ar = wy*64 + i*16 + fr;
    aoff[i] = ar*64 + ((kg ^ ((ar>>1)&3))<<4);
  }
  #pragma unroll
  for(int j=0;j<2;j++){
    int br = wx*32 + j*16 + fr;
    boff[j] = br*64 + ((kg ^ ((br>>1)&3))<<4);
  }

  for(int k0=0;k0<K;k0+=32){
    #pragma unroll
    for(int q=0;q<2;q++){
      int s = q*256 + tid;
      int row = s>>2;
      int gl = (s&3) ^ ((row>>1)&3);
      GLOAD16(A + (size_t)(m0+row)*K + k0 + gl*8, &lA[(q*4+wv_)*512]);
    }
    {
      int s = tid;
      int row = s>>2;
      int gl = (s&3) ^ ((row>>1)&3);
      GLOAD16(WT + (size_t)(n0+row)*K      + k0 + gl*8, &lBa[wv_*512]);
      GLOAD16(WT + (size_t)(Dh+n0+row)*K   + k0 + gl*8, &lBb[wv_*512]);
    }
    __syncthreads();
    bf16x8 af[4], ba[2], bb[2];
    #pragma unroll
    for(int i=0;i<4;i++) af[i] = *(const bf16x8*)((const char*)lA + aoff[i]);
    #pragma unroll
    for(int j=0;j<2;j++){
      ba[j] = *(const bf16x8*)((const char*)lBa + boff[j]);
      bb[j] = *(const bf16x8*)((const char*)lBb + boff[j]);
    }
    #pragma unroll
    for(int i=0;i<4;i++)
      #pragma unroll
      for(int j=0;j<2;j++){
        aca[i][j] = __builtin_amdgcn_mfma_f32_16x16x32_bf16(af[i], ba[j], aca[i][j], 0,0,0);
        acb[i][j] = __builtin_amdgcn_mfma_f32_16x16x32_bf16(af[i], bb[j], acb[i][j], 0,0,0);
      }
    __syncthreads();
  }

  int r0 = (ln_>>4)*4, c0 = ln_&15;
  #pragma unroll
  for(int i=0;i<4;i++){
    #pragma unroll
    for(int j=0;j<2;j++){
      int gr = m0 + wy*64 + i*16 + r0;
      int gc = n0 + wx*32 + j*16 + c0;
      float bva = bias[gc], bvb = bias[Dh+gc];
      #pragma unroll
      for(int r=0;r<4;r++){
        float o = (aca[i][j][r]+bva) * sigf(acb[i][j][r]+bvb);
        outB[(size_t)(gr+r)*Dh + gc] = f2b(o);
      }
    }
  }
}

#define FMA16(acc,va,vb) \
  acc[0][0]+=va.x*vb.x; acc[0][1]+=va.x*vb.y; acc[0][2]+=va.x*vb.z; acc[0][3]+=va.x*vb.w; \
  acc[1][0]+=va.y*vb.x; acc[1][1]+=va.y*vb.y; acc[1][2]+=va.y*vb.z; acc[1][3]+=va.y*vb.w; \
  acc[2][0]+=va.z*vb.x; acc[2][1]+=va.z*vb.y; acc[2][2]+=va.z*vb.z; acc[2][3]+=va.z*vb.w; \
  acc[3][0]+=va.w*vb.x; acc[3][1]+=va.w*vb.y; acc[3][2]+=va.w*vb.z; acc[3][3]+=va.w*vb.w;

// ---------------- attention: scores = q.k^T (fp32) ----------------
__global__ __launch_bounds__(256)
void k_qkt(const float* __restrict__ q, const float* __restrict__ k,
           float* __restrict__ scores){
  int z = blockIdx.z, b = z>>3, h = z&7;
  int i0 = blockIdx.y*64, j0 = blockIdx.x*64;
  __shared__ float Qs[64][64];
  __shared__ float Ks[64][64];
  int tid = threadIdx.x;
  const float* qb = q + ((size_t)b*NL + i0)*ND + h*NDK;
  const float* kb = k + ((size_t)b*NL + j0)*ND + h*NDK;
  #pragma unroll
  for(int r=0;r<4;r++){
    int f4 = tid + r*256;
    int row = f4>>4, dq = (f4&15)*4;
    float4 qa = *(const float4*)&qb[(size_t)row*ND + dq];
    float4 ka = *(const float4*)&kb[(size_t)row*ND + dq];
    Qs[dq+0][row]=qa.x; Qs[dq+1][row]=qa.y; Qs[dq+2][row]=qa.z; Qs[dq+3][row]=qa.w;
    Ks[dq+0][row]=ka.x; Ks[dq+1][row]=ka.y; Ks[dq+2][row]=ka.z; Ks[dq+3][row]=ka.w;
  }
  __syncthreads();
  int tx4 = (tid&15)*4, ty4 = (tid>>4)*4;
  float acc[4][4]={};
  #pragma unroll 8
  for(int d=0; d<64; d++){
    float4 a = *(const float4*)&Qs[d][ty4];
    float4 w = *(const float4*)&Ks[d][tx4];
    FMA16(acc,a,w)
  }
  float* sb = scores + (size_t)z*NL*NL;
  #pragma unroll
  for(int i=0;i<4;i++){
    float4 o; o.x=acc[i][0]; o.y=acc[i][1]; o.z=acc[i][2]; o.w=acc[i][3];
    *(float4*)&sb[(size_t)(i0+ty4+i)*NL + j0 + tx4] = o;
  }
}

// =======================================================================
// Fused Bm + softmax, d-split staging: pos chunk [512][32] f32 (64KB) +
// Qs [64][64] f32 (16KB) = 80KB LDS -> 2 blocks/CU.
// =======================================================================
__global__ __launch_bounds__(512)
void k_bmsm(const float* __restrict__ A, const float* __restrict__ q,
            const float* __restrict__ pos, u16* __restrict__ P){
  int i = blockIdx.x;
  __shared__ float Ps[512][32];   // 64 KB (one d-half)
  __shared__ float Qs[64][64];    // 16 KB
  int tid = threadIdx.x;
  #pragma unroll
  for(int t0=0;t0<2;t0++){
    int t = t0*512 + tid;
    int bh = t>>4, dq = (t&15)*4;
    *(float4*)&Qs[bh][dq] = *(const float4*)&q[((size_t)(bh>>3)*NL + i)*ND + (bh&7)*NDK + dq];
  }
  int jg = tid&31, rg = tid>>5;
  int j0 = jg*16, r0 = rg*4;
  int myx = (jg&7)<<2;
  float acc[4][16];
  #pragma unroll
  for(int r=0;r<4;r++){
    const float* arow = A + ((size_t)(r0+r)*NL + i)*NL + j0;
    #pragma unroll
    for(int c4=0;c4<4;c4++){
      float4 av = *(const float4*)&arow[c4*4];
      acc[r][c4*4+0]=av.x; acc[r][c4*4+1]=av.y; acc[r][c4*4+2]=av.z; acc[r][c4*4+3]=av.w;
    }
  }
  const float4* pp = (const float4*)(pos + (size_t)i*NL*NDK);
  for(int half=0; half<2; half++){
    int d0 = half*32;
    __syncthreads();   // half 0: join Qs/A; half 1: protect Ps reuse
    #pragma unroll
    for(int t0=0;t0<8;t0++){
      int t = t0*512 + tid;
      int j = t>>3, dl = (t&7)*4;
      int dsw = dl ^ (((j>>4)&7)<<2);
      *(float4*)&Ps[j][dsw] = pp[(size_t)j*16 + (d0>>2) + (t&7)];
    }
    __syncthreads();
    for(int d=0; d<32; d+=4){
      float4 q0 = *(const float4*)&Qs[r0+0][d0+d];
      float4 q1 = *(const float4*)&Qs[r0+1][d0+d];
      float4 q2 = *(const float4*)&Qs[r0+2][d0+d];
      float4 q3 = *(const float4*)&Qs[r0+3][d0+d];
      #pragma unroll
      for(int c=0;c<16;c++){
        float4 pv = *(const float4*)&Ps[j0+c][d ^ myx];
        acc[0][c] += q0.x*pv.x + q0.y*pv.y + q0.z*pv.z + q0.w*pv.w;
        acc[1][c] += q1.x*pv.x + q1.y*pv.y + q1.z*pv.z + q1.w*pv.w;
        acc[2][c] += q2.x*pv.x + q2.y*pv.y + q2.z*pv.z + q2.w*pv.w;
        acc[3][c] += q3.x*pv.x + q3.y*pv.y + q3.z*pv.z + q3.w*pv.w;
      }
    }
  }
  #pragma unroll
  for(int r=0;r<4;r++){
    float mx = -3e38f;
    #pragma unroll
    for(int c=0;c<16;c++){ acc[r][c] *= 0.125f; mx = fmaxf(mx, acc[r][c]); }
    #pragma unroll
    for(int o=16;o;o>>=1) mx = fmaxf(mx, __shfl_xor(mx, o));
    float sm = 0.f;
    #pragma unroll
    for(int c=0;c<16;c++){ acc[r][c] = __expf(acc[r][c]-mx); sm += acc[r][c]; }
    #pragma unroll
    for(int o=16;o;o>>=1) sm += __shfl_xor(sm, o);
    float inv = 1.0f/sm;
    u16 tmp[16];
    #pragma unroll
    for(int c=0;c<16;c++) tmp[c] = f2b(acc[r][c]*inv);
    u16* prow = P + ((size_t)(r0+r)*NL + i)*NL + j0;
    *(uint4*)&prow[0] = *(uint4*)&tmp[0];
    *(uint4*)&prow[8] = *(uint4*)&tmp[8];
  }
}

// ---------------- o = P(bf16) @ v(f32) -> bf16 out ----------------
__global__ __launch_bounds__(256)
void k_pv(const u16* __restrict__ attn, const float* __restrict__ v,
          u16* __restrict__ o){
  int z = blockIdx.y, b = z>>3, h = z&7;
  int i0 = blockIdx.x*64;
  __shared__ float As[32][64];
  __shared__ float Vs[32][64];
  const u16* ab = attn + ((size_t)z*NL + i0)*NL;
  const float* vb = v + (size_t)b*NL*ND + h*NDK;
  int tid = threadIdx.x;
  int tx4 = (tid&15)*4, ty4 = (tid>>4)*4;
  float acc[4][4]={};
  for(int k0=0;k0<NL;k0+=32){
    int f40 = tid,     f41 = tid+256;
    int ai0 = f40>>3,  aq0 = (f40&7)*4;
    int ai1 = f41>>3,  aq1 = (f41&7)*4;
    int vk0 = f40>>4,  vd0 = (f40&15)*4;
    int vk1 = f41>>4,  vd1 = (f41&15)*4;
    ushort4 av0 = *(const ushort4*)&ab[(size_t)ai0*NL + k0 + aq0];
    ushort4 av1 = *(const ushort4*)&ab[(size_t)ai1*NL + k0 + aq1];
    float4 vv0 = *(const float4*)&vb[(size_t)(k0+vk0)*ND + vd0];
    float4 vv1 = *(const float4*)&vb[(size_t)(k0+vk1)*ND + vd1];
    __syncthreads();
    As[aq0+0][ai0]=b2f(av0.x); As[aq0+1][ai0]=b2f(av0.y); As[aq0+2][ai0]=b2f(av0.z); As[aq0+3][ai0]=b2f(av0.w);
    As[aq1+0][ai1]=b2f(av1.x); As[aq1+1][ai1]=b2f(av1.y); As[aq1+2][ai1]=b2f(av1.z); As[aq1+3][ai1]=b2f(av1.w);
    *(float4*)&Vs[vk0][vd0]=vv0;
    *(float4*)&Vs[vk1][vd1]=vv1;
    __syncthreads();
    #pragma unroll
    for(int kk=0;kk<32;kk++){
      float4 a = *(const float4*)&As[kk][ty4];
      float4 w = *(const float4*)&Vs[kk][tx4];
      FMA16(acc,a,w)
    }
  }
  u16* ob = o + ((size_t)b*NL + i0)*ND + h*NDK;
  #pragma unroll
  for(int i=0;i<4;i++){
    ushort4 hv = make_ushort4(f2b(acc[i][0]), f2b(acc[i][1]), f2b(acc[i][2]), f2b(acc[i][3]));
    *(ushort4*)&ob[(size_t)(ty4+i)*ND + tx4] = hv;
  }
}

// ---------------- depthwise conv1d, K=31, SAME (bf16 in, bf16 out) ----------------
__global__ __launch_bounds__(256)
void k_dwconv(const u16* __restrict__ in, const float* __restrict__ w,
              const float* __restrict__ bias, u16* __restrict__ out){
  int c  = blockIdx.x*256 + threadIdx.x;
  int t0 = blockIdx.y*4;
  int b  = blockIdx.z;
  const u16* ib = in + (size_t)b*NT*ND + c;
  float win[34];
  #pragma unroll
  for(int r=0;r<34;r++){
    int t = t0 - 15 + r;
    win[r] = (t>=0 && t<NT) ? b2f(ib[(size_t)t*ND]) : 0.0f;
  }
  float wg[31];
  #pragma unroll
  for(int kk=0;kk<31;kk++) wg[kk] = w[c*31+kk];
  float bs = bias[c];
  u16* ob = out + (size_t)b*NT*ND + c;
  #pragma unroll
  for(int oo=0;oo<4;oo++){
    float s = bs;
    #pragma unroll
    for(int kk=0;kk<31;kk++) s += win[oo+kk]*wg[kk];
    ob[(size_t)(t0+oo)*ND] = f2b(s);
  }
}

extern "C" void kernel_launch(void* const* d_in, const int* in_sizes, int n_in,
                              void* d_out, int out_size, void* d_ws, size_t ws_size,
                              hipStream_t stream) {
  const float* x      = (const float*)d_in[0];
  const float* pos    = (const float*)d_in[1];
  const float* mha_g  = (const float*)d_in[2];
  const float* mha_b  = (const float*)d_in[3];
  const float* wq     = (const float*)d_in[4];
  const float* bq     = (const float*)d_in[5];
  const float* wk     = (const float*)d_in[6];
  const float* bk     = (const float*)d_in[7];
  const float* wv     = (const float*)d_in[8];
  const float* bv     = (const float*)d_in[9];
  const float* wo     = (const float*)d_in[10];
  const float* bo     = (const float*)d_in[11];
  const float* ega_wg = (const float*)d_in[12];
  const float* ega_bg = (const float*)d_in[13];
  const float* g1_ln_g= (const float*)d_in[14];
  const float* g1_ln_b= (const float*)d_in[15];
  const float* g1_w1  = (const float*)d_in[16];
  const float* g1_b1  = (const float*)d_in[17];
  const float* g1_w2  = (const float*)d_in[18];
  const float* g1_b2  = (const float*)d_in[19];
  const float* g1_wg  = (const float*)d_in[20];
  const float* g1_bg  = (const float*)d_in[21];
  const float* cla_ln_g=(const float*)d_in[22];
  const float* cla_ln_b=(const float*)d_in[23];
  const float* cla_w1 = (const float*)d_in[24];
  const float* cla_b1 = (const float*)d_in[25];
  const float* dw_w   = (const float*)d_in[26];
  const float* dw_b   = (const float*)d_in[27];
  const float* cla_w2 = (const float*)d_in[28];
  const float* cla_b2 = (const float*)d_in[29];
  const float* g2_ln_g= (const float*)d_in[30];
  const float* g2_ln_b= (const float*)d_in[31];
  const float* g2_w1  = (const float*)d_in[32];
  const float* g2_b1  = (const float*)d_in[33];
  const float* g2_w2  = (const float*)d_in[34];
  const float* g2_b2  = (const float*)d_in[35];
  const float* g2_wg  = (const float*)d_in[36];
  const float* g2_bg  = (const float*)d_in[37];

  float* xo = (float*)d_out;
  float* ws = (float*)d_ws;
  const size_t M1 = 1024*1024;

  // workspace map (f32 units); region [0,16M) is time-multiplexed:
  float* SC    = ws;                       // scores f32 (attn phase)
  u16*  s5b    = (u16*)ws;                 // [0,1)   attn out bf16
  u16*  glu_p  = (u16*)ws;                 // [0,6)   g1/g2 GLU out [4096][1536]
  u16*  glu_b  = (u16*)ws;                 // [0,4)   CLA GLU out [16384][512]
  u16*  conv_b = (u16*)(ws + 4*M1);        // [4,8)   CLA conv out
  u16*  s6b    = (u16*)(ws + 6*M1);        // [6,7)   'up' bf16 [4096][512]
  u16*  lnPb   = (u16*)(ws + 7*M1);        // [7,8)   pooled ln bf16
  u16*  lnFb   = (u16*)(ws + 8*M1);        // [8,12)  CLA ln bf16
  u16*  Pb     = (u16*)(ws + 16*M1);       // [16,24) attn probs bf16
  u16*  xbA    = (u16*)(ws + 24*M1);       // [24,28) stream ping
  u16*  xbB    = (u16*)(ws + 28*M1);       // [28,32) stream pong
  u16*  WTb    = (u16*)(ws + 32*M1);       // [32,36) bf16 weights
  float* q     = ws + 38*M1;               // [38,40)
  float* k     = ws + 40*M1;               // [40,42)
  float* v     = ws + 42*M1;               // [42,44)

  u16* wqT   = WTb + 0;
  u16* wkT   = WTb + 262144;
  u16* wvT   = WTb + 524288;
  u16* woT   = WTb + 786432;
  u16* egaT  = WTb + 1048576;
  u16* g1w1T = WTb + 1310720;   // [3072][512]
  u16* g1w2T = WTb + 2883584;   // [512][1536]
  u16* g1wgT = WTb + 3670016;
  u16* claw1T= WTb + 3932160;   // [1024][512]
  u16* claw2T= WTb + 4456448;
  u16* g2w1T = WTb + 4718592;
  u16* g2w2T = WTb + 6291456;
  u16* g2wgT = WTb + 7077888;

  const int rowsP = NB*NL;        // 4096
  const int rowsF = NB*NT;        // 16384
  const int n4F = rowsF*128;
  dim3 blk(256);
  dim3 gPool(4,64);               // pooled GEMM: BM=64 -> 256 blocks
  dim3 gFull(4,128);              // full-T GEMM: BM=128 -> 512 blocks

  // ---- weight prep: one merged launch (13 jobs) ----
  {
    WtJobs J;
    const float* Wsrc[13] = {wq,wk,wv,wo,ega_wg,g1_w1,g1_w2,g1_wg,cla_w1,cla_w2,g2_w1,g2_w2,g2_wg};
    u16* Wdst[13] = {wqT,wkT,wvT,woT,egaT,g1w1T,g1w2T,g1wgT,claw1T,claw2T,g2w1T,g2w2T,g2wgT};
    int Ks[13] = {512,512,512,512,512, 512,1536,512, 512,512, 512,1536,512};
    int Ns[13] = {512,512,512,512,512, 3072,512,512, 1024,512, 3072,512,512};
    int off = 0;
    for(int t=0;t<13;t++){
      J.W[t]=Wsrc[t]; J.WT[t]=Wdst[t]; J.K[t]=Ks[t]; J.N[t]=Ns[t];
      J.off[t]=off; off += (Ns[t]>>5)*(Ks[t]>>5);
    }
    J.off[13]=off;
    k_wt_all<<<off, blk, 0, stream>>>(J);
  }
  k_castb<<<(n4F+255)/256, blk, 0, stream>>>((const float4*)x, (ushort4*)xbA, n4F);

  // ================= EGA =================
  k_poollnf<<<rowsP, 64, 0, stream>>>(x, lnPb, mha_g, mha_b);
  k_gemm_mfma<0,2><<<gPool, blk, 0, stream>>>(lnPb, wqT, bq, nullptr,nullptr, q, nullptr, rowsP, ND, ND);
  k_gemm_mfma<0,2><<<gPool, blk, 0, stream>>>(lnPb, wkT, bk, nullptr,nullptr, k, nullptr, rowsP, ND, ND);
  k_gemm_mfma<0,2><<<gPool, blk, 0, stream>>>(lnPb, wvT, bv, nullptr,nullptr, v, nullptr, rowsP, ND, ND);
  k_qkt<<<dim3(8,8,64), blk, 0, stream>>>(q, k, SC);
  k_bmsm<<<512, 512, 0, stream>>>(SC, q, pos, Pb);
  k_pv<<<dim3(8,64), blk, 0, stream>>>(Pb, v, s5b);
  k_gemm_mfma<0,2><<<gPool, blk, 0, stream>>>(s5b, woT, bo, nullptr,nullptr, nullptr, s6b, rowsP, ND, ND);
  k_gemm_mfma<1,4><<<gFull, blk, 0, stream>>>(xbA, egaT, ega_bg, xbA, s6b, nullptr, xbB, rowsF, ND, ND);

  // ================= GCFN global (g1) =================
  k_poollnb<<<rowsP, 64, 0, stream>>>(xbB, lnPb, g1_ln_g, g1_ln_b);
  k_glu_mfma<<<dim3(24,32), blk, 0, stream>>>(lnPb, g1w1T, g1_b1, glu_p, rowsP, 1536, ND);
  k_gemm_mfma<0,2><<<gPool, blk, 0, stream>>>(glu_p, g1w2T, g1_b2, nullptr,nullptr, nullptr, s6b, rowsP, ND, 1536);
  k_gemm_mfma<1,4><<<gFull, blk, 0, stream>>>(xbB, g1wgT, g1_bg, xbB, s6b, nullptr, xbA, rowsF, ND, ND);

  // ================= CLA =================
  k_lnb4<<<rowsF/4, blk, 0, stream>>>(xbA, lnFb, cla_ln_g, cla_ln_b);
  k_glu_mfma<<<dim3(8,128), blk, 0, stream>>>(lnFb, claw1T, cla_b1, glu_b, rowsF, 512, ND);
  k_dwconv<<<dim3(2, NT/4, NB), blk, 0, stream>>>(glu_b, dw_w, dw_b, conv_b);
  k_gemm_mfma<2,4><<<gFull, blk, 0, stream>>>(conv_b, claw2T, cla_b2, xbA, nullptr, nullptr, xbB, rowsF, ND, ND);

  // ================= GCFN local (g2) =================
  k_poollnb<<<rowsP, 64, 0, stream>>>(xbB, lnPb, g2_ln_g, g2_ln_b);
  k_glu_mfma<<<dim3(24,32), blk, 0, stream>>>(lnPb, g2w1T, g2_b1, glu_p, rowsP, 1536, ND);
  k_gemm_mfma<0,2><<<gPool, blk, 0, stream>>>(glu_p, g2w2T, g2_b2, nullptr,nullptr, nullptr, s6b, rowsP, ND, 1536);
  k_gemm_mfma<1,4><<<gFull, blk, 0, stream>>>(xbB, g2wgT, g2_bg, xbB, s6b, xo, nullptr, rowsF, ND, ND);
}

// Round 8
// 496.515 us; speedup vs baseline: 3.7993x; 1.1690x over previous
//
#include <hip/hip_runtime.h>
#include <math.h>

#define NB 8
#define NT 2048
#define ND 512
#define NH 8
#define NDK 64
#define NL 512

typedef unsigned short u16;
typedef __attribute__((ext_vector_type(8))) short bf16x8;
typedef __attribute__((ext_vector_type(4))) float f32x4;

__device__ __forceinline__ float sigf(float v){ return 1.0f/(1.0f+__expf(-v)); }

__device__ __forceinline__ u16 f2b(float f){
  union{float f; unsigned u;} v; v.f = f;
  unsigned r = v.u + 0x7fffu + ((v.u>>16)&1u);
  return (u16)(r>>16);
}
__device__ __forceinline__ float b2f(u16 h){
  union{unsigned u; float f;} v; v.u = ((unsigned)h)<<16; return v.f;
}

#define GLOAD16(src, dst) \
  __builtin_amdgcn_global_load_lds((const __attribute__((address_space(1))) void*)(src), \
                                   (__attribute__((address_space(3))) void*)(dst), 16, 0, 0)

// ---------------- fused pool4 + LayerNorm, f32 in -> bf16 out ----------------
__global__ void k_poollnf(const float* __restrict__ in, u16* __restrict__ outb,
                          const float* __restrict__ gam, const float* __restrict__ bet){
  size_t prow = blockIdx.x;
  int lane = threadIdx.x;   // 64
  const float* p = in + prow*4*ND + lane*8;
  float x[8] = {0,0,0,0,0,0,0,0};
  #pragma unroll
  for(int rr=0;rr<4;rr++){
    float4 a = *(const float4*)&p[(size_t)rr*ND];
    float4 b = *(const float4*)&p[(size_t)rr*ND+4];
    x[0]+=a.x; x[1]+=a.y; x[2]+=a.z; x[3]+=a.w;
    x[4]+=b.x; x[5]+=b.y; x[6]+=b.z; x[7]+=b.w;
  }
  #pragma unroll
  for(int e=0;e<8;e++) x[e]*=0.25f;
  float s=0.f, ss=0.f;
  #pragma unroll
  for(int e=0;e<8;e++){ s+=x[e]; ss+=x[e]*x[e]; }
  #pragma unroll
  for(int o=32;o;o>>=1){ s+=__shfl_xor(s,o); ss+=__shfl_xor(ss,o); }
  float m  = s*(1.0f/ND);
  float rs = rsqrtf(ss*(1.0f/ND)-m*m+1e-5f);
  const float4* gp=(const float4*)gam; const float4* bp=(const float4*)bet;
  float4 g0=gp[lane*2],g1=gp[lane*2+1],b0=bp[lane*2],b1=bp[lane*2+1];
  float o0=(x[0]-m)*rs*g0.x+b0.x, o1=(x[1]-m)*rs*g0.y+b0.y;
  float o2=(x[2]-m)*rs*g0.z+b0.z, o3=(x[3]-m)*rs*g0.w+b0.w;
  float o4=(x[4]-m)*rs*g1.x+b1.x, o5=(x[5]-m)*rs*g1.y+b1.y;
  float o6=(x[6]-m)*rs*g1.z+b1.z, o7=(x[7]-m)*rs*g1.w+b1.w;
  uint4 pk;
  pk.x = (unsigned)f2b(o0) | ((unsigned)f2b(o1)<<16);
  pk.y = (unsigned)f2b(o2) | ((unsigned)f2b(o3)<<16);
  pk.z = (unsigned)f2b(o4) | ((unsigned)f2b(o5)<<16);
  pk.w = (unsigned)f2b(o6) | ((unsigned)f2b(o7)<<16);
  *(uint4*)&outb[prow*ND + lane*8] = pk;
}

// ---------------- fused pool4 + LayerNorm, bf16 in -> bf16 out ----------------
__global__ void k_poollnb(const u16* __restrict__ in, u16* __restrict__ outb,
                          const float* __restrict__ gam, const float* __restrict__ bet){
  size_t prow = blockIdx.x;
  int lane = threadIdx.x;
  const u16* p = in + prow*4*ND + lane*8;
  float x[8] = {0,0,0,0,0,0,0,0};
  #pragma unroll
  for(int rr=0;rr<4;rr++){
    ushort4 a = *(const ushort4*)&p[(size_t)rr*ND];
    ushort4 b = *(const ushort4*)&p[(size_t)rr*ND+4];
    x[0]+=b2f(a.x); x[1]+=b2f(a.y); x[2]+=b2f(a.z); x[3]+=b2f(a.w);
    x[4]+=b2f(b.x); x[5]+=b2f(b.y); x[6]+=b2f(b.z); x[7]+=b2f(b.w);
  }
  #pragma unroll
  for(int e=0;e<8;e++) x[e]*=0.25f;
  float s=0.f, ss=0.f;
  #pragma unroll
  for(int e=0;e<8;e++){ s+=x[e]; ss+=x[e]*x[e]; }
  #pragma unroll
  for(int o=32;o;o>>=1){ s+=__shfl_xor(s,o); ss+=__shfl_xor(ss,o); }
  float m  = s*(1.0f/ND);
  float rs = rsqrtf(ss*(1.0f/ND)-m*m+1e-5f);
  const float4* gp=(const float4*)gam; const float4* bp=(const float4*)bet;
  float4 g0=gp[lane*2],g1=gp[lane*2+1],b0=bp[lane*2],b1=bp[lane*2+1];
  float o0=(x[0]-m)*rs*g0.x+b0.x, o1=(x[1]-m)*rs*g0.y+b0.y;
  float o2=(x[2]-m)*rs*g0.z+b0.z, o3=(x[3]-m)*rs*g0.w+b0.w;
  float o4=(x[4]-m)*rs*g1.x+b1.x, o5=(x[5]-m)*rs*g1.y+b1.y;
  float o6=(x[6]-m)*rs*g1.z+b1.z, o7=(x[7]-m)*rs*g1.w+b1.w;
  uint4 pk;
  pk.x = (unsigned)f2b(o0) | ((unsigned)f2b(o1)<<16);
  pk.y = (unsigned)f2b(o2) | ((unsigned)f2b(o3)<<16);
  pk.z = (unsigned)f2b(o4) | ((unsigned)f2b(o5)<<16);
  pk.w = (unsigned)f2b(o6) | ((unsigned)f2b(o7)<<16);
  *(uint4*)&outb[prow*ND + lane*8] = pk;
}

// ---------------- row LayerNorm, bf16 in -> bf16 out, 4 rows/block ----------------
__global__ __launch_bounds__(256)
void k_lnb4(const u16* __restrict__ in, u16* __restrict__ outb,
            const float* __restrict__ gam, const float* __restrict__ bet){
  size_t row = (size_t)blockIdx.x*4 + (threadIdx.x>>6);
  int lane = threadIdx.x & 63;
  const u16* p = in + row*ND + lane*8;
  ushort4 a0 = *(const ushort4*)p;
  ushort4 a1 = *(const ushort4*)(p+4);
  float x0=b2f(a0.x),x1=b2f(a0.y),x2=b2f(a0.z),x3=b2f(a0.w);
  float x4=b2f(a1.x),x5=b2f(a1.y),x6=b2f(a1.z),x7=b2f(a1.w);
  float s  = x0+x1+x2+x3+x4+x5+x6+x7;
  float ss = x0*x0+x1*x1+x2*x2+x3*x3+x4*x4+x5*x5+x6*x6+x7*x7;
  #pragma unroll
  for(int o=32;o;o>>=1){ s+=__shfl_xor(s,o); ss+=__shfl_xor(ss,o); }
  float m  = s*(1.0f/ND);
  float rs = rsqrtf(ss*(1.0f/ND)-m*m+1e-5f);
  const float4* gp=(const float4*)gam; const float4* bp=(const float4*)bet;
  float4 g0=gp[lane*2],g1=gp[lane*2+1],b0=bp[lane*2],b1=bp[lane*2+1];
  float o0=(x0-m)*rs*g0.x+b0.x, o1=(x1-m)*rs*g0.y+b0.y;
  float o2=(x2-m)*rs*g0.z+b0.z, o3=(x3-m)*rs*g0.w+b0.w;
  float o4=(x4-m)*rs*g1.x+b1.x, o5=(x5-m)*rs*g1.y+b1.y;
  float o6=(x6-m)*rs*g1.z+b1.z, o7=(x7-m)*rs*g1.w+b1.w;
  uint4 pk;
  pk.x = (unsigned)f2b(o0) | ((unsigned)f2b(o1)<<16);
  pk.y = (unsigned)f2b(o2) | ((unsigned)f2b(o3)<<16);
  pk.z = (unsigned)f2b(o4) | ((unsigned)f2b(o5)<<16);
  pk.w = (unsigned)f2b(o6) | ((unsigned)f2b(o7)<<16);
  *(uint4*)&outb[row*ND + lane*8] = pk;
}

// ---------------- cast f32 -> bf16 ----------------
__global__ void k_castb(const float4* __restrict__ in, ushort4* __restrict__ out, int n4){
  int i = blockIdx.x*256 + threadIdx.x;
  if(i>=n4) return;
  float4 v = in[i];
  out[i] = make_ushort4(f2b(v.x), f2b(v.y), f2b(v.z), f2b(v.w));
}

// ---------------- merged weight transpose+cast: 13 jobs, one launch ----------------
struct WtJobs {
  const float* W[13];
  u16* WT[13];
  int K[13], N[13];
  int off[14];
};
__global__ __launch_bounds__(256)
void k_wt_all(WtJobs jobs){
  __shared__ float ls[32][33];
  int bid = blockIdx.x;
  int ji = 0;
  #pragma unroll
  for(int t=0;t<12;t++) if(bid >= jobs.off[t+1]) ji = t+1;
  int local = bid - jobs.off[ji];
  const float* W = jobs.W[ji];
  u16* WT = jobs.WT[ji];
  int K = jobs.K[ji], N = jobs.N[ji];
  int tn = N>>5;
  int n0 = (local % tn)*32, k0 = (local / tn)*32;
  int tid = threadIdx.x;
  int tx = tid&31, ty = tid>>5;
  #pragma unroll
  for(int p=0;p<4;p++)
    ls[ty+p*8][tx] = W[(size_t)(k0+ty+p*8)*N + n0+tx];
  __syncthreads();
  #pragma unroll
  for(int p=0;p<4;p++)
    WT[(size_t)(n0+ty+p*8)*K + k0+tx] = f2b(ls[tx][ty+p*8]);
}

// =======================================================================
// MFMA GEMM (generic): C = A_bf16[M,K] @ BT_bf16[N,K]^T (+ epilogue)
// =======================================================================
template<int EPI, int MI>
__global__ __launch_bounds__(256)
void k_gemm_mfma(const u16* __restrict__ A, const u16* __restrict__ BT,
                 const float* __restrict__ bias,
                 const u16* __restrict__ xinB, const u16* __restrict__ upB,
                 float* __restrict__ outF, u16* __restrict__ outB,
                 int M, int N, int K){
  constexpr int BM = MI*32;
  __shared__ short lA[BM*32];
  __shared__ short lB[128*32];
  int tid = threadIdx.x;
  int wv_ = tid>>6, ln_ = tid&63;
  int wy = wv_>>1, wx = wv_&1;
  int nx = gridDim.x;
  int flat = blockIdx.y*nx + blockIdx.x;
  int cpx = (nx*gridDim.y)>>3;
  int swz = (flat&7)*cpx + (flat>>3);
  int m0 = (swz/nx)*BM, n0 = (swz%nx)*128;

  f32x4 acc[MI][4];
  #pragma unroll
  for(int i=0;i<MI;i++)
    #pragma unroll
    for(int j=0;j<4;j++){ f32x4 z = {0.f,0.f,0.f,0.f}; acc[i][j]=z; }

  int fr = ln_&15, kg = ln_>>4;
  int aoff[MI], boff[4];
  #pragma unroll
  for(int i=0;i<MI;i++){
    int ar = wy*(MI*16) + i*16 + fr;
    aoff[i] = ar*64 + ((kg ^ ((ar>>1)&3))<<4);
  }
  #pragma unroll
  for(int j=0;j<4;j++){
    int br = wx*64 + j*16 + fr;
    boff[j] = br*64 + ((kg ^ ((br>>1)&3))<<4);
  }

  for(int k0=0;k0<K;k0+=32){
    #pragma unroll
    for(int q=0;q<BM/64;q++){
      int s = q*256 + tid;
      int row = s>>2;
      int gl = (s&3) ^ ((row>>1)&3);
      GLOAD16(A + (size_t)(m0+row)*K + k0 + gl*8, &lA[(q*4+wv_)*512]);
    }
    #pragma unroll
    for(int q=0;q<2;q++){
      int s = q*256 + tid;
      int row = s>>2;
      int gl = (s&3) ^ ((row>>1)&3);
      GLOAD16(BT + (size_t)(n0+row)*K + k0 + gl*8, &lB[(q*4+wv_)*512]);
    }
    __syncthreads();
    bf16x8 af[MI], bf[4];
    #pragma unroll
    for(int i=0;i<MI;i++) af[i] = *(const bf16x8*)((const char*)lA + aoff[i]);
    #pragma unroll
    for(int j=0;j<4;j++) bf[j] = *(const bf16x8*)((const char*)lB + boff[j]);
    #pragma unroll
    for(int i=0;i<MI;i++)
      #pragma unroll
      for(int j=0;j<4;j++)
        acc[i][j] = __builtin_amdgcn_mfma_f32_16x16x32_bf16(af[i], bf[j], acc[i][j], 0,0,0);
    __syncthreads();
  }

  int r0 = (ln_>>4)*4, c0 = ln_&15;
  #pragma unroll
  for(int i=0;i<MI;i++){
    #pragma unroll
    for(int j=0;j<4;j++){
      int gr = m0 + wy*(MI*16) + i*16 + r0;
      int gc = n0 + wx*64 + j*16 + c0;
      float bv = bias[gc];
      #pragma unroll
      for(int r=0;r<4;r++){
        float val = acc[i][j][r] + bv;
        size_t idx = (size_t)(gr+r)*N + gc;
        float o;
        if(EPI==0){
          o = val;
        } else if(EPI==1){
          o = b2f(xinB[idx]) + sigf(val)*b2f(upB[(size_t)((gr+r)>>2)*N + gc]);
        } else {
          o = b2f(xinB[idx]) + val;
        }
        if(outF) outF[idx] = o;
        if(outB) outB[idx] = f2b(o);
      }
    }
  }
}

// =======================================================================
// MFMA GLU GEMM
// =======================================================================
__global__ __launch_bounds__(256)
void k_glu_mfma(const u16* __restrict__ A, const u16* __restrict__ WT,
                const float* __restrict__ bias, u16* __restrict__ outB,
                int M, int Dh, int K){
  __shared__ short lA [128*32];
  __shared__ short lBa[64*32];
  __shared__ short lBb[64*32];
  int tid = threadIdx.x;
  int wv_ = tid>>6, ln_ = tid&63;
  int wy = wv_>>1, wx = wv_&1;
  int nx = gridDim.x;
  int flat = blockIdx.y*nx + blockIdx.x;
  int cpx = (nx*gridDim.y)>>3;
  int swz = (flat&7)*cpx + (flat>>3);
  int m0 = (swz/nx)*128, n0 = (swz%nx)*64;

  f32x4 aca[4][2], acb[4][2];
  #pragma unroll
  for(int i=0;i<4;i++)
    #pragma unroll
    for(int j=0;j<2;j++){ f32x4 z={0.f,0.f,0.f,0.f}; aca[i][j]=z; acb[i][j]=z; }

  int fr = ln_&15, kg = ln_>>4;
  int aoff[4], boff[2];
  #pragma unroll
  for(int i=0;i<4;i++){
    int ar = wy*64 + i*16 + fr;
    aoff[i] = ar*64 + ((kg ^ ((ar>>1)&3))<<4);
  }
  #pragma unroll
  for(int j=0;j<2;j++){
    int br = wx*32 + j*16 + fr;
    boff[j] = br*64 + ((kg ^ ((br>>1)&3))<<4);
  }

  for(int k0=0;k0<K;k0+=32){
    #pragma unroll
    for(int q=0;q<2;q++){
      int s = q*256 + tid;
      int row = s>>2;
      int gl = (s&3) ^ ((row>>1)&3);
      GLOAD16(A + (size_t)(m0+row)*K + k0 + gl*8, &lA[(q*4+wv_)*512]);
    }
    {
      int s = tid;
      int row = s>>2;
      int gl = (s&3) ^ ((row>>1)&3);
      GLOAD16(WT + (size_t)(n0+row)*K      + k0 + gl*8, &lBa[wv_*512]);
      GLOAD16(WT + (size_t)(Dh+n0+row)*K   + k0 + gl*8, &lBb[wv_*512]);
    }
    __syncthreads();
    bf16x8 af[4], ba[2], bb[2];
    #pragma unroll
    for(int i=0;i<4;i++) af[i] = *(const bf16x8*)((const char*)lA + aoff[i]);
    #pragma unroll
    for(int j=0;j<2;j++){
      ba[j] = *(const bf16x8*)((const char*)lBa + boff[j]);
      bb[j] = *(const bf16x8*)((const char*)lBb + boff[j]);
    }
    #pragma unroll
    for(int i=0;i<4;i++)
      #pragma unroll
      for(int j=0;j<2;j++){
        aca[i][j] = __builtin_amdgcn_mfma_f32_16x16x32_bf16(af[i], ba[j], aca[i][j], 0,0,0);
        acb[i][j] = __builtin_amdgcn_mfma_f32_16x16x32_bf16(af[i], bb[j], acb[i][j], 0,0,0);
      }
    __syncthreads();
  }

  int r0 = (ln_>>4)*4, c0 = ln_&15;
  #pragma unroll
  for(int i=0;i<4;i++){
    #pragma unroll
    for(int j=0;j<2;j++){
      int gr = m0 + wy*64 + i*16 + r0;
      int gc = n0 + wx*32 + j*16 + c0;
      float bva = bias[gc], bvb = bias[Dh+gc];
      #pragma unroll
      for(int r=0;r<4;r++){
        float o = (aca[i][j][r]+bva) * sigf(acb[i][j][r]+bvb);
        outB[(size_t)(gr+r)*Dh + gc] = f2b(o);
      }
    }
  }
}

// =======================================================================
// MFMA QK^T: SC[z][i][j] = q_z[i][:] . k_z[j][:]  (bf16 in, f32 out)
// grid (jt=4, it=4, z=64), 128x128 tiles, K=64 (lda/ldb = 512)
// =======================================================================
__global__ __launch_bounds__(256)
void k_qkt_mfma(const u16* __restrict__ qb, const u16* __restrict__ kb,
                float* __restrict__ SC){
  int z = blockIdx.z, b = z>>3, h = z&7;
  int i0 = blockIdx.y*128, j0 = blockIdx.x*128;
  __shared__ short lA[128*32];
  __shared__ short lB[128*32];
  int tid = threadIdx.x;
  int wv_ = tid>>6, ln_ = tid&63;
  int wy = wv_>>1, wx = wv_&1;
  const u16* Ab = qb + ((size_t)b*NL + i0)*ND + h*NDK;
  const u16* Bb = kb + ((size_t)b*NL + j0)*ND + h*NDK;

  f32x4 acc[4][4];
  #pragma unroll
  for(int i=0;i<4;i++)
    #pragma unroll
    for(int j=0;j<4;j++){ f32x4 zz={0.f,0.f,0.f,0.f}; acc[i][j]=zz; }

  int fr = ln_&15, kg = ln_>>4;
  int aoff[4], boff[4];
  #pragma unroll
  for(int i=0;i<4;i++){
    int ar = wy*64 + i*16 + fr;
    aoff[i] = ar*64 + ((kg ^ ((ar>>1)&3))<<4);
    int br = wx*64 + i*16 + fr;
    boff[i] = br*64 + ((kg ^ ((br>>1)&3))<<4);
  }

  #pragma unroll
  for(int k0=0;k0<64;k0+=32){
    #pragma unroll
    for(int q=0;q<2;q++){
      int s = q*256 + tid;
      int row = s>>2;
      int gl = (s&3) ^ ((row>>1)&3);
      GLOAD16(Ab + (size_t)row*ND + k0 + gl*8, &lA[(q*4+wv_)*512]);
      GLOAD16(Bb + (size_t)row*ND + k0 + gl*8, &lB[(q*4+wv_)*512]);
    }
    __syncthreads();
    bf16x8 af[4], bf[4];
    #pragma unroll
    for(int i=0;i<4;i++) af[i] = *(const bf16x8*)((const char*)lA + aoff[i]);
    #pragma unroll
    for(int j=0;j<4;j++) bf[j] = *(const bf16x8*)((const char*)lB + boff[j]);
    #pragma unroll
    for(int i=0;i<4;i++)
      #pragma unroll
      for(int j=0;j<4;j++)
        acc[i][j] = __builtin_amdgcn_mfma_f32_16x16x32_bf16(af[i], bf[j], acc[i][j], 0,0,0);
    __syncthreads();
  }

  float* sb = SC + (size_t)z*NL*NL;
  int r0 = (ln_>>4)*4, c0 = ln_&15;
  #pragma unroll
  for(int i=0;i<4;i++){
    #pragma unroll
    for(int j=0;j<4;j++){
      int gr = i0 + wy*64 + i*16 + r0;
      int gc = j0 + wx*64 + j*16 + c0;
      #pragma unroll
      for(int r=0;r<4;r++)
        sb[(size_t)(gr+r)*NL + gc] = acc[i][j][r];
    }
  }
}

// =======================================================================
// MFMA Bm + softmax: per i, P[bh][j] = softmax_j((SC[bh][i][j] + q_i@pos_i^T)/8)
// A = q_i [64 bh][64 d] bf16 (LDS, XOR-swz), B = pos[i] [512 j][64 d] -> bf16 LDS.
// 8 waves: wave w owns j in [w*64, w*64+64). Cross-wave softmax via LDS tables.
// LDS: 64KB pos + 8KB q + 4KB red = 76KB -> 2 blocks/CU.
// =======================================================================
__global__ __launch_bounds__(512)
void k_bmsm_mfma(const float* __restrict__ SC, const u16* __restrict__ qb,
                 const float* __restrict__ pos, u16* __restrict__ P){
  int i = blockIdx.x;
  __shared__ short posB[512*64];   // 64 KB (also reused as P repack buffer)
  __shared__ short qB[64*64];      // 8 KB
  __shared__ float redM[8][64];
  __shared__ float redS[8][64];
  int tid = threadIdx.x;
  int w = tid>>6, ln = tid&63;
  // stage q_i: 64 bh x 64 d
  {
    int bh = tid>>3, d8 = (tid&7)*8;
    const u16* src = qb + ((size_t)(bh>>3)*NL + i)*ND + (bh&7)*NDK + d8;
    uint4 v = *(const uint4*)src;
    int byt = (bh*128 + d8*2) ^ ((bh&7)<<4);
    *(uint4*)((char*)qB + byt) = v;
  }
  // stage pos[i]: 512 j x 64 d, f32 -> bf16
  const float* pp = pos + (size_t)i*NL*NDK;
  #pragma unroll
  for(int t0=0;t0<8;t0++){
    int t = t0*512 + tid;
    int j = t>>3, d8 = (t&7)*8;
    float4 a = *(const float4*)&pp[(size_t)j*64 + d8];
    float4 b = *(const float4*)&pp[(size_t)j*64 + d8 + 4];
    uint4 pk;
    pk.x = (unsigned)f2b(a.x) | ((unsigned)f2b(a.y)<<16);
    pk.y = (unsigned)f2b(a.z) | ((unsigned)f2b(a.w)<<16);
    pk.z = (unsigned)f2b(b.x) | ((unsigned)f2b(b.y)<<16);
    pk.w = (unsigned)f2b(b.z) | ((unsigned)f2b(b.w)<<16);
    int byt = (j*128 + d8*2) ^ ((j&7)<<4);
    *(uint4*)((char*)posB + byt) = pk;
  }
  __syncthreads();
  int fr = ln&15, kg = ln>>4;
  f32x4 acc[4][4];
  #pragma unroll
  for(int mi=0;mi<4;mi++)
    #pragma unroll
    for(int nj=0;nj<4;nj++){ f32x4 z={0.f,0.f,0.f,0.f}; acc[mi][nj]=z; }
  #pragma unroll
  for(int ks=0;ks<2;ks++){
    int kb = ks*64;   // byte offset of k-step (32 bf16)
    bf16x8 af[4], bf[4];
    #pragma unroll
    for(int mi=0;mi<4;mi++){
      int row = mi*16 + fr;
      int byt = (row*128 + kb + kg*16) ^ ((row&7)<<4);
      af[mi] = *(const bf16x8*)((const char*)qB + byt);
    }
    #pragma unroll
    for(int nj=0;nj<4;nj++){
      int row = w*64 + nj*16 + fr;
      int byt = (row*128 + kb + kg*16) ^ ((row&7)<<4);
      bf[nj] = *(const bf16x8*)((const char*)posB + byt);
    }
    #pragma unroll
    for(int mi=0;mi<4;mi++)
      #pragma unroll
      for(int nj=0;nj<4;nj++)
        acc[mi][nj] = __builtin_amdgcn_mfma_f32_16x16x32_bf16(af[mi], bf[nj], acc[mi][nj], 0,0,0);
  }
  // epilogue: add SC, scale, softmax over 512 j
  // lane holds rows bh = mi*16 + kg*4 + r ; cols j = w*64 + nj*16 + fr
  #pragma unroll
  for(int mi=0;mi<4;mi++){
    #pragma unroll
    for(int r=0;r<4;r++){
      int bh = mi*16 + kg*4 + r;
      const float* scr = SC + ((size_t)bh*NL + i)*NL;
      #pragma unroll
      for(int nj=0;nj<4;nj++){
        int j = w*64 + nj*16 + fr;
        acc[mi][nj][r] = (acc[mi][nj][r] + scr[j]) * 0.125f;
      }
    }
  }
  float gm[4][4];
  #pragma unroll
  for(int mi=0;mi<4;mi++)
    #pragma unroll
    for(int r=0;r<4;r++){
      float m = fmaxf(fmaxf(acc[mi][0][r],acc[mi][1][r]),fmaxf(acc[mi][2][r],acc[mi][3][r]));
      #pragma unroll
      for(int o=8;o;o>>=1) m = fmaxf(m, __shfl_xor(m,o));
      gm[mi][r] = m;
    }
  if(fr==0){
    #pragma unroll
    for(int mi=0;mi<4;mi++)
      #pragma unroll
      for(int r=0;r<4;r++) redM[w][mi*16+kg*4+r] = gm[mi][r];
  }
  __syncthreads();
  #pragma unroll
  for(int mi=0;mi<4;mi++)
    #pragma unroll
    for(int r=0;r<4;r++){
      int bh = mi*16 + kg*4 + r;
      float m = redM[0][bh];
      #pragma unroll
      for(int w2=1;w2<8;w2++) m = fmaxf(m, redM[w2][bh]);
      gm[mi][r] = m;
    }
  float sv[4][4];
  #pragma unroll
  for(int mi=0;mi<4;mi++)
    #pragma unroll
    for(int r=0;r<4;r++){
      float s = 0.f;
      #pragma unroll
      for(int nj=0;nj<4;nj++){
        acc[mi][nj][r] = __expf(acc[mi][nj][r] - gm[mi][r]);
        s += acc[mi][nj][r];
      }
      #pragma unroll
      for(int o=8;o;o>>=1) s += __shfl_xor(s,o);
      sv[mi][r] = s;
    }
  if(fr==0){
    #pragma unroll
    for(int mi=0;mi<4;mi++)
      #pragma unroll
      for(int r=0;r<4;r++) redS[w][mi*16+kg*4+r] = sv[mi][r];
  }
  __syncthreads();
  // write P into posB repack buffer [64 bh][512 j] bf16
  u16* Pls = (u16*)posB;
  #pragma unroll
  for(int mi=0;mi<4;mi++)
    #pragma unroll
    for(int r=0;r<4;r++){
      int bh = mi*16 + kg*4 + r;
      float tot = 0.f;
      #pragma unroll
      for(int w2=0;w2<8;w2++) tot += redS[w2][bh];
      float inv = 1.0f/tot;
      #pragma unroll
      for(int nj=0;nj<4;nj++){
        int j = w*64 + nj*16 + fr;
        Pls[bh*512 + j] = f2b(acc[mi][nj][r]*inv);
      }
    }
  __syncthreads();
  // coalesced copy LDS -> global
  #pragma unroll
  for(int t0=0;t0<8;t0++){
    int t = t0*512 + tid;   // uint4 index, 4096 total
    int bh = t>>6;
    int j8 = (t&63)*8;
    uint4 v = *(const uint4*)&Pls[bh*512 + j8];
    *(uint4*)&P[((size_t)bh*NL + i)*NL + j8] = v;
  }
}

// =======================================================================
// MFMA PV: o[b,i,h*64+d] = sum_j P[z][i][j] * v[b,j,h*64+d]  (bf16)
// grid (it=4, z=64), BM=128 i, BN=64 d, K=512 j (BK=32).
// V^T staged per k-step via reg transpose into padded swizzled LDS.
// =======================================================================
__global__ __launch_bounds__(256)
void k_pv_mfma(const u16* __restrict__ P, const u16* __restrict__ vb,
               u16* __restrict__ o){
  int z = blockIdx.y, b = z>>3, h = z&7;
  int i0 = blockIdx.x*128;
  __shared__ short lA[128*32];    // P tile
  __shared__ short lBt[64*64];    // V^T [64 d][32 j] padded rows (128B), swizzled
  int tid = threadIdx.x;
  int wv_ = tid>>6, ln_ = tid&63;
  int wy = wv_>>1, wx = wv_&1;
  const u16* Ab = P + ((size_t)z*NL + i0)*NL;

  f32x4 acc[4][2];
  #pragma unroll
  for(int mi=0;mi<4;mi++)
    #pragma unroll
    for(int nj=0;nj<2;nj++){ f32x4 zz={0.f,0.f,0.f,0.f}; acc[mi][nj]=zz; }

  int fr = ln_&15, kg = ln_>>4;
  int aoff[4];
  #pragma unroll
  for(int mi=0;mi<4;mi++){
    int ar = wy*64 + mi*16 + fr;
    aoff[mi] = ar*64 + ((kg ^ ((ar>>1)&3))<<4);
  }
  int boff[2];
  #pragma unroll
  for(int nj=0;nj<2;nj++){
    int n = wx*32 + nj*16 + fr;
    boff[nj] = (n*128 + kg*16) ^ ((n&7)<<4);
  }
  int jrow = tid>>3, d8 = (tid&7)*8;

  for(int k0=0;k0<NL;k0+=32){
    #pragma unroll
    for(int q=0;q<2;q++){
      int s = q*256 + tid;
      int row = s>>2;
      int gl = (s&3) ^ ((row>>1)&3);
      GLOAD16(Ab + (size_t)row*NL + k0 + gl*8, &lA[(q*4+wv_)*512]);
    }
    // transpose-stage V: rows j=k0+jrow (32), cols d8..d8+8
    {
      uint4 v = *(const uint4*)&vb[((size_t)b*NL + k0 + jrow)*ND + h*NDK + d8];
      u16 e[8];
      e[0]=(u16)(v.x&0xffff); e[1]=(u16)(v.x>>16);
      e[2]=(u16)(v.y&0xffff); e[3]=(u16)(v.y>>16);
      e[4]=(u16)(v.z&0xffff); e[5]=(u16)(v.z>>16);
      e[6]=(u16)(v.w&0xffff); e[7]=(u16)(v.w>>16);
      #pragma unroll
      for(int ee=0;ee<8;ee++){
        int d = d8+ee;
        int byt = (d*128 + jrow*2) ^ ((d&7)<<4);
        *(u16*)((char*)lBt + byt) = e[ee];
      }
    }
    __syncthreads();
    bf16x8 af[4], bf[2];
    #pragma unroll
    for(int mi=0;mi<4;mi++) af[mi] = *(const bf16x8*)((const char*)lA + aoff[mi]);
    #pragma unroll
    for(int nj=0;nj<2;nj++) bf[nj] = *(const bf16x8*)((const char*)lBt + boff[nj]);
    #pragma unroll
    for(int mi=0;mi<4;mi++)
      #pragma unroll
      for(int nj=0;nj<2;nj++)
        acc[mi][nj] = __builtin_amdgcn_mfma_f32_16x16x32_bf16(af[mi], bf[nj], acc[mi][nj], 0,0,0);
    __syncthreads();
  }

  int r0 = (ln_>>4)*4;
  #pragma unroll
  for(int mi=0;mi<4;mi++){
    #pragma unroll
    for(int nj=0;nj<2;nj++){
      #pragma unroll
      for(int r=0;r<4;r++){
        int gi = i0 + wy*64 + mi*16 + r0 + r;
        int gd = wx*32 + nj*16 + fr;
        o[((size_t)b*NL + gi)*ND + h*NDK + gd] = f2b(acc[mi][nj][r]);
      }
    }
  }
}

// ---------------- depthwise conv1d, K=31, SAME (bf16 in, bf16 out) ----------------
__global__ __launch_bounds__(256)
void k_dwconv(const u16* __restrict__ in, const float* __restrict__ w,
              const float* __restrict__ bias, u16* __restrict__ out){
  int c  = blockIdx.x*256 + threadIdx.x;
  int t0 = blockIdx.y*4;
  int b  = blockIdx.z;
  const u16* ib = in + (size_t)b*NT*ND + c;
  float win[34];
  #pragma unroll
  for(int r=0;r<34;r++){
    int t = t0 - 15 + r;
    win[r] = (t>=0 && t<NT) ? b2f(ib[(size_t)t*ND]) : 0.0f;
  }
  float wg[31];
  #pragma unroll
  for(int kk=0;kk<31;kk++) wg[kk] = w[c*31+kk];
  float bs = bias[c];
  u16* ob = out + (size_t)b*NT*ND + c;
  #pragma unroll
  for(int oo=0;oo<4;oo++){
    float s = bs;
    #pragma unroll
    for(int kk=0;kk<31;kk++) s += win[oo+kk]*wg[kk];
    ob[(size_t)(t0+oo)*ND] = f2b(s);
  }
}

extern "C" void kernel_launch(void* const* d_in, const int* in_sizes, int n_in,
                              void* d_out, int out_size, void* d_ws, size_t ws_size,
                              hipStream_t stream) {
  const float* x      = (const float*)d_in[0];
  const float* pos    = (const float*)d_in[1];
  const float* mha_g  = (const float*)d_in[2];
  const float* mha_b  = (const float*)d_in[3];
  const float* wq     = (const float*)d_in[4];
  const float* bq     = (const float*)d_in[5];
  const float* wk     = (const float*)d_in[6];
  const float* bk     = (const float*)d_in[7];
  const float* wv     = (const float*)d_in[8];
  const float* bv     = (const float*)d_in[9];
  const float* wo     = (const float*)d_in[10];
  const float* bo     = (const float*)d_in[11];
  const float* ega_wg = (const float*)d_in[12];
  const float* ega_bg = (const float*)d_in[13];
  const float* g1_ln_g= (const float*)d_in[14];
  const float* g1_ln_b= (const float*)d_in[15];
  const float* g1_w1  = (const float*)d_in[16];
  const float* g1_b1  = (const float*)d_in[17];
  const float* g1_w2  = (const float*)d_in[18];
  const float* g1_b2  = (const float*)d_in[19];
  const float* g1_wg  = (const float*)d_in[20];
  const float* g1_bg  = (const float*)d_in[21];
  const float* cla_ln_g=(const float*)d_in[22];
  const float* cla_ln_b=(const float*)d_in[23];
  const float* cla_w1 = (const float*)d_in[24];
  const float* cla_b1 = (const float*)d_in[25];
  const float* dw_w   = (const float*)d_in[26];
  const float* dw_b   = (const float*)d_in[27];
  const float* cla_w2 = (const float*)d_in[28];
  const float* cla_b2 = (const float*)d_in[29];
  const float* g2_ln_g= (const float*)d_in[30];
  const float* g2_ln_b= (const float*)d_in[31];
  const float* g2_w1  = (const float*)d_in[32];
  const float* g2_b1  = (const float*)d_in[33];
  const float* g2_w2  = (const float*)d_in[34];
  const float* g2_b2  = (const float*)d_in[35];
  const float* g2_wg  = (const float*)d_in[36];
  const float* g2_bg  = (const float*)d_in[37];

  float* xo = (float*)d_out;
  float* ws = (float*)d_ws;
  const size_t M1 = 1024*1024;

  // workspace map (f32 units); [0,16M) time-multiplexed (SC fits exactly 16M):
  float* SC    = ws;                       // scores f32 (attn phase)
  u16*  s5b    = (u16*)ws;                 // [0,1)   attn out bf16 (post-pv)
  u16*  glu_p  = (u16*)ws;                 // [0,6)   g1/g2 GLU out
  u16*  glu_b  = (u16*)ws;                 // [0,4)   CLA GLU out
  u16*  conv_b = (u16*)(ws + 4*M1);        // [4,8)   CLA conv out
  u16*  s6b    = (u16*)(ws + 6*M1);        // [6,7)   'up' bf16
  u16*  lnPb   = (u16*)(ws + 7*M1);        // [7,8)   pooled ln bf16
  u16*  lnFb   = (u16*)(ws + 8*M1);        // [8,12)  CLA ln bf16
  u16*  Pb     = (u16*)(ws + 16*M1);       // [16,24) attn probs bf16
  u16*  xbA    = (u16*)(ws + 24*M1);       // [24,28) stream ping
  u16*  xbB    = (u16*)(ws + 28*M1);       // [28,32) stream pong
  u16*  WTb    = (u16*)(ws + 32*M1);       // [32,36) bf16 weights
  u16*  q_b    = (u16*)(ws + 38*M1);       // [38,39) q bf16
  u16*  k_b    = (u16*)(ws + 39*M1);       // [39,40) k bf16
  u16*  v_b    = (u16*)(ws + 40*M1);       // [40,41) v bf16

  u16* wqT   = WTb + 0;
  u16* wkT   = WTb + 262144;
  u16* wvT   = WTb + 524288;
  u16* woT   = WTb + 786432;
  u16* egaT  = WTb + 1048576;
  u16* g1w1T = WTb + 1310720;
  u16* g1w2T = WTb + 2883584;
  u16* g1wgT = WTb + 3670016;
  u16* claw1T= WTb + 3932160;
  u16* claw2T= WTb + 4456448;
  u16* g2w1T = WTb + 4718592;
  u16* g2w2T = WTb + 6291456;
  u16* g2wgT = WTb + 7077888;

  const int rowsP = NB*NL;        // 4096
  const int rowsF = NB*NT;        // 16384
  const int n4F = rowsF*128;
  dim3 blk(256);
  dim3 gPool(4,64);
  dim3 gFull(4,128);

  // ---- weight prep ----
  {
    WtJobs J;
    const float* Wsrc[13] = {wq,wk,wv,wo,ega_wg,g1_w1,g1_w2,g1_wg,cla_w1,cla_w2,g2_w1,g2_w2,g2_wg};
    u16* Wdst[13] = {wqT,wkT,wvT,woT,egaT,g1w1T,g1w2T,g1wgT,claw1T,claw2T,g2w1T,g2w2T,g2wgT};
    int Ks[13] = {512,512,512,512,512, 512,1536,512, 512,512, 512,1536,512};
    int Ns[13] = {512,512,512,512,512, 3072,512,512, 1024,512, 3072,512,512};
    int off = 0;
    for(int t=0;t<13;t++){
      J.W[t]=Wsrc[t]; J.WT[t]=Wdst[t]; J.K[t]=Ks[t]; J.N[t]=Ns[t];
      J.off[t]=off; off += (Ns[t]>>5)*(Ks[t]>>5);
    }
    J.off[13]=off;
    k_wt_all<<<off, blk, 0, stream>>>(J);
  }
  k_castb<<<(n4F+255)/256, blk, 0, stream>>>((const float4*)x, (ushort4*)xbA, n4F);

  // ================= EGA =================
  k_poollnf<<<rowsP, 64, 0, stream>>>(x, lnPb, mha_g, mha_b);
  k_gemm_mfma<0,2><<<gPool, blk, 0, stream>>>(lnPb, wqT, bq, nullptr,nullptr, nullptr, q_b, rowsP, ND, ND);
  k_gemm_mfma<0,2><<<gPool, blk, 0, stream>>>(lnPb, wkT, bk, nullptr,nullptr, nullptr, k_b, rowsP, ND, ND);
  k_gemm_mfma<0,2><<<gPool, blk, 0, stream>>>(lnPb, wvT, bv, nullptr,nullptr, nullptr, v_b, rowsP, ND, ND);
  k_qkt_mfma<<<dim3(4,4,64), blk, 0, stream>>>(q_b, k_b, SC);
  k_bmsm_mfma<<<512, 512, 0, stream>>>(SC, q_b, pos, Pb);
  k_pv_mfma<<<dim3(4,64), blk, 0, stream>>>(Pb, v_b, s5b);
  k_gemm_mfma<0,2><<<gPool, blk, 0, stream>>>(s5b, woT, bo, nullptr,nullptr, nullptr, s6b, rowsP, ND, ND);
  k_gemm_mfma<1,4><<<gFull, blk, 0, stream>>>(xbA, egaT, ega_bg, xbA, s6b, nullptr, xbB, rowsF, ND, ND);

  // ================= GCFN global (g1) =================
  k_poollnb<<<rowsP, 64, 0, stream>>>(xbB, lnPb, g1_ln_g, g1_ln_b);
  k_glu_mfma<<<dim3(24,32), blk, 0, stream>>>(lnPb, g1w1T, g1_b1, glu_p, rowsP, 1536, ND);
  k_gemm_mfma<0,2><<<gPool, blk, 0, stream>>>(glu_p, g1w2T, g1_b2, nullptr,nullptr, nullptr, s6b, rowsP, ND, 1536);
  k_gemm_mfma<1,4><<<gFull, blk, 0, stream>>>(xbB, g1wgT, g1_bg, xbB, s6b, nullptr, xbA, rowsF, ND, ND);

  // ================= CLA =================
  k_lnb4<<<rowsF/4, blk, 0, stream>>>(xbA, lnFb, cla_ln_g, cla_ln_b);
  k_glu_mfma<<<dim3(8,128), blk, 0, stream>>>(lnFb, claw1T, cla_b1, glu_b, rowsF, 512, ND);
  k_dwconv<<<dim3(2, NT/4, NB), blk, 0, stream>>>(glu_b, dw_w, dw_b, conv_b);
  k_gemm_mfma<2,4><<<gFull, blk, 0, stream>>>(conv_b, claw2T, cla_b2, xbA, nullptr, nullptr, xbB, rowsF, ND, ND);

  // ================= GCFN local (g2) =================
  k_poollnb<<<rowsP, 64, 0, stream>>>(xbB, lnPb, g2_ln_g, g2_ln_b);
  k_glu_mfma<<<dim3(24,32), blk, 0, stream>>>(lnPb, g2w1T, g2_b1, glu_p, rowsP, 1536, ND);
  k_gemm_mfma<0,2><<<gPool, blk, 0, stream>>>(glu_p, g2w2T, g2_b2, nullptr,nullptr, nullptr, s6b, rowsP, ND, 1536);
  k_gemm_mfma<1,4><<<gFull, blk, 0, stream>>>(xbB, g2wgT, g2_bg, xbB, s6b, xo, nullptr, rowsF, ND, ND);
}

// Round 9
// 457.597 us; speedup vs baseline: 4.1224x; 1.0851x over previous
//
#include <hip/hip_runtime.h>
#include <math.h>

#define NB 8
#define NT 2048
#define ND 512
#define NH 8
#define NDK 64
#define NL 512
#define CONV_T 16

typedef unsigned short u16;
typedef __attribute__((ext_vector_type(8))) short bf16x8;
typedef __attribute__((ext_vector_type(4))) float f32x4;

__device__ __forceinline__ float sigf(float v){ return 1.0f/(1.0f+__expf(-v)); }

__device__ __forceinline__ u16 f2b(float f){
  union{float f; unsigned u;} v; v.f = f;
  unsigned r = v.u + 0x7fffu + ((v.u>>16)&1u);
  return (u16)(r>>16);
}
__device__ __forceinline__ float b2f(u16 h){
  union{unsigned u; float f;} v; v.u = ((unsigned)h)<<16; return v.f;
}

#define GLOAD16(src, dst) \
  __builtin_amdgcn_global_load_lds((const __attribute__((address_space(1))) void*)(src), \
                                   (__attribute__((address_space(3))) void*)(dst), 16, 0, 0)

// ---------------- fused pool4 + LayerNorm, f32 in -> bf16 out ----------------
__global__ void k_poollnf(const float* __restrict__ in, u16* __restrict__ outb,
                          const float* __restrict__ gam, const float* __restrict__ bet){
  size_t prow = blockIdx.x;
  int lane = threadIdx.x;   // 64
  const float* p = in + prow*4*ND + lane*8;
  float x[8] = {0,0,0,0,0,0,0,0};
  #pragma unroll
  for(int rr=0;rr<4;rr++){
    float4 a = *(const float4*)&p[(size_t)rr*ND];
    float4 b = *(const float4*)&p[(size_t)rr*ND+4];
    x[0]+=a.x; x[1]+=a.y; x[2]+=a.z; x[3]+=a.w;
    x[4]+=b.x; x[5]+=b.y; x[6]+=b.z; x[7]+=b.w;
  }
  #pragma unroll
  for(int e=0;e<8;e++) x[e]*=0.25f;
  float s=0.f, ss=0.f;
  #pragma unroll
  for(int e=0;e<8;e++){ s+=x[e]; ss+=x[e]*x[e]; }
  #pragma unroll
  for(int o=32;o;o>>=1){ s+=__shfl_xor(s,o); ss+=__shfl_xor(ss,o); }
  float m  = s*(1.0f/ND);
  float rs = rsqrtf(ss*(1.0f/ND)-m*m+1e-5f);
  const float4* gp=(const float4*)gam; const float4* bp=(const float4*)bet;
  float4 g0=gp[lane*2],g1=gp[lane*2+1],b0=bp[lane*2],b1=bp[lane*2+1];
  float o0=(x[0]-m)*rs*g0.x+b0.x, o1=(x[1]-m)*rs*g0.y+b0.y;
  float o2=(x[2]-m)*rs*g0.z+b0.z, o3=(x[3]-m)*rs*g0.w+b0.w;
  float o4=(x[4]-m)*rs*g1.x+b1.x, o5=(x[5]-m)*rs*g1.y+b1.y;
  float o6=(x[6]-m)*rs*g1.z+b1.z, o7=(x[7]-m)*rs*g1.w+b1.w;
  uint4 pk;
  pk.x = (unsigned)f2b(o0) | ((unsigned)f2b(o1)<<16);
  pk.y = (unsigned)f2b(o2) | ((unsigned)f2b(o3)<<16);
  pk.z = (unsigned)f2b(o4) | ((unsigned)f2b(o5)<<16);
  pk.w = (unsigned)f2b(o6) | ((unsigned)f2b(o7)<<16);
  *(uint4*)&outb[prow*ND + lane*8] = pk;
}

// ---------------- fused pool4 + LayerNorm, bf16 in -> bf16 out ----------------
__global__ void k_poollnb(const u16* __restrict__ in, u16* __restrict__ outb,
                          const float* __restrict__ gam, const float* __restrict__ bet){
  size_t prow = blockIdx.x;
  int lane = threadIdx.x;
  const u16* p = in + prow*4*ND + lane*8;
  float x[8] = {0,0,0,0,0,0,0,0};
  #pragma unroll
  for(int rr=0;rr<4;rr++){
    ushort4 a = *(const ushort4*)&p[(size_t)rr*ND];
    ushort4 b = *(const ushort4*)&p[(size_t)rr*ND+4];
    x[0]+=b2f(a.x); x[1]+=b2f(a.y); x[2]+=b2f(a.z); x[3]+=b2f(a.w);
    x[4]+=b2f(b.x); x[5]+=b2f(b.y); x[6]+=b2f(b.z); x[7]+=b2f(b.w);
  }
  #pragma unroll
  for(int e=0;e<8;e++) x[e]*=0.25f;
  float s=0.f, ss=0.f;
  #pragma unroll
  for(int e=0;e<8;e++){ s+=x[e]; ss+=x[e]*x[e]; }
  #pragma unroll
  for(int o=32;o;o>>=1){ s+=__shfl_xor(s,o); ss+=__shfl_xor(ss,o); }
  float m  = s*(1.0f/ND);
  float rs = rsqrtf(ss*(1.0f/ND)-m*m+1e-5f);
  const float4* gp=(const float4*)gam; const float4* bp=(const float4*)bet;
  float4 g0=gp[lane*2],g1=gp[lane*2+1],b0=bp[lane*2],b1=bp[lane*2+1];
  float o0=(x[0]-m)*rs*g0.x+b0.x, o1=(x[1]-m)*rs*g0.y+b0.y;
  float o2=(x[2]-m)*rs*g0.z+b0.z, o3=(x[3]-m)*rs*g0.w+b0.w;
  float o4=(x[4]-m)*rs*g1.x+b1.x, o5=(x[5]-m)*rs*g1.y+b1.y;
  float o6=(x[6]-m)*rs*g1.z+b1.z, o7=(x[7]-m)*rs*g1.w+b1.w;
  uint4 pk;
  pk.x = (unsigned)f2b(o0) | ((unsigned)f2b(o1)<<16);
  pk.y = (unsigned)f2b(o2) | ((unsigned)f2b(o3)<<16);
  pk.z = (unsigned)f2b(o4) | ((unsigned)f2b(o5)<<16);
  pk.w = (unsigned)f2b(o6) | ((unsigned)f2b(o7)<<16);
  *(uint4*)&outb[prow*ND + lane*8] = pk;
}

// ---------------- row LayerNorm, bf16 in -> bf16 out, 4 rows/block ----------------
__global__ __launch_bounds__(256)
void k_lnb4(const u16* __restrict__ in, u16* __restrict__ outb,
            const float* __restrict__ gam, const float* __restrict__ bet){
  size_t row = (size_t)blockIdx.x*4 + (threadIdx.x>>6);
  int lane = threadIdx.x & 63;
  const u16* p = in + row*ND + lane*8;
  ushort4 a0 = *(const ushort4*)p;
  ushort4 a1 = *(const ushort4*)(p+4);
  float x0=b2f(a0.x),x1=b2f(a0.y),x2=b2f(a0.z),x3=b2f(a0.w);
  float x4=b2f(a1.x),x5=b2f(a1.y),x6=b2f(a1.z),x7=b2f(a1.w);
  float s  = x0+x1+x2+x3+x4+x5+x6+x7;
  float ss = x0*x0+x1*x1+x2*x2+x3*x3+x4*x4+x5*x5+x6*x6+x7*x7;
  #pragma unroll
  for(int o=32;o;o>>=1){ s+=__shfl_xor(s,o); ss+=__shfl_xor(ss,o); }
  float m  = s*(1.0f/ND);
  float rs = rsqrtf(ss*(1.0f/ND)-m*m+1e-5f);
  const float4* gp=(const float4*)gam; const float4* bp=(const float4*)bet;
  float4 g0=gp[lane*2],g1=gp[lane*2+1],b0=bp[lane*2],b1=bp[lane*2+1];
  float o0=(x0-m)*rs*g0.x+b0.x, o1=(x1-m)*rs*g0.y+b0.y;
  float o2=(x2-m)*rs*g0.z+b0.z, o3=(x3-m)*rs*g0.w+b0.w;
  float o4=(x4-m)*rs*g1.x+b1.x, o5=(x5-m)*rs*g1.y+b1.y;
  float o6=(x6-m)*rs*g1.z+b1.z, o7=(x7-m)*rs*g1.w+b1.w;
  uint4 pk;
  pk.x = (unsigned)f2b(o0) | ((unsigned)f2b(o1)<<16);
  pk.y = (unsigned)f2b(o2) | ((unsigned)f2b(o3)<<16);
  pk.z = (unsigned)f2b(o4) | ((unsigned)f2b(o5)<<16);
  pk.w = (unsigned)f2b(o6) | ((unsigned)f2b(o7)<<16);
  *(uint4*)&outb[row*ND + lane*8] = pk;
}

// ---------------- cast f32 -> bf16 ----------------
__global__ void k_castb(const float4* __restrict__ in, ushort4* __restrict__ out, int n4){
  int i = blockIdx.x*256 + threadIdx.x;
  if(i>=n4) return;
  float4 v = in[i];
  out[i] = make_ushort4(f2b(v.x), f2b(v.y), f2b(v.z), f2b(v.w));
}

// ---------------- merged weight transpose+cast: 13 jobs, one launch ----------------
struct WtJobs {
  const float* W[13];
  u16* WT[13];
  int K[13], N[13];
  int off[14];
};
__global__ __launch_bounds__(256)
void k_wt_all(WtJobs jobs){
  __shared__ float ls[32][33];
  int bid = blockIdx.x;
  int ji = 0;
  #pragma unroll
  for(int t=0;t<12;t++) if(bid >= jobs.off[t+1]) ji = t+1;
  int local = bid - jobs.off[ji];
  const float* W = jobs.W[ji];
  u16* WT = jobs.WT[ji];
  int K = jobs.K[ji], N = jobs.N[ji];
  int tn = N>>5;
  int n0 = (local % tn)*32, k0 = (local / tn)*32;
  int tid = threadIdx.x;
  int tx = tid&31, ty = tid>>5;
  #pragma unroll
  for(int p=0;p<4;p++)
    ls[ty+p*8][tx] = W[(size_t)(k0+ty+p*8)*N + n0+tx];
  __syncthreads();
  #pragma unroll
  for(int p=0;p<4;p++)
    WT[(size_t)(n0+ty+p*8)*K + k0+tx] = f2b(ls[tx][ty+p*8]);
}

// =======================================================================
// MFMA GEMM (generic): C = A_bf16[M,K] @ BT_bf16[N,K]^T (+ epilogue)
// =======================================================================
template<int EPI, int MI>
__global__ __launch_bounds__(256)
void k_gemm_mfma(const u16* __restrict__ A, const u16* __restrict__ BT,
                 const float* __restrict__ bias,
                 const u16* __restrict__ xinB, const u16* __restrict__ upB,
                 float* __restrict__ outF, u16* __restrict__ outB,
                 int M, int N, int K){
  constexpr int BM = MI*32;
  __shared__ short lA[BM*32];
  __shared__ short lB[128*32];
  int tid = threadIdx.x;
  int wv_ = tid>>6, ln_ = tid&63;
  int wy = wv_>>1, wx = wv_&1;
  int nx = gridDim.x;
  int flat = blockIdx.y*nx + blockIdx.x;
  int cpx = (nx*gridDim.y)>>3;
  int swz = (flat&7)*cpx + (flat>>3);
  int m0 = (swz/nx)*BM, n0 = (swz%nx)*128;

  f32x4 acc[MI][4];
  #pragma unroll
  for(int i=0;i<MI;i++)
    #pragma unroll
    for(int j=0;j<4;j++){ f32x4 z = {0.f,0.f,0.f,0.f}; acc[i][j]=z; }

  int fr = ln_&15, kg = ln_>>4;
  int aoff[MI], boff[4];
  #pragma unroll
  for(int i=0;i<MI;i++){
    int ar = wy*(MI*16) + i*16 + fr;
    aoff[i] = ar*64 + ((kg ^ ((ar>>1)&3))<<4);
  }
  #pragma unroll
  for(int j=0;j<4;j++){
    int br = wx*64 + j*16 + fr;
    boff[j] = br*64 + ((kg ^ ((br>>1)&3))<<4);
  }

  for(int k0=0;k0<K;k0+=32){
    #pragma unroll
    for(int q=0;q<BM/64;q++){
      int s = q*256 + tid;
      int row = s>>2;
      int gl = (s&3) ^ ((row>>1)&3);
      GLOAD16(A + (size_t)(m0+row)*K + k0 + gl*8, &lA[(q*4+wv_)*512]);
    }
    #pragma unroll
    for(int q=0;q<2;q++){
      int s = q*256 + tid;
      int row = s>>2;
      int gl = (s&3) ^ ((row>>1)&3);
      GLOAD16(BT + (size_t)(n0+row)*K + k0 + gl*8, &lB[(q*4+wv_)*512]);
    }
    __syncthreads();
    bf16x8 af[MI], bf[4];
    #pragma unroll
    for(int i=0;i<MI;i++) af[i] = *(const bf16x8*)((const char*)lA + aoff[i]);
    #pragma unroll
    for(int j=0;j<4;j++) bf[j] = *(const bf16x8*)((const char*)lB + boff[j]);
    #pragma unroll
    for(int i=0;i<MI;i++)
      #pragma unroll
      for(int j=0;j<4;j++)
        acc[i][j] = __builtin_amdgcn_mfma_f32_16x16x32_bf16(af[i], bf[j], acc[i][j], 0,0,0);
    __syncthreads();
  }

  int r0 = (ln_>>4)*4, c0 = ln_&15;
  #pragma unroll
  for(int i=0;i<MI;i++){
    #pragma unroll
    for(int j=0;j<4;j++){
      int gr = m0 + wy*(MI*16) + i*16 + r0;
      int gc = n0 + wx*64 + j*16 + c0;
      float bv = bias[gc];
      #pragma unroll
      for(int r=0;r<4;r++){
        float val = acc[i][j][r] + bv;
        size_t idx = (size_t)(gr+r)*N + gc;
        float o;
        if(EPI==0){
          o = val;
        } else if(EPI==1){
          o = b2f(xinB[idx]) + sigf(val)*b2f(upB[(size_t)((gr+r)>>2)*N + gc]);
        } else {
          o = b2f(xinB[idx]) + val;
        }
        if(outF) outF[idx] = o;
        if(outB) outB[idx] = f2b(o);
      }
    }
  }
}

// =======================================================================
// MFMA GLU GEMM
// =======================================================================
__global__ __launch_bounds__(256)
void k_glu_mfma(const u16* __restrict__ A, const u16* __restrict__ WT,
                const float* __restrict__ bias, u16* __restrict__ outB,
                int M, int Dh, int K){
  __shared__ short lA [128*32];
  __shared__ short lBa[64*32];
  __shared__ short lBb[64*32];
  int tid = threadIdx.x;
  int wv_ = tid>>6, ln_ = tid&63;
  int wy = wv_>>1, wx = wv_&1;
  int nx = gridDim.x;
  int flat = blockIdx.y*nx + blockIdx.x;
  int cpx = (nx*gridDim.y)>>3;
  int swz = (flat&7)*cpx + (flat>>3);
  int m0 = (swz/nx)*128, n0 = (swz%nx)*64;

  f32x4 aca[4][2], acb[4][2];
  #pragma unroll
  for(int i=0;i<4;i++)
    #pragma unroll
    for(int j=0;j<2;j++){ f32x4 z={0.f,0.f,0.f,0.f}; aca[i][j]=z; acb[i][j]=z; }

  int fr = ln_&15, kg = ln_>>4;
  int aoff[4], boff[2];
  #pragma unroll
  for(int i=0;i<4;i++){
    int ar = wy*64 + i*16 + fr;
    aoff[i] = ar*64 + ((kg ^ ((ar>>1)&3))<<4);
  }
  #pragma unroll
  for(int j=0;j<2;j++){
    int br = wx*32 + j*16 + fr;
    boff[j] = br*64 + ((kg ^ ((br>>1)&3))<<4);
  }

  for(int k0=0;k0<K;k0+=32){
    #pragma unroll
    for(int q=0;q<2;q++){
      int s = q*256 + tid;
      int row = s>>2;
      int gl = (s&3) ^ ((row>>1)&3);
      GLOAD16(A + (size_t)(m0+row)*K + k0 + gl*8, &lA[(q*4+wv_)*512]);
    }
    {
      int s = tid;
      int row = s>>2;
      int gl = (s&3) ^ ((row>>1)&3);
      GLOAD16(WT + (size_t)(n0+row)*K      + k0 + gl*8, &lBa[wv_*512]);
      GLOAD16(WT + (size_t)(Dh+n0+row)*K   + k0 + gl*8, &lBb[wv_*512]);
    }
    __syncthreads();
    bf16x8 af[4], ba[2], bb[2];
    #pragma unroll
    for(int i=0;i<4;i++) af[i] = *(const bf16x8*)((const char*)lA + aoff[i]);
    #pragma unroll
    for(int j=0;j<2;j++){
      ba[j] = *(const bf16x8*)((const char*)lBa + boff[j]);
      bb[j] = *(const bf16x8*)((const char*)lBb + boff[j]);
    }
    #pragma unroll
    for(int i=0;i<4;i++)
      #pragma unroll
      for(int j=0;j<2;j++){
        aca[i][j] = __builtin_amdgcn_mfma_f32_16x16x32_bf16(af[i], ba[j], aca[i][j], 0,0,0);
        acb[i][j] = __builtin_amdgcn_mfma_f32_16x16x32_bf16(af[i], bb[j], acb[i][j], 0,0,0);
      }
    __syncthreads();
  }

  int r0 = (ln_>>4)*4, c0 = ln_&15;
  #pragma unroll
  for(int i=0;i<4;i++){
    #pragma unroll
    for(int j=0;j<2;j++){
      int gr = m0 + wy*64 + i*16 + r0;
      int gc = n0 + wx*32 + j*16 + c0;
      float bva = bias[gc], bvb = bias[Dh+gc];
      #pragma unroll
      for(int r=0;r<4;r++){
        float o = (aca[i][j][r]+bva) * sigf(acb[i][j][r]+bvb);
        outB[(size_t)(gr+r)*Dh + gc] = f2b(o);
      }
    }
  }
}

// =======================================================================
// MFMA QK^T: SC[z][i][j] (bf16 out now — saves 64MB of HBM round-trip)
// =======================================================================
__global__ __launch_bounds__(256)
void k_qkt_mfma(const u16* __restrict__ qb, const u16* __restrict__ kb,
                u16* __restrict__ SC){
  int z = blockIdx.z, b = z>>3, h = z&7;
  int i0 = blockIdx.y*128, j0 = blockIdx.x*128;
  __shared__ short lA[128*32];
  __shared__ short lB[128*32];
  int tid = threadIdx.x;
  int wv_ = tid>>6, ln_ = tid&63;
  int wy = wv_>>1, wx = wv_&1;
  const u16* Ab = qb + ((size_t)b*NL + i0)*ND + h*NDK;
  const u16* Bb = kb + ((size_t)b*NL + j0)*ND + h*NDK;

  f32x4 acc[4][4];
  #pragma unroll
  for(int i=0;i<4;i++)
    #pragma unroll
    for(int j=0;j<4;j++){ f32x4 zz={0.f,0.f,0.f,0.f}; acc[i][j]=zz; }

  int fr = ln_&15, kg = ln_>>4;
  int aoff[4], boff[4];
  #pragma unroll
  for(int i=0;i<4;i++){
    int ar = wy*64 + i*16 + fr;
    aoff[i] = ar*64 + ((kg ^ ((ar>>1)&3))<<4);
    int br = wx*64 + i*16 + fr;
    boff[i] = br*64 + ((kg ^ ((br>>1)&3))<<4);
  }

  #pragma unroll
  for(int k0=0;k0<64;k0+=32){
    #pragma unroll
    for(int q=0;q<2;q++){
      int s = q*256 + tid;
      int row = s>>2;
      int gl = (s&3) ^ ((row>>1)&3);
      GLOAD16(Ab + (size_t)row*ND + k0 + gl*8, &lA[(q*4+wv_)*512]);
      GLOAD16(Bb + (size_t)row*ND + k0 + gl*8, &lB[(q*4+wv_)*512]);
    }
    __syncthreads();
    bf16x8 af[4], bf[4];
    #pragma unroll
    for(int i=0;i<4;i++) af[i] = *(const bf16x8*)((const char*)lA + aoff[i]);
    #pragma unroll
    for(int j=0;j<4;j++) bf[j] = *(const bf16x8*)((const char*)lB + boff[j]);
    #pragma unroll
    for(int i=0;i<4;i++)
      #pragma unroll
      for(int j=0;j<4;j++)
        acc[i][j] = __builtin_amdgcn_mfma_f32_16x16x32_bf16(af[i], bf[j], acc[i][j], 0,0,0);
    __syncthreads();
  }

  u16* sb = SC + (size_t)z*NL*NL;
  int r0 = (ln_>>4)*4, c0 = ln_&15;
  #pragma unroll
  for(int i=0;i<4;i++){
    #pragma unroll
    for(int j=0;j<4;j++){
      int gr = i0 + wy*64 + i*16 + r0;
      int gc = j0 + wx*64 + j*16 + c0;
      #pragma unroll
      for(int r=0;r<4;r++)
        sb[(size_t)(gr+r)*NL + gc] = f2b(acc[i][j][r]);
    }
  }
}

// =======================================================================
// MFMA Bm + softmax (SC now bf16 in)
// =======================================================================
__global__ __launch_bounds__(512)
void k_bmsm_mfma(const u16* __restrict__ SC, const u16* __restrict__ qb,
                 const float* __restrict__ pos, u16* __restrict__ P){
  int i = blockIdx.x;
  __shared__ short posB[512*64];   // 64 KB (reused as P repack buffer)
  __shared__ short qB[64*64];      // 8 KB
  __shared__ float redM[8][64];
  __shared__ float redS[8][64];
  int tid = threadIdx.x;
  int w = tid>>6, ln = tid&63;
  {
    int bh = tid>>3, d8 = (tid&7)*8;
    const u16* src = qb + ((size_t)(bh>>3)*NL + i)*ND + (bh&7)*NDK + d8;
    uint4 v = *(const uint4*)src;
    int byt = (bh*128 + d8*2) ^ ((bh&7)<<4);
    *(uint4*)((char*)qB + byt) = v;
  }
  const float* pp = pos + (size_t)i*NL*NDK;
  #pragma unroll
  for(int t0=0;t0<8;t0++){
    int t = t0*512 + tid;
    int j = t>>3, d8 = (t&7)*8;
    float4 a = *(const float4*)&pp[(size_t)j*64 + d8];
    float4 b = *(const float4*)&pp[(size_t)j*64 + d8 + 4];
    uint4 pk;
    pk.x = (unsigned)f2b(a.x) | ((unsigned)f2b(a.y)<<16);
    pk.y = (unsigned)f2b(a.z) | ((unsigned)f2b(a.w)<<16);
    pk.z = (unsigned)f2b(b.x) | ((unsigned)f2b(b.y)<<16);
    pk.w = (unsigned)f2b(b.z) | ((unsigned)f2b(b.w)<<16);
    int byt = (j*128 + d8*2) ^ ((j&7)<<4);
    *(uint4*)((char*)posB + byt) = pk;
  }
  __syncthreads();
  int fr = ln&15, kg = ln>>4;
  f32x4 acc[4][4];
  #pragma unroll
  for(int mi=0;mi<4;mi++)
    #pragma unroll
    for(int nj=0;nj<4;nj++){ f32x4 z={0.f,0.f,0.f,0.f}; acc[mi][nj]=z; }
  #pragma unroll
  for(int ks=0;ks<2;ks++){
    int kb = ks*64;
    bf16x8 af[4], bf[4];
    #pragma unroll
    for(int mi=0;mi<4;mi++){
      int row = mi*16 + fr;
      int byt = (row*128 + kb + kg*16) ^ ((row&7)<<4);
      af[mi] = *(const bf16x8*)((const char*)qB + byt);
    }
    #pragma unroll
    for(int nj=0;nj<4;nj++){
      int row = w*64 + nj*16 + fr;
      int byt = (row*128 + kb + kg*16) ^ ((row&7)<<4);
      bf[nj] = *(const bf16x8*)((const char*)posB + byt);
    }
    #pragma unroll
    for(int mi=0;mi<4;mi++)
      #pragma unroll
      for(int nj=0;nj<4;nj++)
        acc[mi][nj] = __builtin_amdgcn_mfma_f32_16x16x32_bf16(af[mi], bf[nj], acc[mi][nj], 0,0,0);
  }
  #pragma unroll
  for(int mi=0;mi<4;mi++){
    #pragma unroll
    for(int r=0;r<4;r++){
      int bh = mi*16 + kg*4 + r;
      const u16* scr = SC + ((size_t)bh*NL + i)*NL;
      #pragma unroll
      for(int nj=0;nj<4;nj++){
        int j = w*64 + nj*16 + fr;
        acc[mi][nj][r] = (acc[mi][nj][r] + b2f(scr[j])) * 0.125f;
      }
    }
  }
  float gm[4][4];
  #pragma unroll
  for(int mi=0;mi<4;mi++)
    #pragma unroll
    for(int r=0;r<4;r++){
      float m = fmaxf(fmaxf(acc[mi][0][r],acc[mi][1][r]),fmaxf(acc[mi][2][r],acc[mi][3][r]));
      #pragma unroll
      for(int o=8;o;o>>=1) m = fmaxf(m, __shfl_xor(m,o));
      gm[mi][r] = m;
    }
  if(fr==0){
    #pragma unroll
    for(int mi=0;mi<4;mi++)
      #pragma unroll
      for(int r=0;r<4;r++) redM[w][mi*16+kg*4+r] = gm[mi][r];
  }
  __syncthreads();
  #pragma unroll
  for(int mi=0;mi<4;mi++)
    #pragma unroll
    for(int r=0;r<4;r++){
      int bh = mi*16 + kg*4 + r;
      float m = redM[0][bh];
      #pragma unroll
      for(int w2=1;w2<8;w2++) m = fmaxf(m, redM[w2][bh]);
      gm[mi][r] = m;
    }
  float sv[4][4];
  #pragma unroll
  for(int mi=0;mi<4;mi++)
    #pragma unroll
    for(int r=0;r<4;r++){
      float s = 0.f;
      #pragma unroll
      for(int nj=0;nj<4;nj++){
        acc[mi][nj][r] = __expf(acc[mi][nj][r] - gm[mi][r]);
        s += acc[mi][nj][r];
      }
      #pragma unroll
      for(int o=8;o;o>>=1) s += __shfl_xor(s,o);
      sv[mi][r] = s;
    }
  if(fr==0){
    #pragma unroll
    for(int mi=0;mi<4;mi++)
      #pragma unroll
      for(int r=0;r<4;r++) redS[w][mi*16+kg*4+r] = sv[mi][r];
  }
  __syncthreads();
  u16* Pls = (u16*)posB;
  #pragma unroll
  for(int mi=0;mi<4;mi++)
    #pragma unroll
    for(int r=0;r<4;r++){
      int bh = mi*16 + kg*4 + r;
      float tot = 0.f;
      #pragma unroll
      for(int w2=0;w2<8;w2++) tot += redS[w2][bh];
      float inv = 1.0f/tot;
      #pragma unroll
      for(int nj=0;nj<4;nj++){
        int j = w*64 + nj*16 + fr;
        Pls[bh*512 + j] = f2b(acc[mi][nj][r]*inv);
      }
    }
  __syncthreads();
  #pragma unroll
  for(int t0=0;t0<8;t0++){
    int t = t0*512 + tid;
    int bh = t>>6;
    int j8 = (t&63)*8;
    uint4 v = *(const uint4*)&Pls[bh*512 + j8];
    *(uint4*)&P[((size_t)bh*NL + i)*NL + j8] = v;
  }
}

// =======================================================================
// MFMA PV
// =======================================================================
__global__ __launch_bounds__(256)
void k_pv_mfma(const u16* __restrict__ P, const u16* __restrict__ vb,
               u16* __restrict__ o){
  int z = blockIdx.y, b = z>>3, h = z&7;
  int i0 = blockIdx.x*128;
  __shared__ short lA[128*32];
  __shared__ short lBt[64*64];
  int tid = threadIdx.x;
  int wv_ = tid>>6, ln_ = tid&63;
  int wy = wv_>>1, wx = wv_&1;
  const u16* Ab = P + ((size_t)z*NL + i0)*NL;

  f32x4 acc[4][2];
  #pragma unroll
  for(int mi=0;mi<4;mi++)
    #pragma unroll
    for(int nj=0;nj<2;nj++){ f32x4 zz={0.f,0.f,0.f,0.f}; acc[mi][nj]=zz; }

  int fr = ln_&15, kg = ln_>>4;
  int aoff[4];
  #pragma unroll
  for(int mi=0;mi<4;mi++){
    int ar = wy*64 + mi*16 + fr;
    aoff[mi] = ar*64 + ((kg ^ ((ar>>1)&3))<<4);
  }
  int boff[2];
  #pragma unroll
  for(int nj=0;nj<2;nj++){
    int n = wx*32 + nj*16 + fr;
    boff[nj] = (n*128 + kg*16) ^ ((n&7)<<4);
  }
  int jrow = tid>>3, d8 = (tid&7)*8;

  for(int k0=0;k0<NL;k0+=32){
    #pragma unroll
    for(int q=0;q<2;q++){
      int s = q*256 + tid;
      int row = s>>2;
      int gl = (s&3) ^ ((row>>1)&3);
      GLOAD16(Ab + (size_t)row*NL + k0 + gl*8, &lA[(q*4+wv_)*512]);
    }
    {
      uint4 v = *(const uint4*)&vb[((size_t)b*NL + k0 + jrow)*ND + h*NDK + d8];
      u16 e[8];
      e[0]=(u16)(v.x&0xffff); e[1]=(u16)(v.x>>16);
      e[2]=(u16)(v.y&0xffff); e[3]=(u16)(v.y>>16);
      e[4]=(u16)(v.z&0xffff); e[5]=(u16)(v.z>>16);
      e[6]=(u16)(v.w&0xffff); e[7]=(u16)(v.w>>16);
      #pragma unroll
      for(int ee=0;ee<8;ee++){
        int d = d8+ee;
        int byt = (d*128 + jrow*2) ^ ((d&7)<<4);
        *(u16*)((char*)lBt + byt) = e[ee];
      }
    }
    __syncthreads();
    bf16x8 af[4], bf[2];
    #pragma unroll
    for(int mi=0;mi<4;mi++) af[mi] = *(const bf16x8*)((const char*)lA + aoff[mi]);
    #pragma unroll
    for(int nj=0;nj<2;nj++) bf[nj] = *(const bf16x8*)((const char*)lBt + boff[nj]);
    #pragma unroll
    for(int mi=0;mi<4;mi++)
      #pragma unroll
      for(int nj=0;nj<2;nj++)
        acc[mi][nj] = __builtin_amdgcn_mfma_f32_16x16x32_bf16(af[mi], bf[nj], acc[mi][nj], 0,0,0);
    __syncthreads();
  }

  int r0 = (ln_>>4)*4;
  #pragma unroll
  for(int mi=0;mi<4;mi++){
    #pragma unroll
    for(int nj=0;nj<2;nj++){
      #pragma unroll
      for(int r=0;r<4;r++){
        int gi = i0 + wy*64 + mi*16 + r0 + r;
        int gd = wx*32 + nj*16 + fr;
        o[((size_t)b*NL + gi)*ND + h*NDK + gd] = f2b(acc[mi][nj][r]);
      }
    }
  }
}

// ---------------- depthwise conv1d, K=31, SAME — 16 outputs/thread ----------------
__global__ __launch_bounds__(256)
void k_dwconv(const u16* __restrict__ in, const float* __restrict__ w,
              const float* __restrict__ bias, u16* __restrict__ out){
  int c  = blockIdx.x*256 + threadIdx.x;
  int t0 = blockIdx.y*CONV_T;
  int b  = blockIdx.z;
  const u16* ib = in + (size_t)b*NT*ND + c;
  float win[CONV_T+30];
  #pragma unroll
  for(int r=0;r<CONV_T+30;r++){
    int t = t0 - 15 + r;
    win[r] = (t>=0 && t<NT) ? b2f(ib[(size_t)t*ND]) : 0.0f;
  }
  float wg[31];
  #pragma unroll
  for(int kk=0;kk<31;kk++) wg[kk] = w[c*31+kk];
  float bs = bias[c];
  u16* ob = out + (size_t)b*NT*ND + c;
  #pragma unroll
  for(int oo=0;oo<CONV_T;oo++){
    float s = bs;
    #pragma unroll
    for(int kk=0;kk<31;kk++) s += win[oo+kk]*wg[kk];
    ob[(size_t)(t0+oo)*ND] = f2b(s);
  }
}

extern "C" void kernel_launch(void* const* d_in, const int* in_sizes, int n_in,
                              void* d_out, int out_size, void* d_ws, size_t ws_size,
                              hipStream_t stream) {
  const float* x      = (const float*)d_in[0];
  const float* pos    = (const float*)d_in[1];
  const float* mha_g  = (const float*)d_in[2];
  const float* mha_b  = (const float*)d_in[3];
  const float* wq     = (const float*)d_in[4];
  const float* bq     = (const float*)d_in[5];
  const float* wk     = (const float*)d_in[6];
  const float* bk     = (const float*)d_in[7];
  const float* wv     = (const float*)d_in[8];
  const float* bv     = (const float*)d_in[9];
  const float* wo     = (const float*)d_in[10];
  const float* bo     = (const float*)d_in[11];
  const float* ega_wg = (const float*)d_in[12];
  const float* ega_bg = (const float*)d_in[13];
  const float* g1_ln_g= (const float*)d_in[14];
  const float* g1_ln_b= (const float*)d_in[15];
  const float* g1_w1  = (const float*)d_in[16];
  const float* g1_b1  = (const float*)d_in[17];
  const float* g1_w2  = (const float*)d_in[18];
  const float* g1_b2  = (const float*)d_in[19];
  const float* g1_wg  = (const float*)d_in[20];
  const float* g1_bg  = (const float*)d_in[21];
  const float* cla_ln_g=(const float*)d_in[22];
  const float* cla_ln_b=(const float*)d_in[23];
  const float* cla_w1 = (const float*)d_in[24];
  const float* cla_b1 = (const float*)d_in[25];
  const float* dw_w   = (const float*)d_in[26];
  const float* dw_b   = (const float*)d_in[27];
  const float* cla_w2 = (const float*)d_in[28];
  const float* cla_b2 = (const float*)d_in[29];
  const float* g2_ln_g= (const float*)d_in[30];
  const float* g2_ln_b= (const float*)d_in[31];
  const float* g2_w1  = (const float*)d_in[32];
  const float* g2_b1  = (const float*)d_in[33];
  const float* g2_w2  = (const float*)d_in[34];
  const float* g2_b2  = (const float*)d_in[35];
  const float* g2_wg  = (const float*)d_in[36];
  const float* g2_bg  = (const float*)d_in[37];

  float* xo = (float*)d_out;
  float* ws = (float*)d_ws;
  const size_t M1 = 1024*1024;

  // workspace map (f32 units); [0,16M) time-multiplexed:
  u16*  SCb    = (u16*)ws;                 // scores bf16 [0,8M f32) (attn phase)
  u16*  s5b    = (u16*)ws;                 // [0,1)   attn out bf16 (post-bmsm)
  u16*  glu_p  = (u16*)ws;                 // [0,6)   g1/g2 GLU out
  u16*  glu_b  = (u16*)ws;                 // [0,4)   CLA GLU out
  u16*  conv_b = (u16*)(ws + 4*M1);        // [4,8)   CLA conv out
  u16*  s6b    = (u16*)(ws + 6*M1);        // [6,7)   'up' bf16
  u16*  lnPb   = (u16*)(ws + 7*M1);        // [7,8)   pooled ln bf16
  u16*  lnFb   = (u16*)(ws + 8*M1);        // [8,12)  CLA ln bf16
  u16*  Pb     = (u16*)(ws + 16*M1);       // [16,24) attn probs bf16
  u16*  xbA    = (u16*)(ws + 24*M1);       // [24,28) stream ping
  u16*  xbB    = (u16*)(ws + 28*M1);       // [28,32) stream pong
  u16*  WTb    = (u16*)(ws + 32*M1);       // [32,36) bf16 weights
  u16*  q_b    = (u16*)(ws + 38*M1);       // [38,39) q bf16
  u16*  k_b    = (u16*)(ws + 39*M1);       // [39,40) k bf16
  u16*  v_b    = (u16*)(ws + 40*M1);       // [40,41) v bf16

  u16* wqT   = WTb + 0;
  u16* wkT   = WTb + 262144;
  u16* wvT   = WTb + 524288;
  u16* woT   = WTb + 786432;
  u16* egaT  = WTb + 1048576;
  u16* g1w1T = WTb + 1310720;
  u16* g1w2T = WTb + 2883584;
  u16* g1wgT = WTb + 3670016;
  u16* claw1T= WTb + 3932160;
  u16* claw2T= WTb + 4456448;
  u16* g2w1T = WTb + 4718592;
  u16* g2w2T = WTb + 6291456;
  u16* g2wgT = WTb + 7077888;

  const int rowsP = NB*NL;        // 4096
  const int rowsF = NB*NT;        // 16384
  const int n4F = rowsF*128;
  dim3 blk(256);
  dim3 gPool(4,64);
  dim3 gFull(4,128);

  // ---- weight prep ----
  {
    WtJobs J;
    const float* Wsrc[13] = {wq,wk,wv,wo,ega_wg,g1_w1,g1_w2,g1_wg,cla_w1,cla_w2,g2_w1,g2_w2,g2_wg};
    u16* Wdst[13] = {wqT,wkT,wvT,woT,egaT,g1w1T,g1w2T,g1wgT,claw1T,claw2T,g2w1T,g2w2T,g2wgT};
    int Ks[13] = {512,512,512,512,512, 512,1536,512, 512,512, 512,1536,512};
    int Ns[13] = {512,512,512,512,512, 3072,512,512, 1024,512, 3072,512,512};
    int off = 0;
    for(int t=0;t<13;t++){
      J.W[t]=Wsrc[t]; J.WT[t]=Wdst[t]; J.K[t]=Ks[t]; J.N[t]=Ns[t];
      J.off[t]=off; off += (Ns[t]>>5)*(Ks[t]>>5);
    }
    J.off[13]=off;
    k_wt_all<<<off, blk, 0, stream>>>(J);
  }
  k_castb<<<(n4F+255)/256, blk, 0, stream>>>((const float4*)x, (ushort4*)xbA, n4F);

  // ================= EGA =================
  k_poollnf<<<rowsP, 64, 0, stream>>>(x, lnPb, mha_g, mha_b);
  k_gemm_mfma<0,2><<<gPool, blk, 0, stream>>>(lnPb, wqT, bq, nullptr,nullptr, nullptr, q_b, rowsP, ND, ND);
  k_gemm_mfma<0,2><<<gPool, blk, 0, stream>>>(lnPb, wkT, bk, nullptr,nullptr, nullptr, k_b, rowsP, ND, ND);
  k_gemm_mfma<0,2><<<gPool, blk, 0, stream>>>(lnPb, wvT, bv, nullptr,nullptr, nullptr, v_b, rowsP, ND, ND);
  k_qkt_mfma<<<dim3(4,4,64), blk, 0, stream>>>(q_b, k_b, SCb);
  k_bmsm_mfma<<<512, 512, 0, stream>>>(SCb, q_b, pos, Pb);
  k_pv_mfma<<<dim3(4,64), blk, 0, stream>>>(Pb, v_b, s5b);
  k_gemm_mfma<0,2><<<gPool, blk, 0, stream>>>(s5b, woT, bo, nullptr,nullptr, nullptr, s6b, rowsP, ND, ND);
  k_gemm_mfma<1,4><<<gFull, blk, 0, stream>>>(xbA, egaT, ega_bg, xbA, s6b, nullptr, xbB, rowsF, ND, ND);

  // ================= GCFN global (g1) =================
  k_poollnb<<<rowsP, 64, 0, stream>>>(xbB, lnPb, g1_ln_g, g1_ln_b);
  k_glu_mfma<<<dim3(24,32), blk, 0, stream>>>(lnPb, g1w1T, g1_b1, glu_p, rowsP, 1536, ND);
  k_gemm_mfma<0,2><<<gPool, blk, 0, stream>>>(glu_p, g1w2T, g1_b2, nullptr,nullptr, nullptr, s6b, rowsP, ND, 1536);
  k_gemm_mfma<1,4><<<gFull, blk, 0, stream>>>(xbB, g1wgT, g1_bg, xbB, s6b, nullptr, xbA, rowsF, ND, ND);

  // ================= CLA =================
  k_lnb4<<<rowsF/4, blk, 0, stream>>>(xbA, lnFb, cla_ln_g, cla_ln_b);
  k_glu_mfma<<<dim3(8,128), blk, 0, stream>>>(lnFb, claw1T, cla_b1, glu_b, rowsF, 512, ND);
  k_dwconv<<<dim3(2, NT/CONV_T, NB), blk, 0, stream>>>(glu_b, dw_w, dw_b, conv_b);
  k_gemm_mfma<2,4><<<gFull, blk, 0, stream>>>(conv_b, claw2T, cla_b2, xbA, nullptr, nullptr, xbB, rowsF, ND, ND);

  // ================= GCFN local (g2) =================
  k_poollnb<<<rowsP, 64, 0, stream>>>(xbB, lnPb, g2_ln_g, g2_ln_b);
  k_glu_mfma<<<dim3(24,32), blk, 0, stream>>>(lnPb, g2w1T, g2_b1, glu_p, rowsP, 1536, ND);
  k_gemm_mfma<0,2><<<gPool, blk, 0, stream>>>(glu_p, g2w2T, g2_b2, nullptr,nullptr, nullptr, s6b, rowsP, ND, 1536);
  k_gemm_mfma<1,4><<<gFull, blk, 0, stream>>>(xbB, g2wgT, g2_bg, xbB, s6b, xo, nullptr, rowsF, ND, ND);
}